// Round 5
// baseline (1406.486 us; speedup 1.0000x reference)
//
#include <hip/hip_runtime.h>
#include <hip/hip_bf16.h>
#include <cfloat>

#define B_ 4
#define N_ 2048
#define NG_ 12
#define K_ 16
#define H_ 64
#define C_ 128
#define BD_ 64
#define M_ 512

typedef __attribute__((ext_vector_type(8))) short short8;
typedef __attribute__((ext_vector_type(4))) float floatx4;
typedef unsigned short ushort_t;
typedef unsigned int uint_t;

__device__ __forceinline__ float gelu_f(float x){
  float s = 0.7978845608028654f*(x + 0.044715f*x*x*x);
  float e = __expf(2.0f*s);
  float t = 1.0f - 2.0f/(e + 1.0f);
  return 0.5f*x*(1.0f + t);
}

__device__ __forceinline__ ushort_t bf16_rne(float x){
  uint_t u = __float_as_uint(x);
  uint_t r = (u + 0x7fffu + ((u >> 16) & 1u)) >> 16;
  return (ushort_t)r;
}

// DPP argmax step: combine (v,vi) with DPP-shifted partner; take larger v, tie -> smaller vi.
#define DPP_AMAX(CTRL) { \
  int _vb = __float_as_int(v); \
  int _ov = __builtin_amdgcn_update_dpp(_vb, _vb, (CTRL), 0xF, 0xF, false); \
  int _oi = __builtin_amdgcn_update_dpp(vi, vi, (CTRL), 0xF, 0xF, false); \
  float _of = __int_as_float(_ov); \
  bool _tk = (_of > v) || (_of == v && _oi < vi); \
  v = _tk ? _of : v; vi = _tk ? _oi : vi; }

// DPP argmin step: take smaller v, tie -> smaller vi.
#define DPP_AMIN(CTRL) { \
  int _vb = __float_as_int(v); \
  int _ov = __builtin_amdgcn_update_dpp(_vb, _vb, (CTRL), 0xF, 0xF, false); \
  int _oi = __builtin_amdgcn_update_dpp(vi, vi, (CTRL), 0xF, 0xF, false); \
  float _of = __int_as_float(_ov); \
  bool _tk = (_of < v) || (_of == v && _oi < vi); \
  v = _tk ? _of : v; vi = _tk ? _oi : vi; }

// ---------------- K1: lift + embed -> x1 [B,N,NG,H] ----------------
__global__ __launch_bounds__(256) void k_lift(
    const float* __restrict__ pos, const float* __restrict__ normal,
    const float* __restrict__ grid,
    const float* __restrict__ e1w, const float* __restrict__ e1b,
    const float* __restrict__ e2w, const float* __restrict__ e2b,
    float* __restrict__ x1){
  int tid = threadIdx.x;
  int q = tid>>6, lane = tid&63;
  int fid = blockIdx.x*4 + q;
  int g = fid % NG_;
  int n = (fid / NG_) % N_;
  int b = fid / (NG_*N_);
  const float* nm = normal + (size_t)(b*N_+n)*3;
  const float* pp = pos + (size_t)(b*N_+n)*3;
  const float* gg = grid + g*3;
  float f0 = nm[0]*gg[0] + nm[1]*gg[1] + nm[2]*gg[2];
  float t = e1b[lane] + f0*e1w[lane] + pp[0]*e1w[64+lane] + pp[1]*e1w[128+lane] + pp[2]*e1w[192+lane];
  __shared__ float ts[4][64];
  ts[q][lane] = gelu_f(t);
  __syncthreads();
  float acc = e2b[lane];
  #pragma unroll
  for (int i=0;i<64;++i) acc = fmaf(ts[q][i], e2w[i*64+lane], acc);
  x1[(size_t)fid*64 + lane] = acc;
}

// ---------------- K2: farthest point sampling -> ps [B,M,3] ----------------
// 4 waves; DPP in-wave argmax; one barrier/iter for cross-wave combine.
__global__ __launch_bounds__(256) void k_fps(const float* __restrict__ pos, float* __restrict__ ps){
  int b = blockIdx.x, tid = threadIdx.x;
  __shared__ float4 posS4[N_];
  __shared__ float2 wred[2][4];
  for (int i=tid;i<N_;i+=256){
    const float* p = pos + (size_t)b*N_*3 + (size_t)i*3;
    posS4[i] = make_float4(p[0], p[1], p[2], 0.f);
  }
  __syncthreads();
  float px[8],py[8],pz[8],d[8];
  #pragma unroll
  for (int j=0;j<8;++j){
    float4 pt = posS4[tid + 256*j];
    px[j]=pt.x; py[j]=pt.y; pz[j]=pt.z;
    d[j]=1e10f;
  }
  int wave = tid>>6, lane = tid&63;
  int last = 0;
  for (int s=0;s<M_;++s){
    float4 lp = posS4[last];
    float lx=lp.x, ly=lp.y, lz=lp.z;
    if (tid==0){ float* o = ps + ((size_t)b*M_+s)*3; o[0]=lx;o[1]=ly;o[2]=lz; }
    #pragma unroll
    for (int j=0;j<8;++j){
      float dx=__fsub_rn(px[j],lx), dy=__fsub_rn(py[j],ly), dz=__fsub_rn(pz[j],lz);
      float dist=__fadd_rn(__fadd_rn(__fmul_rn(dx,dx),__fmul_rn(dy,dy)),__fmul_rn(dz,dz));
      d[j]=fminf(d[j],dist);
    }
    if (s==M_-1) break;
    // local argmax over 8 (depth-3 tree, ties -> lower j = lower global index)
    float va = d[1]>d[0]?d[1]:d[0]; int ja = d[1]>d[0]?1:0;
    float vb = d[3]>d[2]?d[3]:d[2]; int jb = d[3]>d[2]?3:2;
    float vc = d[5]>d[4]?d[5]:d[4]; int jc = d[5]>d[4]?5:4;
    float vd = d[7]>d[6]?d[7]:d[6]; int jd = d[7]>d[6]?7:6;
    float ve = vb>va?vb:va; int je = vb>va?jb:ja;
    float vf = vd>vc?vd:vc; int jf = vd>vc?jd:jc;
    float v  = vf>ve?vf:ve; int jj = vf>ve?jf:je;
    int vi = tid + (jj<<8);
    // in-wave DPP argmax -> lane 63 holds wave champion
    DPP_AMAX(0x121); DPP_AMAX(0x122); DPP_AMAX(0x124); DPP_AMAX(0x128);
    DPP_AMAX(0x142); DPP_AMAX(0x143);
    int sv = __builtin_amdgcn_readlane(__float_as_int(v), 63);
    int si = __builtin_amdgcn_readlane(vi, 63);
    if (lane==0) wred[s&1][wave] = make_float2(__int_as_float(sv), __int_as_float(si));
    __syncthreads();
    float2 r0 = wred[s&1][0], r1 = wred[s&1][1], r2 = wred[s&1][2], r3 = wred[s&1][3];
    float bv = r0.x; int bi = __float_as_int(r0.y);
    int i1 = __float_as_int(r1.y); if (r1.x>bv || (r1.x==bv && i1<bi)){ bv=r1.x; bi=i1; }
    int i2 = __float_as_int(r2.y); if (r2.x>bv || (r2.x==bv && i2<bi)){ bv=r2.x; bi=i2; }
    int i3 = __float_as_int(r3.y); if (r3.x>bv || (r3.x==bv && i3<bi)){ bv=r3.x; bi=i3; }
    last = bi;
  }
}

// ---------------- K3: exact KNN (k smallest d2, stable ties), DPP reduce ----------------
template<int NP>
__global__ __launch_bounds__(64) void k_knn(const float* __restrict__ qp, const float* __restrict__ pool,
                                            int* __restrict__ out){
  constexpr int R = NP/64;
  int lane = threadIdx.x;
  int qm = blockIdx.x;            // b*M + m
  int b = qm / M_;
  const float* q = qp + (size_t)qm*3;
  float qx=q[0], qy=q[1], qz=q[2];
  float d2[R];
  #pragma unroll
  for (int j=0;j<R;++j){
    int n = lane + 64*j;
    const float* p = pool + ((size_t)b*NP + n)*3;
    float dx=__fsub_rn(qx,p[0]), dy=__fsub_rn(qy,p[1]), dz=__fsub_rn(qz,p[2]);
    d2[j]=__fadd_rn(__fadd_rn(__fmul_rn(dx,dx),__fmul_rn(dy,dy)),__fmul_rn(dz,dz));
  }
  for (int r=0;r<K_;++r){
    // local argmin over R (tree; ties -> lower j = lower global index)
    float tv[R]; int ti[R];
    #pragma unroll
    for (int j=0;j<R;++j){ tv[j]=d2[j]; ti[j]=lane+64*j; }
    #pragma unroll
    for (int w=R/2; w>0; w>>=1){
      #pragma unroll
      for (int j=0;j<w;++j){
        bool tk = (tv[j+w]<tv[j]) || (tv[j+w]==tv[j] && ti[j+w]<ti[j]);
        tv[j] = tk?tv[j+w]:tv[j];
        ti[j] = tk?ti[j+w]:ti[j];
      }
    }
    float v = tv[0]; int vi = ti[0];
    DPP_AMIN(0x121); DPP_AMIN(0x122); DPP_AMIN(0x124); DPP_AMIN(0x128);
    DPP_AMIN(0x142); DPP_AMIN(0x143);
    int si = __builtin_amdgcn_readlane(vi, 63);
    if (lane==0) out[(size_t)qm*K_ + r] = si;
    #pragma unroll
    for (int j=0;j<R;++j){ if (si == lane + 64*j) d2[j] = FLT_MAX; }
  }
}

// ---------------- K4: fused down-proj + relu + neighbor-max -> xA [B,M,NG,C] ----------------
__global__ __launch_bounds__(256) void k_downmax(
    const float* __restrict__ x1, const int* __restrict__ nbrD,
    const float* __restrict__ dw, const float* __restrict__ db,
    float* __restrict__ xA){
  int bm = blockIdx.x; int b = bm / M_;
  int tid = threadIdx.x;
  __shared__ int nb[K_];
  __shared__ float xs[K_][NG_*H_];     // 48 KB
  if (tid<K_) nb[tid] = nbrD[(size_t)bm*K_ + tid];
  __syncthreads();
  for (int idx=tid; idx<K_*NG_*H_/4; idx+=256){
    int k = idx / (NG_*H_/4), r = idx % (NG_*H_/4);
    ((float4*)&xs[k][0])[r] = ((const float4*)&x1[((size_t)(b*N_) + nb[k])*(NG_*H_)])[r];
  }
  __syncthreads();
  int c = tid & 127, gh = tid >> 7;
  float dbc = db[c];
  for (int gi=0; gi<6; ++gi){
    int g = gh*6 + gi;
    float acc[K_];
    #pragma unroll
    for (int k=0;k<K_;++k) acc[k]=dbc;
    for (int i4=0;i4<16;++i4){
      float w0 = dw[(i4*4+0)*C_ + c];
      float w1 = dw[(i4*4+1)*C_ + c];
      float w2 = dw[(i4*4+2)*C_ + c];
      float w3 = dw[(i4*4+3)*C_ + c];
      #pragma unroll
      for (int k=0;k<K_;++k){
        float4 xv = *(const float4*)&xs[k][g*H_ + i4*4];
        acc[k] = fmaf(xv.x,w0,fmaf(xv.y,w1,fmaf(xv.z,w2,fmaf(xv.w,w3,acc[k]))));
      }
    }
    float best = acc[0];
    #pragma unroll
    for (int k=1;k<K_;++k) best = fmaxf(best, acc[k]);
    xA[(size_t)bm*(NG_*C_) + g*C_ + c] = fmaxf(best, 0.0f);
  }
}

// ---------------- K5: kbR basis MLP [NG,NG,BD] ----------------
__global__ __launch_bounds__(128) void k_kbR(
    const float* __restrict__ grid, const float* __restrict__ rff,
    const float* __restrict__ w1, const float* __restrict__ b1,
    const float* __restrict__ w2, const float* __restrict__ b2,
    float* __restrict__ kbR){
  int gm = blockIdx.x / NG_, gn = blockIdx.x % NG_;
  int j = threadIdx.x;
  float z = grid[gm*3]*grid[gn*3] + grid[gm*3+1]*grid[gn*3+1] + grid[gm*3+2]*grid[gn*3+2];
  __shared__ float fs[128], hs[128];
  int jj = j & 63;
  float ang = 6.283185307179586f * (z * rff[jj]);
  fs[j] = (j<64) ? sinf(ang) : cosf(ang);
  __syncthreads();
  float acc = b1[j];
  for (int i=0;i<128;++i) acc = fmaf(fs[i], w1[i*128+j], acc);
  hs[j] = gelu_f(acc);
  __syncthreads();
  if (j < 64){
    float a2 = b2[j];
    for (int i=0;i<128;++i) a2 = fmaf(hs[i], w2[i*64+j], a2);
    kbR[(size_t)blockIdx.x*64 + j] = gelu_f(a2);
  }
}

// ---------------- K6: kR = kbR @ kR_w + b  [NG,NG,C] ----------------
__global__ __launch_bounds__(128) void k_kR(
    const float* __restrict__ kbR, const float* __restrict__ kRw, const float* __restrict__ kRb,
    float* __restrict__ kR){
  int pair = blockIdx.x; int c = threadIdx.x;
  __shared__ float kb[64];
  if (c<64) kb[c] = kbR[(size_t)pair*64 + c];
  __syncthreads();
  float acc = kRb[c];
  for (int d=0;d<64;++d) acc = fmaf(kb[d], kRw[d*128+c], acc);
  kR[(size_t)pair*128 + c] = acc;
}

// ---------------- K6b: split weights into transposed bf16 hi/lo ----------------
__global__ __launch_bounds__(256) void k_wsplit(
    const float* __restrict__ w1, const float* __restrict__ w2,
    ushort_t* __restrict__ w1hiT, ushort_t* __restrict__ w1loT,
    ushort_t* __restrict__ w2hiT, ushort_t* __restrict__ w2loT){
  int tid = blockIdx.x*256 + threadIdx.x;
  if (tid < 16384){
    int j = tid >> 7, k = tid & 127;
    float x = w1[k*128 + j];
    ushort_t hi = bf16_rne(x);
    float hif = __uint_as_float(((uint_t)hi)<<16);
    ushort_t lo = bf16_rne(x - hif);
    w1hiT[tid] = hi; w1loT[tid] = lo;
  }
  if (tid < 8192){
    int c = tid >> 7, j = tid & 127;
    float x = w2[j*64 + c];
    ushort_t hi = bf16_rne(x);
    float hif = __uint_as_float(((uint_t)hi)<<16);
    ushort_t lo = bf16_rne(x - hif);
    w2hiT[tid] = hi; w2loT[tid] = lo;
  }
}

// ---------------- K7: kbx basis MLP via MFMA bf16 x3 (hi/lo split) ----------------
__global__ __launch_bounds__(256) void k_kbx(
    const float* __restrict__ ps, const int* __restrict__ nbr,
    const float* __restrict__ grid, const float* __restrict__ rff,
    const ushort_t* __restrict__ w1hiT, const ushort_t* __restrict__ w1loT,
    const ushort_t* __restrict__ w2hiT, const ushort_t* __restrict__ w2loT,
    const float* __restrict__ b1, const float* __restrict__ b2,
    float* __restrict__ kbx){
  __shared__ float z0s[128], z1s[128], rws[128];
  __shared__ float bounce[4][32*34];
  int tid = threadIdx.x;
  if (tid < 128){
    rws[tid] = rff[tid];
    int fid = blockIdx.x*128 + tid;
    int g = fid % NG_;
    int k = (fid/NG_) % K_;
    int bm = fid / (NG_*K_);
    int b = bm / M_;
    int nb = nbr[(size_t)bm*K_ + k];
    const float* pm = ps + (size_t)bm*3;
    const float* pn = ps + ((size_t)(b*M_) + nb)*3;
    float rx = pn[0]-pm[0], ry = pn[1]-pm[1], rz3 = pn[2]-pm[2];
    const float* gg = grid + g*3;
    float rz = rx*gg[0] + ry*gg[1] + rz3*gg[2];
    float vx = rx - rz*gg[0], vy = ry - rz*gg[1], vz = rz3 - rz*gg[2];
    float rxy = sqrtf(vx*vx + vy*vy + vz*vz + 1e-12f);
    z0s[tid]=rxy; z1s[tid]=rz;
  }
  __syncthreads();
  int wid = tid>>6, lane = tid&63;
  int ln = lane & 15, g = lane >> 4;

  short8 ahi[2][4], alo[2][4];
  #pragma unroll
  for (int rt=0; rt<2; ++rt){
    float z0 = z0s[wid*32 + rt*16 + ln];
    float z1 = z1s[wid*32 + rt*16 + ln];
    #pragma unroll
    for (int ks=0; ks<4; ++ks){
      #pragma unroll
      for (int e=0; e<8; ++e){
        int kd = ks*32 + g*8 + e;
        int kk = kd & 63;
        float t = z0*rws[kk] + z1*rws[64+kk];
        t = t - floorf(t);
        float v = (ks < 2) ? __builtin_amdgcn_sinf(t) : __builtin_amdgcn_cosf(t);
        ushort_t hi = bf16_rne(v);
        float hif = __uint_as_float(((uint_t)hi)<<16);
        ushort_t lo = bf16_rne(v - hif);
        ahi[rt][ks][e] = (short)hi;
        alo[rt][ks][e] = (short)lo;
      }
    }
  }

  floatx4 acc2[2][4];
  #pragma unroll
  for (int rt=0; rt<2; ++rt)
    #pragma unroll
    for (int ct=0; ct<4; ++ct)
      acc2[rt][ct] = (floatx4){0.f,0.f,0.f,0.f};

  float* bw = &bounce[wid][0];

  #pragma unroll
  for (int jp=0; jp<4; ++jp){
    floatx4 acc1[2][2];
    #pragma unroll
    for (int rt=0; rt<2; ++rt)
      #pragma unroll
      for (int jt=0; jt<2; ++jt)
        acc1[rt][jt] = (floatx4){0.f,0.f,0.f,0.f};
    #pragma unroll
    for (int ks=0; ks<4; ++ks){
      #pragma unroll
      for (int jt=0; jt<2; ++jt){
        int j = jp*32 + jt*16 + ln;
        short8 bhi = *(const short8*)&w1hiT[(size_t)j*128 + ks*32 + g*8];
        short8 blo = *(const short8*)&w1loT[(size_t)j*128 + ks*32 + g*8];
        #pragma unroll
        for (int rt=0; rt<2; ++rt){
          acc1[rt][jt] = __builtin_amdgcn_mfma_f32_16x16x32_bf16(ahi[rt][ks], bhi, acc1[rt][jt], 0,0,0);
          acc1[rt][jt] = __builtin_amdgcn_mfma_f32_16x16x32_bf16(alo[rt][ks], bhi, acc1[rt][jt], 0,0,0);
          acc1[rt][jt] = __builtin_amdgcn_mfma_f32_16x16x32_bf16(ahi[rt][ks], blo, acc1[rt][jt], 0,0,0);
        }
      }
    }
    #pragma unroll
    for (int jt=0; jt<2; ++jt){
      float bb = b1[jp*32 + jt*16 + ln];
      #pragma unroll
      for (int rt=0; rt<2; ++rt)
        #pragma unroll
        for (int i=0; i<4; ++i)
          bw[(rt*16 + g*4 + i)*34 + jt*16 + ln] = gelu_f(bb + acc1[rt][jt][i]);
    }
    #pragma unroll
    for (int rt=0; rt<2; ++rt){
      int base = (rt*16 + ln)*34 + g*8;
      float2 p0 = *(float2*)&bw[base+0];
      float2 p1 = *(float2*)&bw[base+2];
      float2 p2 = *(float2*)&bw[base+4];
      float2 p3 = *(float2*)&bw[base+6];
      float hv[8] = {p0.x,p0.y,p1.x,p1.y,p2.x,p2.y,p3.x,p3.y};
      short8 a2h, a2l;
      #pragma unroll
      for (int e=0; e<8; ++e){
        ushort_t hi = bf16_rne(hv[e]);
        float hif = __uint_as_float(((uint_t)hi)<<16);
        ushort_t lo = bf16_rne(hv[e] - hif);
        a2h[e] = (short)hi;
        a2l[e] = (short)lo;
      }
      #pragma unroll
      for (int ct=0; ct<4; ++ct){
        short8 b2h = *(const short8*)&w2hiT[(size_t)(ct*16+ln)*128 + jp*32 + g*8];
        short8 b2l = *(const short8*)&w2loT[(size_t)(ct*16+ln)*128 + jp*32 + g*8];
        acc2[rt][ct] = __builtin_amdgcn_mfma_f32_16x16x32_bf16(a2h, b2h, acc2[rt][ct], 0,0,0);
        acc2[rt][ct] = __builtin_amdgcn_mfma_f32_16x16x32_bf16(a2l, b2h, acc2[rt][ct], 0,0,0);
        acc2[rt][ct] = __builtin_amdgcn_mfma_f32_16x16x32_bf16(a2h, b2l, acc2[rt][ct], 0,0,0);
      }
    }
  }
  #pragma unroll
  for (int ct=0; ct<4; ++ct){
    float bb = b2[ct*16 + ln];
    #pragma unroll
    for (int rt=0; rt<2; ++rt)
      #pragma unroll
      for (int i=0; i<4; ++i){
        int row = wid*32 + rt*16 + g*4 + i;
        size_t fiber = (size_t)blockIdx.x*128 + row;
        kbx[fiber*64 + ct*16 + ln] = gelu_f(bb + acc2[rt][ct][i]);
      }
  }
}

// ---------------- K8: interaction layer ----------------
__global__ __launch_bounds__(256) void k_inter(
    const float* __restrict__ xin, const int* __restrict__ nbr,
    const float* __restrict__ kbx, const float* __restrict__ kR,
    const float* __restrict__ kxw, const float* __restrict__ kxb,
    const float* __restrict__ mw, const float* __restrict__ mb,
    float* __restrict__ xout){
  int bm = blockIdx.x; int b = bm / M_;
  int tid = threadIdx.x;
  int c = tid & 127, gh = tid >> 7;
  __shared__ float kbs[NG_*BD_];    // 3 KB
  __shared__ float xns[NG_*C_];     // 6 KB
  __shared__ float aggS[NG_][C_];   // 6 KB
  __shared__ float yS[NG_][C_];     // 6 KB
  float wreg[64];
  #pragma unroll
  for (int d=0; d<64; ++d) wreg[d] = kxw[d*C_ + c];
  float accg[6] = {0,0,0,0,0,0};
  float kxbc = kxb[c];
  for (int k=0;k<K_;++k){
    int nb = nbr[(size_t)bm*K_ + k];
    __syncthreads();
    {
      const float4* src = (const float4*)&kbx[((size_t)bm*K_ + k)*(NG_*BD_)];
      for (int idx=tid; idx<NG_*BD_/4; idx+=256) ((float4*)kbs)[idx] = src[idx];
      const float4* src2 = (const float4*)&xin[((size_t)(b*M_) + nb)*(NG_*C_)];
      for (int idx=tid; idx<NG_*C_/4; idx+=256) ((float4*)xns)[idx] = src2[idx];
    }
    __syncthreads();
    float t6[6] = {0,0,0,0,0,0};
    #pragma unroll
    for (int d4=0; d4<16; ++d4){
      #pragma unroll
      for (int gi=0; gi<6; ++gi){
        int g = gh*6+gi;
        float4 kv = *(const float4*)&kbs[g*BD_ + d4*4];
        t6[gi] = fmaf(kv.x,wreg[d4*4+0],fmaf(kv.y,wreg[d4*4+1],fmaf(kv.z,wreg[d4*4+2],fmaf(kv.w,wreg[d4*4+3],t6[gi]))));
      }
    }
    #pragma unroll
    for (int gi=0; gi<6; ++gi){
      int g = gh*6+gi;
      accg[gi] = fmaf(t6[gi]+kxbc, xns[g*C_+c], accg[gi]);
    }
  }
  __syncthreads();
  #pragma unroll
  for (int gi=0; gi<6; ++gi)
    aggS[gh*6+gi][c] = accg[gi] * (1.0f/16.0f);
  __syncthreads();
  #pragma unroll
  for (int gi=0; gi<6; ++gi){
    int g = gh*6+gi;
    float yv = 0.f;
    #pragma unroll
    for (int n=0;n<NG_;++n) yv = fmaf(aggS[n][c], kR[((size_t)g*NG_+n)*C_ + c], yv);
    yS[g][c] = yv * (1.0f/12.0f);
  }
  __syncthreads();
  float m6[6] = {0,0,0,0,0,0};
  for (int i4=0;i4<32;++i4){
    float w0 = mw[(i4*4+0)*C_+c], w1 = mw[(i4*4+1)*C_+c],
          w2 = mw[(i4*4+2)*C_+c], w3 = mw[(i4*4+3)*C_+c];
    #pragma unroll
    for (int gi=0;gi<6;++gi){
      int g = gh*6+gi;
      float4 yv = *(const float4*)&yS[g][i4*4];
      m6[gi] = fmaf(yv.x,w0,fmaf(yv.y,w1,fmaf(yv.z,w2,fmaf(yv.w,w3,m6[gi]))));
    }
  }
  float mbc = mb[c];
  #pragma unroll
  for (int gi=0;gi<6;++gi){
    int g = gh*6+gi;
    size_t off = (size_t)bm*(NG_*C_) + g*C_ + c;
    xout[off] = xin[off] + gelu_f(m6[gi] + mbc);
  }
}

// ---------------- K9a: parallel partial reduction ----------------
__global__ __launch_bounds__(256) void k_reduce(
    const float* __restrict__ x, float* __restrict__ part){
  int blk = blockIdx.x;
  int b = blk >> 6, ch = blk & 63;
  int tid = threadIdx.x;
  int c = tid & 127, half = tid >> 7;
  const float* xb = x + (size_t)b*(M_*NG_)*C_;
  int r0 = ch*96;
  float acc = 0.f;
  for (int r = r0 + half; r < r0 + 96; r += 2)
    acc += xb[(size_t)r*C_ + c];
  __shared__ float red[256];
  red[tid] = acc;
  __syncthreads();
  if (half == 0)
    part[(size_t)blk*C_ + c] = red[c] + red[128 + c];
}

// ---------------- K9b: final reduce + MLP head ----------------
__global__ __launch_bounds__(256) void k_head(
    const float* __restrict__ part,
    const float* __restrict__ p1w, const float* __restrict__ p1b,
    const float* __restrict__ p2w, const float* __restrict__ p2b,
    const float* __restrict__ p3w, const float* __restrict__ p3b,
    float* __restrict__ out){
  int b = blockIdx.x, tid = threadIdx.x;
  __shared__ float gs[128];
  if (tid < 128){
    float a = 0.f;
    const float* pb = part + (size_t)b*64*C_;
    for (int ch = 0; ch < 64; ++ch) a += pb[(size_t)ch*C_ + tid];
    gs[tid] = a * (1.0f/(M_*NG_));
  }
  __syncthreads();
  __shared__ float h1[256];
  {
    float a = p1b[tid];
    for (int i=0;i<128;++i) a = fmaf(gs[i], p1w[i*256+tid], a);
    h1[tid] = gelu_f(a);
  }
  __syncthreads();
  __shared__ float h2[64];
  if (tid<64){
    float a = p2b[tid];
    for (int i=0;i<256;++i) a = fmaf(h1[i], p2w[i*64+tid], a);
    h2[tid] = gelu_f(a);
  }
  __syncthreads();
  if (tid==0){
    float a = p3b[0];
    for (int i=0;i<64;++i) a = fmaf(h2[i], p3w[i], a);
    out[b] = a;
  }
}

extern "C" void kernel_launch(void* const* d_in, const int* in_sizes, int n_in,
                              void* d_out, int out_size, void* d_ws, size_t ws_size,
                              hipStream_t stream){
  const float* pos    = (const float*)d_in[0];
  const float* normal = (const float*)d_in[1];
  const float* grid   = (const float*)d_in[2];
  const float* e1w = (const float*)d_in[3];  const float* e1b = (const float*)d_in[4];
  const float* e2w = (const float*)d_in[5];  const float* e2b = (const float*)d_in[6];
  const float* dww = (const float*)d_in[7];  const float* dwb = (const float*)d_in[8];
  const float* bx_rff = (const float*)d_in[9];
  const float* bx1w = (const float*)d_in[10]; const float* bx1b = (const float*)d_in[11];
  const float* bx2w = (const float*)d_in[12]; const float* bx2b = (const float*)d_in[13];
  const float* bR_rff = (const float*)d_in[14];
  const float* bR1w = (const float*)d_in[15]; const float* bR1b = (const float*)d_in[16];
  const float* bR2w = (const float*)d_in[17]; const float* bR2b = (const float*)d_in[18];
  const float* i1kxw = (const float*)d_in[19]; const float* i1kxb = (const float*)d_in[20];
  const float* i1kRw = (const float*)d_in[21]; const float* i1kRb = (const float*)d_in[22];
  const float* i1mw  = (const float*)d_in[23]; const float* i1mb  = (const float*)d_in[24];
  const float* i2kxw = (const float*)d_in[25]; const float* i2kxb = (const float*)d_in[26];
  const float* i2kRw = (const float*)d_in[27]; const float* i2kRb = (const float*)d_in[28];
  const float* i2mw  = (const float*)d_in[29]; const float* i2mb  = (const float*)d_in[30];
  const float* p1w = (const float*)d_in[31]; const float* p1b = (const float*)d_in[32];
  const float* p2w = (const float*)d_in[33]; const float* p2b = (const float*)d_in[34];
  const float* p3w = (const float*)d_in[35]; const float* p3b = (const float*)d_in[36];
  float* out = (float*)d_out;

  float* ws = (float*)d_ws;
  size_t o = 0;
  float* x1  = ws + o; o += (size_t)B_*N_*NG_*H_;       // 6,291,456
  float* psb = ws + o; o += (size_t)B_*M_*3;            // 6,144
  float* xA  = ws + o; o += (size_t)B_*M_*NG_*C_;       // 3,145,728
  float* xB  = ws + o; o += (size_t)B_*M_*NG_*C_;       // 3,145,728
  float* kbx = ws + o; o += (size_t)B_*M_*K_*NG_*BD_;   // 25,165,824
  float* kbR = ws + o; o += (size_t)NG_*NG_*BD_;        // 9,216
  float* kRb = ws + o; o += (size_t)NG_*NG_*C_;         // 18,432
  float* part = ws + o; o += (size_t)B_*64*C_;          // 32,768
  int* nbrD  = (int*)(ws + o); o += (size_t)B_*M_*K_;   // 32,768
  int* nbrS  = (int*)(ws + o); o += (size_t)B_*M_*K_;   // 32,768
  ushort_t* w1hiT = (ushort_t*)(ws + o); o += 8192;     // 16384 ushort
  ushort_t* w1loT = (ushort_t*)(ws + o); o += 8192;
  ushort_t* w2hiT = (ushort_t*)(ws + o); o += 4096;     // 8192 ushort
  ushort_t* w2loT = (ushort_t*)(ws + o); o += 4096;

  k_lift<<<B_*N_*NG_/4, 256, 0, stream>>>(pos, normal, grid, e1w,e1b,e2w,e2b, x1);
  k_fps<<<B_, 256, 0, stream>>>(pos, psb);
  k_wsplit<<<64, 256, 0, stream>>>(bx1w, bx2w, w1hiT, w1loT, w2hiT, w2loT);
  k_knn<N_><<<B_*M_, 64, 0, stream>>>(psb, pos, nbrD);
  k_knn<M_><<<B_*M_, 64, 0, stream>>>(psb, psb, nbrS);
  k_downmax<<<B_*M_, 256, 0, stream>>>(x1, nbrD, dww, dwb, xA);
  k_kbR<<<NG_*NG_, 128, 0, stream>>>(grid, bR_rff, bR1w, bR1b, bR2w, bR2b, kbR);
  k_kbx<<<(B_*M_*K_*NG_)/128, 256, 0, stream>>>(psb, nbrS, grid, bx_rff,
      w1hiT, w1loT, w2hiT, w2loT, bx1b, bx2b, kbx);
  k_kR<<<NG_*NG_, 128, 0, stream>>>(kbR, i1kRw, i1kRb, kRb);
  k_inter<<<B_*M_, 256, 0, stream>>>(xA, nbrS, kbx, kRb, i1kxw, i1kxb, i1mw, i1mb, xB);
  k_kR<<<NG_*NG_, 128, 0, stream>>>(kbR, i2kRw, i2kRb, kRb);
  k_inter<<<B_*M_, 256, 0, stream>>>(xB, nbrS, kbx, kRb, i2kxw, i2kxb, i2mw, i2mb, xA);
  k_reduce<<<B_*64, 256, 0, stream>>>(xA, part);
  k_head<<<B_, 256, 0, stream>>>(part, p1w,p1b,p2w,p2b,p3w,p3b, out);
}

// Round 6
// 1370.719 us; speedup vs baseline: 1.0261x; 1.0261x over previous
//
#include <hip/hip_runtime.h>
#include <hip/hip_bf16.h>
#include <cfloat>

#define B_ 4
#define N_ 2048
#define NG_ 12
#define K_ 16
#define H_ 64
#define C_ 128
#define BD_ 64
#define M_ 512

typedef __attribute__((ext_vector_type(8))) short short8;
typedef __attribute__((ext_vector_type(4))) float floatx4;
typedef unsigned short ushort_t;
typedef unsigned int uint_t;

__device__ __forceinline__ float gelu_f(float x){
  float s = 0.7978845608028654f*(x + 0.044715f*x*x*x);
  float e = __expf(2.0f*s);
  float t = 1.0f - 2.0f/(e + 1.0f);
  return 0.5f*x*(1.0f + t);
}

__device__ __forceinline__ ushort_t bf16_rne(float x){
  uint_t u = __float_as_uint(x);
  uint_t r = (u + 0x7fffu + ((u >> 16) & 1u)) >> 16;
  return (ushort_t)r;
}

// DPP argmax step: combine (v,vi) with DPP partner; larger v wins, tie -> smaller vi.
#define DPP_AMAX(CTRL) { \
  int _vb = __float_as_int(v); \
  int _ov = __builtin_amdgcn_update_dpp(_vb, _vb, (CTRL), 0xF, 0xF, false); \
  int _oi = __builtin_amdgcn_update_dpp(vi, vi, (CTRL), 0xF, 0xF, false); \
  float _of = __int_as_float(_ov); \
  bool _tk = (_of > v) || (_of == v && _oi < vi); \
  v = _tk ? _of : v; vi = _tk ? _oi : vi; }

// DPP argmin step: smaller v wins, tie -> smaller vi.
#define DPP_AMIN(CTRL) { \
  int _vb = __float_as_int(v); \
  int _ov = __builtin_amdgcn_update_dpp(_vb, _vb, (CTRL), 0xF, 0xF, false); \
  int _oi = __builtin_amdgcn_update_dpp(vi, vi, (CTRL), 0xF, 0xF, false); \
  float _of = __int_as_float(_ov); \
  bool _tk = (_of < v) || (_of == v && _oi < vi); \
  v = _tk ? _of : v; vi = _tk ? _oi : vi; }

// ---------------- K1: lift + embed -> x1 [B,N,NG,H] ----------------
__global__ __launch_bounds__(256) void k_lift(
    const float* __restrict__ pos, const float* __restrict__ normal,
    const float* __restrict__ grid,
    const float* __restrict__ e1w, const float* __restrict__ e1b,
    const float* __restrict__ e2w, const float* __restrict__ e2b,
    float* __restrict__ x1){
  int tid = threadIdx.x;
  int q = tid>>6, lane = tid&63;
  int fid = blockIdx.x*4 + q;
  int g = fid % NG_;
  int n = (fid / NG_) % N_;
  int b = fid / (NG_*N_);
  const float* nm = normal + (size_t)(b*N_+n)*3;
  const float* pp = pos + (size_t)(b*N_+n)*3;
  const float* gg = grid + g*3;
  float f0 = nm[0]*gg[0] + nm[1]*gg[1] + nm[2]*gg[2];
  float t = e1b[lane] + f0*e1w[lane] + pp[0]*e1w[64+lane] + pp[1]*e1w[128+lane] + pp[2]*e1w[192+lane];
  __shared__ float ts[4][64];
  ts[q][lane] = gelu_f(t);
  __syncthreads();
  float acc = e2b[lane];
  #pragma unroll
  for (int i=0;i<64;++i) acc = fmaf(ts[q][i], e2w[i*64+lane], acc);
  x1[(size_t)fid*64 + lane] = acc;
}

// ---------------- K2: farthest point sampling, single wave, no barriers ----------------
__global__ __launch_bounds__(64) void k_fps(const float* __restrict__ pos, float* __restrict__ ps){
  int b = blockIdx.x, lane = threadIdx.x;
  __shared__ float4 posS4[N_];
  for (int i=lane;i<N_;i+=64){
    const float* p = pos + (size_t)b*N_*3 + (size_t)i*3;
    posS4[i] = make_float4(p[0], p[1], p[2], 0.f);
  }
  __syncthreads();
  float px[32],py[32],pz[32],d[32];
  #pragma unroll
  for (int j=0;j<32;++j){
    float4 pt = posS4[lane + 64*j];
    px[j]=pt.x; py[j]=pt.y; pz[j]=pt.z;
    d[j]=1e10f;
  }
  int last = 0;
  for (int s=0;s<M_;++s){
    float4 lp = posS4[last];
    float lx=lp.x, ly=lp.y, lz=lp.z;
    if (lane==0){ float* o = ps + ((size_t)b*M_+s)*3; o[0]=lx;o[1]=ly;o[2]=lz; }
    if (s==M_-1) break;
    // update distances; 4 parallel argmax chains (tie -> smaller global index)
    float v0=-1.f,v1=-1.f,v2=-1.f,v3=-1.f;
    int i0=0x7fffffff,i1=0x7fffffff,i2=0x7fffffff,i3=0x7fffffff;
    #pragma unroll
    for (int j=0;j<32;j+=4){
      {
        float dx=__fsub_rn(px[j],lx), dy=__fsub_rn(py[j],ly), dz=__fsub_rn(pz[j],lz);
        float dist=__fadd_rn(__fadd_rn(__fmul_rn(dx,dx),__fmul_rn(dy,dy)),__fmul_rn(dz,dz));
        float dn=fminf(d[j],dist); d[j]=dn;
        if (dn>v0){ v0=dn; i0=lane+64*j; }
      }
      {
        float dx=__fsub_rn(px[j+1],lx), dy=__fsub_rn(py[j+1],ly), dz=__fsub_rn(pz[j+1],lz);
        float dist=__fadd_rn(__fadd_rn(__fmul_rn(dx,dx),__fmul_rn(dy,dy)),__fmul_rn(dz,dz));
        float dn=fminf(d[j+1],dist); d[j+1]=dn;
        if (dn>v1){ v1=dn; i1=lane+64*(j+1); }
      }
      {
        float dx=__fsub_rn(px[j+2],lx), dy=__fsub_rn(py[j+2],ly), dz=__fsub_rn(pz[j+2],lz);
        float dist=__fadd_rn(__fadd_rn(__fmul_rn(dx,dx),__fmul_rn(dy,dy)),__fmul_rn(dz,dz));
        float dn=fminf(d[j+2],dist); d[j+2]=dn;
        if (dn>v2){ v2=dn; i2=lane+64*(j+2); }
      }
      {
        float dx=__fsub_rn(px[j+3],lx), dy=__fsub_rn(py[j+3],ly), dz=__fsub_rn(pz[j+3],lz);
        float dist=__fadd_rn(__fadd_rn(__fmul_rn(dx,dx),__fmul_rn(dy,dy)),__fmul_rn(dz,dz));
        float dn=fminf(d[j+3],dist); d[j+3]=dn;
        if (dn>v3){ v3=dn; i3=lane+64*(j+3); }
      }
    }
    // merge chains (comparator is associative: max, tie -> smaller index)
    bool t01 = (v1>v0) || (v1==v0 && i1<i0); float va=t01?v1:v0; int ia=t01?i1:i0;
    bool t23 = (v3>v2) || (v3==v2 && i3<i2); float vb=t23?v3:v2; int ib=t23?i3:i2;
    bool tab = (vb>va) || (vb==va && ib<ia); float v=tab?vb:va;  int vi=tab?ib:ia;
    // in-wave DPP argmax -> lane 63
    DPP_AMAX(0x121); DPP_AMAX(0x122); DPP_AMAX(0x124); DPP_AMAX(0x128);
    DPP_AMAX(0x142); DPP_AMAX(0x143);
    last = __builtin_amdgcn_readlane(vi, 63);
  }
}

// ---------------- K3: exact KNN (k smallest d2, stable ties), serial scan + DPP ----------------
template<int NP>
__global__ __launch_bounds__(64) void k_knn(const float* __restrict__ qp, const float* __restrict__ pool,
                                            int* __restrict__ out){
  constexpr int R = NP/64;
  int lane = threadIdx.x;
  int qm = blockIdx.x;            // b*M + m
  int b = qm / M_;
  const float* q = qp + (size_t)qm*3;
  float qx=q[0], qy=q[1], qz=q[2];
  float d2[R];
  #pragma unroll
  for (int j=0;j<R;++j){
    int n = lane + 64*j;
    const float* p = pool + ((size_t)b*NP + n)*3;
    float dx=__fsub_rn(qx,p[0]), dy=__fsub_rn(qy,p[1]), dz=__fsub_rn(qz,p[2]);
    d2[j]=__fadd_rn(__fadd_rn(__fmul_rn(dx,dx),__fmul_rn(dy,dy)),__fmul_rn(dz,dz));
  }
  for (int r=0;r<K_;++r){
    float v=FLT_MAX; int vi=0x7fffffff;
    #pragma unroll
    for (int j=0;j<R;++j){
      if (d2[j]<v){ v=d2[j]; vi=lane+64*j; }   // strict < : earlier j (smaller idx) kept
    }
    DPP_AMIN(0x121); DPP_AMIN(0x122); DPP_AMIN(0x124); DPP_AMIN(0x128);
    DPP_AMIN(0x142); DPP_AMIN(0x143);
    int si = __builtin_amdgcn_readlane(vi, 63);
    if (lane==0) out[(size_t)qm*K_ + r] = si;
    #pragma unroll
    for (int j=0;j<R;++j){ if (si == lane + 64*j) d2[j] = FLT_MAX; }
  }
}

// ---------------- K4: fused down-proj + relu + neighbor-max -> xA [B,M,NG,C] ----------------
__global__ __launch_bounds__(256) void k_downmax(
    const float* __restrict__ x1, const int* __restrict__ nbrD,
    const float* __restrict__ dw, const float* __restrict__ db,
    float* __restrict__ xA){
  int bm = blockIdx.x; int b = bm / M_;
  int tid = threadIdx.x;
  __shared__ int nb[K_];
  __shared__ float xs[K_][NG_*H_];     // 48 KB
  if (tid<K_) nb[tid] = nbrD[(size_t)bm*K_ + tid];
  __syncthreads();
  for (int idx=tid; idx<K_*NG_*H_/4; idx+=256){
    int k = idx / (NG_*H_/4), r = idx % (NG_*H_/4);
    ((float4*)&xs[k][0])[r] = ((const float4*)&x1[((size_t)(b*N_) + nb[k])*(NG_*H_)])[r];
  }
  __syncthreads();
  int c = tid & 127, gh = tid >> 7;
  float dbc = db[c];
  for (int gi=0; gi<6; ++gi){
    int g = gh*6 + gi;
    float acc[K_];
    #pragma unroll
    for (int k=0;k<K_;++k) acc[k]=dbc;
    for (int i4=0;i4<16;++i4){
      float w0 = dw[(i4*4+0)*C_ + c];
      float w1 = dw[(i4*4+1)*C_ + c];
      float w2 = dw[(i4*4+2)*C_ + c];
      float w3 = dw[(i4*4+3)*C_ + c];
      #pragma unroll
      for (int k=0;k<K_;++k){
        float4 xv = *(const float4*)&xs[k][g*H_ + i4*4];
        acc[k] = fmaf(xv.x,w0,fmaf(xv.y,w1,fmaf(xv.z,w2,fmaf(xv.w,w3,acc[k]))));
      }
    }
    float best = acc[0];
    #pragma unroll
    for (int k=1;k<K_;++k) best = fmaxf(best, acc[k]);
    xA[(size_t)bm*(NG_*C_) + g*C_ + c] = fmaxf(best, 0.0f);
  }
}

// ---------------- K5: kbR basis MLP [NG,NG,BD] ----------------
__global__ __launch_bounds__(128) void k_kbR(
    const float* __restrict__ grid, const float* __restrict__ rff,
    const float* __restrict__ w1, const float* __restrict__ b1,
    const float* __restrict__ w2, const float* __restrict__ b2,
    float* __restrict__ kbR){
  int gm = blockIdx.x / NG_, gn = blockIdx.x % NG_;
  int j = threadIdx.x;
  float z = grid[gm*3]*grid[gn*3] + grid[gm*3+1]*grid[gn*3+1] + grid[gm*3+2]*grid[gn*3+2];
  __shared__ float fs[128], hs[128];
  int jj = j & 63;
  float ang = 6.283185307179586f * (z * rff[jj]);
  fs[j] = (j<64) ? sinf(ang) : cosf(ang);
  __syncthreads();
  float acc = b1[j];
  for (int i=0;i<128;++i) acc = fmaf(fs[i], w1[i*128+j], acc);
  hs[j] = gelu_f(acc);
  __syncthreads();
  if (j < 64){
    float a2 = b2[j];
    for (int i=0;i<128;++i) a2 = fmaf(hs[i], w2[i*64+j], a2);
    kbR[(size_t)blockIdx.x*64 + j] = gelu_f(a2);
  }
}

// ---------------- K6: kR = kbR @ kR_w + b  [NG,NG,C] ----------------
__global__ __launch_bounds__(128) void k_kR(
    const float* __restrict__ kbR, const float* __restrict__ kRw, const float* __restrict__ kRb,
    float* __restrict__ kR){
  int pair = blockIdx.x; int c = threadIdx.x;
  __shared__ float kb[64];
  if (c<64) kb[c] = kbR[(size_t)pair*64 + c];
  __syncthreads();
  float acc = kRb[c];
  for (int d=0;d<64;++d) acc = fmaf(kb[d], kRw[d*128+c], acc);
  kR[(size_t)pair*128 + c] = acc;
}

// ---------------- K6b: split weights into transposed bf16 hi/lo ----------------
__global__ __launch_bounds__(256) void k_wsplit(
    const float* __restrict__ w1, const float* __restrict__ w2,
    ushort_t* __restrict__ w1hiT, ushort_t* __restrict__ w1loT,
    ushort_t* __restrict__ w2hiT, ushort_t* __restrict__ w2loT){
  int tid = blockIdx.x*256 + threadIdx.x;
  if (tid < 16384){
    int j = tid >> 7, k = tid & 127;
    float x = w1[k*128 + j];
    ushort_t hi = bf16_rne(x);
    float hif = __uint_as_float(((uint_t)hi)<<16);
    ushort_t lo = bf16_rne(x - hif);
    w1hiT[tid] = hi; w1loT[tid] = lo;
  }
  if (tid < 8192){
    int c = tid >> 7, j = tid & 127;
    float x = w2[j*64 + c];
    ushort_t hi = bf16_rne(x);
    float hif = __uint_as_float(((uint_t)hi)<<16);
    ushort_t lo = bf16_rne(x - hif);
    w2hiT[tid] = hi; w2loT[tid] = lo;
  }
}

// ---------------- K7: kbx basis MLP via MFMA bf16 x3 (hi/lo split) ----------------
__global__ __launch_bounds__(256) void k_kbx(
    const float* __restrict__ ps, const int* __restrict__ nbr,
    const float* __restrict__ grid, const float* __restrict__ rff,
    const ushort_t* __restrict__ w1hiT, const ushort_t* __restrict__ w1loT,
    const ushort_t* __restrict__ w2hiT, const ushort_t* __restrict__ w2loT,
    const float* __restrict__ b1, const float* __restrict__ b2,
    float* __restrict__ kbx){
  __shared__ float z0s[128], z1s[128], rws[128];
  __shared__ float bounce[4][32*34];
  int tid = threadIdx.x;
  if (tid < 128){
    rws[tid] = rff[tid];
    int fid = blockIdx.x*128 + tid;
    int g = fid % NG_;
    int k = (fid/NG_) % K_;
    int bm = fid / (NG_*K_);
    int b = bm / M_;
    int nb = nbr[(size_t)bm*K_ + k];
    const float* pm = ps + (size_t)bm*3;
    const float* pn = ps + ((size_t)(b*M_) + nb)*3;
    float rx = pn[0]-pm[0], ry = pn[1]-pm[1], rz3 = pn[2]-pm[2];
    const float* gg = grid + g*3;
    float rz = rx*gg[0] + ry*gg[1] + rz3*gg[2];
    float vx = rx - rz*gg[0], vy = ry - rz*gg[1], vz = rz3 - rz*gg[2];
    float rxy = sqrtf(vx*vx + vy*vy + vz*vz + 1e-12f);
    z0s[tid]=rxy; z1s[tid]=rz;
  }
  __syncthreads();
  int wid = tid>>6, lane = tid&63;
  int ln = lane & 15, g = lane >> 4;

  short8 ahi[2][4], alo[2][4];
  #pragma unroll
  for (int rt=0; rt<2; ++rt){
    float z0 = z0s[wid*32 + rt*16 + ln];
    float z1 = z1s[wid*32 + rt*16 + ln];
    #pragma unroll
    for (int ks=0; ks<4; ++ks){
      #pragma unroll
      for (int e=0; e<8; ++e){
        int kd = ks*32 + g*8 + e;
        int kk = kd & 63;
        float t = z0*rws[kk] + z1*rws[64+kk];
        t = t - floorf(t);
        float v = (ks < 2) ? __builtin_amdgcn_sinf(t) : __builtin_amdgcn_cosf(t);
        ushort_t hi = bf16_rne(v);
        float hif = __uint_as_float(((uint_t)hi)<<16);
        ushort_t lo = bf16_rne(v - hif);
        ahi[rt][ks][e] = (short)hi;
        alo[rt][ks][e] = (short)lo;
      }
    }
  }

  floatx4 acc2[2][4];
  #pragma unroll
  for (int rt=0; rt<2; ++rt)
    #pragma unroll
    for (int ct=0; ct<4; ++ct)
      acc2[rt][ct] = (floatx4){0.f,0.f,0.f,0.f};

  float* bw = &bounce[wid][0];

  #pragma unroll
  for (int jp=0; jp<4; ++jp){
    floatx4 acc1[2][2];
    #pragma unroll
    for (int rt=0; rt<2; ++rt)
      #pragma unroll
      for (int jt=0; jt<2; ++jt)
        acc1[rt][jt] = (floatx4){0.f,0.f,0.f,0.f};
    #pragma unroll
    for (int ks=0; ks<4; ++ks){
      #pragma unroll
      for (int jt=0; jt<2; ++jt){
        int j = jp*32 + jt*16 + ln;
        short8 bhi = *(const short8*)&w1hiT[(size_t)j*128 + ks*32 + g*8];
        short8 blo = *(const short8*)&w1loT[(size_t)j*128 + ks*32 + g*8];
        #pragma unroll
        for (int rt=0; rt<2; ++rt){
          acc1[rt][jt] = __builtin_amdgcn_mfma_f32_16x16x32_bf16(ahi[rt][ks], bhi, acc1[rt][jt], 0,0,0);
          acc1[rt][jt] = __builtin_amdgcn_mfma_f32_16x16x32_bf16(alo[rt][ks], bhi, acc1[rt][jt], 0,0,0);
          acc1[rt][jt] = __builtin_amdgcn_mfma_f32_16x16x32_bf16(ahi[rt][ks], blo, acc1[rt][jt], 0,0,0);
        }
      }
    }
    #pragma unroll
    for (int jt=0; jt<2; ++jt){
      float bb = b1[jp*32 + jt*16 + ln];
      #pragma unroll
      for (int rt=0; rt<2; ++rt)
        #pragma unroll
        for (int i=0; i<4; ++i)
          bw[(rt*16 + g*4 + i)*34 + jt*16 + ln] = gelu_f(bb + acc1[rt][jt][i]);
    }
    #pragma unroll
    for (int rt=0; rt<2; ++rt){
      int base = (rt*16 + ln)*34 + g*8;
      float2 p0 = *(float2*)&bw[base+0];
      float2 p1 = *(float2*)&bw[base+2];
      float2 p2 = *(float2*)&bw[base+4];
      float2 p3 = *(float2*)&bw[base+6];
      float hv[8] = {p0.x,p0.y,p1.x,p1.y,p2.x,p2.y,p3.x,p3.y};
      short8 a2h, a2l;
      #pragma unroll
      for (int e=0; e<8; ++e){
        ushort_t hi = bf16_rne(hv[e]);
        float hif = __uint_as_float(((uint_t)hi)<<16);
        ushort_t lo = bf16_rne(hv[e] - hif);
        a2h[e] = (short)hi;
        a2l[e] = (short)lo;
      }
      #pragma unroll
      for (int ct=0; ct<4; ++ct){
        short8 b2h = *(const short8*)&w2hiT[(size_t)(ct*16+ln)*128 + jp*32 + g*8];
        short8 b2l = *(const short8*)&w2loT[(size_t)(ct*16+ln)*128 + jp*32 + g*8];
        acc2[rt][ct] = __builtin_amdgcn_mfma_f32_16x16x32_bf16(a2h, b2h, acc2[rt][ct], 0,0,0);
        acc2[rt][ct] = __builtin_amdgcn_mfma_f32_16x16x32_bf16(a2l, b2h, acc2[rt][ct], 0,0,0);
        acc2[rt][ct] = __builtin_amdgcn_mfma_f32_16x16x32_bf16(a2h, b2l, acc2[rt][ct], 0,0,0);
      }
    }
  }
  #pragma unroll
  for (int ct=0; ct<4; ++ct){
    float bb = b2[ct*16 + ln];
    #pragma unroll
    for (int rt=0; rt<2; ++rt)
      #pragma unroll
      for (int i=0; i<4; ++i){
        int row = wid*32 + rt*16 + g*4 + i;
        size_t fiber = (size_t)blockIdx.x*128 + row;
        kbx[fiber*64 + ct*16 + ln] = gelu_f(bb + acc2[rt][ct][i]);
      }
  }
}

// ---------------- K8: interaction layer ----------------
__global__ __launch_bounds__(256) void k_inter(
    const float* __restrict__ xin, const int* __restrict__ nbr,
    const float* __restrict__ kbx, const float* __restrict__ kR,
    const float* __restrict__ kxw, const float* __restrict__ kxb,
    const float* __restrict__ mw, const float* __restrict__ mb,
    float* __restrict__ xout){
  int bm = blockIdx.x; int b = bm / M_;
  int tid = threadIdx.x;
  int c = tid & 127, gh = tid >> 7;
  __shared__ float kbs[NG_*BD_];    // 3 KB
  __shared__ float xns[NG_*C_];     // 6 KB
  __shared__ float aggS[NG_][C_];   // 6 KB
  __shared__ float yS[NG_][C_];     // 6 KB
  float wreg[64];
  #pragma unroll
  for (int d=0; d<64; ++d) wreg[d] = kxw[d*C_ + c];
  float accg[6] = {0,0,0,0,0,0};
  float kxbc = kxb[c];
  for (int k=0;k<K_;++k){
    int nb = nbr[(size_t)bm*K_ + k];
    __syncthreads();
    {
      const float4* src = (const float4*)&kbx[((size_t)bm*K_ + k)*(NG_*BD_)];
      for (int idx=tid; idx<NG_*BD_/4; idx+=256) ((float4*)kbs)[idx] = src[idx];
      const float4* src2 = (const float4*)&xin[((size_t)(b*M_) + nb)*(NG_*C_)];
      for (int idx=tid; idx<NG_*C_/4; idx+=256) ((float4*)xns)[idx] = src2[idx];
    }
    __syncthreads();
    float t6[6] = {0,0,0,0,0,0};
    #pragma unroll
    for (int d4=0; d4<16; ++d4){
      #pragma unroll
      for (int gi=0; gi<6; ++gi){
        int g = gh*6+gi;
        float4 kv = *(const float4*)&kbs[g*BD_ + d4*4];
        t6[gi] = fmaf(kv.x,wreg[d4*4+0],fmaf(kv.y,wreg[d4*4+1],fmaf(kv.z,wreg[d4*4+2],fmaf(kv.w,wreg[d4*4+3],t6[gi]))));
      }
    }
    #pragma unroll
    for (int gi=0; gi<6; ++gi){
      int g = gh*6+gi;
      accg[gi] = fmaf(t6[gi]+kxbc, xns[g*C_+c], accg[gi]);
    }
  }
  __syncthreads();
  #pragma unroll
  for (int gi=0; gi<6; ++gi)
    aggS[gh*6+gi][c] = accg[gi] * (1.0f/16.0f);
  __syncthreads();
  #pragma unroll
  for (int gi=0; gi<6; ++gi){
    int g = gh*6+gi;
    float yv = 0.f;
    #pragma unroll
    for (int n=0;n<NG_;++n) yv = fmaf(aggS[n][c], kR[((size_t)g*NG_+n)*C_ + c], yv);
    yS[g][c] = yv * (1.0f/12.0f);
  }
  __syncthreads();
  float m6[6] = {0,0,0,0,0,0};
  for (int i4=0;i4<32;++i4){
    float w0 = mw[(i4*4+0)*C_+c], w1 = mw[(i4*4+1)*C_+c],
          w2 = mw[(i4*4+2)*C_+c], w3 = mw[(i4*4+3)*C_+c];
    #pragma unroll
    for (int gi=0;gi<6;++gi){
      int g = gh*6+gi;
      float4 yv = *(const float4*)&yS[g][i4*4];
      m6[gi] = fmaf(yv.x,w0,fmaf(yv.y,w1,fmaf(yv.z,w2,fmaf(yv.w,w3,m6[gi]))));
    }
  }
  float mbc = mb[c];
  #pragma unroll
  for (int gi=0;gi<6;++gi){
    int g = gh*6+gi;
    size_t off = (size_t)bm*(NG_*C_) + g*C_ + c;
    xout[off] = xin[off] + gelu_f(m6[gi] + mbc);
  }
}

// ---------------- K9a: parallel partial reduction ----------------
__global__ __launch_bounds__(256) void k_reduce(
    const float* __restrict__ x, float* __restrict__ part){
  int blk = blockIdx.x;
  int b = blk >> 6, ch = blk & 63;
  int tid = threadIdx.x;
  int c = tid & 127, half = tid >> 7;
  const float* xb = x + (size_t)b*(M_*NG_)*C_;
  int r0 = ch*96;
  float acc = 0.f;
  for (int r = r0 + half; r < r0 + 96; r += 2)
    acc += xb[(size_t)r*C_ + c];
  __shared__ float red[256];
  red[tid] = acc;
  __syncthreads();
  if (half == 0)
    part[(size_t)blk*C_ + c] = red[c] + red[128 + c];
}

// ---------------- K9b: final reduce + MLP head ----------------
__global__ __launch_bounds__(256) void k_head(
    const float* __restrict__ part,
    const float* __restrict__ p1w, const float* __restrict__ p1b,
    const float* __restrict__ p2w, const float* __restrict__ p2b,
    const float* __restrict__ p3w, const float* __restrict__ p3b,
    float* __restrict__ out){
  int b = blockIdx.x, tid = threadIdx.x;
  __shared__ float gs[128];
  if (tid < 128){
    float a = 0.f;
    const float* pb = part + (size_t)b*64*C_;
    for (int ch = 0; ch < 64; ++ch) a += pb[(size_t)ch*C_ + tid];
    gs[tid] = a * (1.0f/(M_*NG_));
  }
  __syncthreads();
  __shared__ float h1[256];
  {
    float a = p1b[tid];
    for (int i=0;i<128;++i) a = fmaf(gs[i], p1w[i*256+tid], a);
    h1[tid] = gelu_f(a);
  }
  __syncthreads();
  __shared__ float h2[64];
  if (tid<64){
    float a = p2b[tid];
    for (int i=0;i<256;++i) a = fmaf(h1[i], p2w[i*64+tid], a);
    h2[tid] = gelu_f(a);
  }
  __syncthreads();
  if (tid==0){
    float a = p3b[0];
    for (int i=0;i<64;++i) a = fmaf(h2[i], p3w[i], a);
    out[b] = a;
  }
}

extern "C" void kernel_launch(void* const* d_in, const int* in_sizes, int n_in,
                              void* d_out, int out_size, void* d_ws, size_t ws_size,
                              hipStream_t stream){
  const float* pos    = (const float*)d_in[0];
  const float* normal = (const float*)d_in[1];
  const float* grid   = (const float*)d_in[2];
  const float* e1w = (const float*)d_in[3];  const float* e1b = (const float*)d_in[4];
  const float* e2w = (const float*)d_in[5];  const float* e2b = (const float*)d_in[6];
  const float* dww = (const float*)d_in[7];  const float* dwb = (const float*)d_in[8];
  const float* bx_rff = (const float*)d_in[9];
  const float* bx1w = (const float*)d_in[10]; const float* bx1b = (const float*)d_in[11];
  const float* bx2w = (const float*)d_in[12]; const float* bx2b = (const float*)d_in[13];
  const float* bR_rff = (const float*)d_in[14];
  const float* bR1w = (const float*)d_in[15]; const float* bR1b = (const float*)d_in[16];
  const float* bR2w = (const float*)d_in[17]; const float* bR2b = (const float*)d_in[18];
  const float* i1kxw = (const float*)d_in[19]; const float* i1kxb = (const float*)d_in[20];
  const float* i1kRw = (const float*)d_in[21]; const float* i1kRb = (const float*)d_in[22];
  const float* i1mw  = (const float*)d_in[23]; const float* i1mb  = (const float*)d_in[24];
  const float* i2kxw = (const float*)d_in[25]; const float* i2kxb = (const float*)d_in[26];
  const float* i2kRw = (const float*)d_in[27]; const float* i2kRb = (const float*)d_in[28];
  const float* i2mw  = (const float*)d_in[29]; const float* i2mb  = (const float*)d_in[30];
  const float* p1w = (const float*)d_in[31]; const float* p1b = (const float*)d_in[32];
  const float* p2w = (const float*)d_in[33]; const float* p2b = (const float*)d_in[34];
  const float* p3w = (const float*)d_in[35]; const float* p3b = (const float*)d_in[36];
  float* out = (float*)d_out;

  float* ws = (float*)d_ws;
  size_t o = 0;
  float* x1  = ws + o; o += (size_t)B_*N_*NG_*H_;       // 6,291,456
  float* psb = ws + o; o += (size_t)B_*M_*3;            // 6,144
  float* xA  = ws + o; o += (size_t)B_*M_*NG_*C_;       // 3,145,728
  float* xB  = ws + o; o += (size_t)B_*M_*NG_*C_;       // 3,145,728
  float* kbx = ws + o; o += (size_t)B_*M_*K_*NG_*BD_;   // 25,165,824
  float* kbR = ws + o; o += (size_t)NG_*NG_*BD_;        // 9,216
  float* kRb = ws + o; o += (size_t)NG_*NG_*C_;         // 18,432
  float* part = ws + o; o += (size_t)B_*64*C_;          // 32,768
  int* nbrD  = (int*)(ws + o); o += (size_t)B_*M_*K_;   // 32,768
  int* nbrS  = (int*)(ws + o); o += (size_t)B_*M_*K_;   // 32,768
  ushort_t* w1hiT = (ushort_t*)(ws + o); o += 8192;     // 16384 ushort
  ushort_t* w1loT = (ushort_t*)(ws + o); o += 8192;
  ushort_t* w2hiT = (ushort_t*)(ws + o); o += 4096;     // 8192 ushort
  ushort_t* w2loT = (ushort_t*)(ws + o); o += 4096;

  k_lift<<<B_*N_*NG_/4, 256, 0, stream>>>(pos, normal, grid, e1w,e1b,e2w,e2b, x1);
  k_fps<<<B_, 64, 0, stream>>>(pos, psb);
  k_wsplit<<<64, 256, 0, stream>>>(bx1w, bx2w, w1hiT, w1loT, w2hiT, w2loT);
  k_knn<N_><<<B_*M_, 64, 0, stream>>>(psb, pos, nbrD);
  k_knn<M_><<<B_*M_, 64, 0, stream>>>(psb, psb, nbrS);
  k_downmax<<<B_*M_, 256, 0, stream>>>(x1, nbrD, dww, dwb, xA);
  k_kbR<<<NG_*NG_, 128, 0, stream>>>(grid, bR_rff, bR1w, bR1b, bR2w, bR2b, kbR);
  k_kbx<<<(B_*M_*K_*NG_)/128, 256, 0, stream>>>(psb, nbrS, grid, bx_rff,
      w1hiT, w1loT, w2hiT, w2loT, bx1b, bx2b, kbx);
  k_kR<<<NG_*NG_, 128, 0, stream>>>(kbR, i1kRw, i1kRb, kRb);
  k_inter<<<B_*M_, 256, 0, stream>>>(xA, nbrS, kbx, kRb, i1kxw, i1kxb, i1mw, i1mb, xB);
  k_kR<<<NG_*NG_, 128, 0, stream>>>(kbR, i2kRw, i2kRb, kRb);
  k_inter<<<B_*M_, 256, 0, stream>>>(xB, nbrS, kbx, kRb, i2kxw, i2kxb, i2mw, i2mb, xA);
  k_reduce<<<B_*64, 256, 0, stream>>>(xA, part);
  k_head<<<B_, 256, 0, stream>>>(part, p1w,p1b,p2w,p2b,p3w,p3b, out);
}

// Round 7
// 974.991 us; speedup vs baseline: 1.4426x; 1.4059x over previous
//
#include <hip/hip_runtime.h>
#include <hip/hip_bf16.h>
#include <cfloat>

#define B_ 4
#define N_ 2048
#define NG_ 12
#define K_ 16
#define H_ 64
#define C_ 128
#define BD_ 64
#define M_ 512

typedef __attribute__((ext_vector_type(8))) short short8;
typedef __attribute__((ext_vector_type(4))) float floatx4;
typedef unsigned short ushort_t;
typedef unsigned int uint_t;

__device__ __forceinline__ float gelu_f(float x){
  float s = 0.7978845608028654f*(x + 0.044715f*x*x*x);
  float e = __expf(2.0f*s);
  float t = 1.0f - 2.0f/(e + 1.0f);
  return 0.5f*x*(1.0f + t);
}

__device__ __forceinline__ ushort_t bf16_rne(float x){
  uint_t u = __float_as_uint(x);
  uint_t r = (u + 0x7fffu + ((u >> 16) & 1u)) >> 16;
  return (ushort_t)r;
}

#define DPP_AMAX(CTRL) { \
  int _vb = __float_as_int(v); \
  int _ov = __builtin_amdgcn_update_dpp(_vb, _vb, (CTRL), 0xF, 0xF, false); \
  int _oi = __builtin_amdgcn_update_dpp(vi, vi, (CTRL), 0xF, 0xF, false); \
  float _of = __int_as_float(_ov); \
  bool _tk = (_of > v) || (_of == v && _oi < vi); \
  v = _tk ? _of : v; vi = _tk ? _oi : vi; }

#define DPP_AMIN(CTRL) { \
  int _vb = __float_as_int(v); \
  int _ov = __builtin_amdgcn_update_dpp(_vb, _vb, (CTRL), 0xF, 0xF, false); \
  int _oi = __builtin_amdgcn_update_dpp(vi, vi, (CTRL), 0xF, 0xF, false); \
  float _of = __int_as_float(_ov); \
  bool _tk = (_of < v) || (_of == v && _oi < vi); \
  v = _tk ? _of : v; vi = _tk ? _oi : vi; }

// ---------------- K1: lift + embed -> x1 [B,N,NG,H] ----------------
__global__ __launch_bounds__(256) void k_lift(
    const float* __restrict__ pos, const float* __restrict__ normal,
    const float* __restrict__ grid,
    const float* __restrict__ e1w, const float* __restrict__ e1b,
    const float* __restrict__ e2w, const float* __restrict__ e2b,
    float* __restrict__ x1){
  int tid = threadIdx.x;
  int q = tid>>6, lane = tid&63;
  int fid = blockIdx.x*4 + q;
  int g = fid % NG_;
  int n = (fid / NG_) % N_;
  int b = fid / (NG_*N_);
  const float* nm = normal + (size_t)(b*N_+n)*3;
  const float* pp = pos + (size_t)(b*N_+n)*3;
  const float* gg = grid + g*3;
  float f0 = nm[0]*gg[0] + nm[1]*gg[1] + nm[2]*gg[2];
  float t = e1b[lane] + f0*e1w[lane] + pp[0]*e1w[64+lane] + pp[1]*e1w[128+lane] + pp[2]*e1w[192+lane];
  __shared__ float ts[4][64];
  ts[q][lane] = gelu_f(t);
  __syncthreads();
  float acc = e2b[lane];
  #pragma unroll
  for (int i=0;i<64;++i) acc = fmaf(ts[q][i], e2w[i*64+lane], acc);
  x1[(size_t)fid*64 + lane] = acc;
}

// ---------------- K2: FPS, 4 waves, DPP + coords-through-slot ----------------
__global__ __launch_bounds__(256) void k_fps(const float* __restrict__ pos, float* __restrict__ ps){
  int b = blockIdx.x, tid = threadIdx.x;
  __shared__ float4 posS4[N_];
  __shared__ float4 wred4[2][4];
  __shared__ int    wredi[2][4];
  for (int i=tid;i<N_;i+=256){
    const float* p = pos + (size_t)b*N_*3 + (size_t)i*3;
    posS4[i] = make_float4(p[0], p[1], p[2], 0.f);
  }
  __syncthreads();
  float px[8],py[8],pz[8],d[8];
  #pragma unroll
  for (int j=0;j<8;++j){
    float4 pt = posS4[tid + 256*j];
    px[j]=pt.x; py[j]=pt.y; pz[j]=pt.z;
    d[j]=1e10f;
  }
  int wave = tid>>6, lane = tid&63;
  float4 cur = posS4[0];
  for (int s=0;s<M_;++s){
    float lx=cur.x, ly=cur.y, lz=cur.z;
    if (tid==0){ float* o = ps + ((size_t)b*M_+s)*3; o[0]=lx;o[1]=ly;o[2]=lz; }
    #pragma unroll
    for (int j=0;j<8;++j){
      float dx=__fsub_rn(px[j],lx), dy=__fsub_rn(py[j],ly), dz=__fsub_rn(pz[j],lz);
      float dist=__fadd_rn(__fadd_rn(__fmul_rn(dx,dx),__fmul_rn(dy,dy)),__fmul_rn(dz,dz));
      d[j]=fminf(d[j],dist);
    }
    if (s==M_-1) break;
    // local argmax over 8 (depth-3 tree, ties -> lower j = lower global index)
    float va = d[1]>d[0]?d[1]:d[0]; int ja = d[1]>d[0]?1:0;
    float vb = d[3]>d[2]?d[3]:d[2]; int jb = d[3]>d[2]?3:2;
    float vc = d[5]>d[4]?d[5]:d[4]; int jc = d[5]>d[4]?5:4;
    float vd = d[7]>d[6]?d[7]:d[6]; int jd = d[7]>d[6]?7:6;
    float ve = vb>va?vb:va; int je = vb>va?jb:ja;
    float vf = vd>vc?vd:vc; int jf = vd>vc?jd:jc;
    float v  = vf>ve?vf:ve; int jj = vf>ve?jf:je;
    int vi = tid + (jj<<8);
    DPP_AMAX(0x121); DPP_AMAX(0x122); DPP_AMAX(0x124); DPP_AMAX(0x128);
    DPP_AMAX(0x142); DPP_AMAX(0x143);
    if (lane==63){
      float4 cp = posS4[vi];
      cp.w = v;
      wred4[s&1][wave] = cp;
      wredi[s&1][wave] = vi;
    }
    __syncthreads();
    float4 r0 = wred4[s&1][0], r1 = wred4[s&1][1], r2 = wred4[s&1][2], r3 = wred4[s&1][3];
    int j0 = wredi[s&1][0], j1 = wredi[s&1][1], j2 = wredi[s&1][2], j3 = wredi[s&1][3];
    float4 bw = r0; int bi = j0;
    if (r1.w>bw.w || (r1.w==bw.w && j1<bi)){ bw=r1; bi=j1; }
    if (r2.w>bw.w || (r2.w==bw.w && j2<bi)){ bw=r2; bi=j2; }
    if (r3.w>bw.w || (r3.w==bw.w && j3<bi)){ bw=r3; bi=j3; }
    cur = bw;
  }
}

// ---------------- K3: exact KNN (k smallest d2, stable ties), serial scan + DPP ----------------
template<int NP>
__global__ __launch_bounds__(64) void k_knn(const float* __restrict__ qp, const float* __restrict__ pool,
                                            int* __restrict__ out){
  constexpr int R = NP/64;
  int lane = threadIdx.x;
  int qm = blockIdx.x;            // b*M + m
  int b = qm / M_;
  const float* q = qp + (size_t)qm*3;
  float qx=q[0], qy=q[1], qz=q[2];
  float d2[R];
  #pragma unroll
  for (int j=0;j<R;++j){
    int n = lane + 64*j;
    const float* p = pool + ((size_t)b*NP + n)*3;
    float dx=__fsub_rn(qx,p[0]), dy=__fsub_rn(qy,p[1]), dz=__fsub_rn(qz,p[2]);
    d2[j]=__fadd_rn(__fadd_rn(__fmul_rn(dx,dx),__fmul_rn(dy,dy)),__fmul_rn(dz,dz));
  }
  for (int r=0;r<K_;++r){
    float v=FLT_MAX; int vi=0x7fffffff;
    #pragma unroll
    for (int j=0;j<R;++j){
      if (d2[j]<v){ v=d2[j]; vi=lane+64*j; }
    }
    DPP_AMIN(0x121); DPP_AMIN(0x122); DPP_AMIN(0x124); DPP_AMIN(0x128);
    DPP_AMIN(0x142); DPP_AMIN(0x143);
    int si = __builtin_amdgcn_readlane(vi, 63);
    if (lane==0) out[(size_t)qm*K_ + r] = si;
    #pragma unroll
    for (int j=0;j<R;++j){ if (si == lane + 64*j) d2[j] = FLT_MAX; }
  }
}

// ---------------- K4: fused down-proj + relu + neighbor-max -> xA [B,M,NG,C] ----------------
__global__ __launch_bounds__(256) void k_downmax(
    const float* __restrict__ x1, const int* __restrict__ nbrD,
    const float* __restrict__ dw, const float* __restrict__ db,
    float* __restrict__ xA){
  int bm = blockIdx.x; int b = bm / M_;
  int tid = threadIdx.x;
  __shared__ int nb[K_];
  __shared__ float xs[K_][NG_*H_];     // 48 KB
  if (tid<K_) nb[tid] = nbrD[(size_t)bm*K_ + tid];
  __syncthreads();
  for (int idx=tid; idx<K_*NG_*H_/4; idx+=256){
    int k = idx / (NG_*H_/4), r = idx % (NG_*H_/4);
    ((float4*)&xs[k][0])[r] = ((const float4*)&x1[((size_t)(b*N_) + nb[k])*(NG_*H_)])[r];
  }
  __syncthreads();
  int c = tid & 127, gh = tid >> 7;
  float dbc = db[c];
  for (int gi=0; gi<6; ++gi){
    int g = gh*6 + gi;
    float acc[K_];
    #pragma unroll
    for (int k=0;k<K_;++k) acc[k]=dbc;
    for (int i4=0;i4<16;++i4){
      float w0 = dw[(i4*4+0)*C_ + c];
      float w1 = dw[(i4*4+1)*C_ + c];
      float w2 = dw[(i4*4+2)*C_ + c];
      float w3 = dw[(i4*4+3)*C_ + c];
      #pragma unroll
      for (int k=0;k<K_;++k){
        float4 xv = *(const float4*)&xs[k][g*H_ + i4*4];
        acc[k] = fmaf(xv.x,w0,fmaf(xv.y,w1,fmaf(xv.z,w2,fmaf(xv.w,w3,acc[k]))));
      }
    }
    float best = acc[0];
    #pragma unroll
    for (int k=1;k<K_;++k) best = fmaxf(best, acc[k]);
    xA[(size_t)bm*(NG_*C_) + g*C_ + c] = fmaxf(best, 0.0f);
  }
}

// ---------------- K5: kbR basis MLP [NG,NG,BD] ----------------
__global__ __launch_bounds__(128) void k_kbR(
    const float* __restrict__ grid, const float* __restrict__ rff,
    const float* __restrict__ w1, const float* __restrict__ b1,
    const float* __restrict__ w2, const float* __restrict__ b2,
    float* __restrict__ kbR){
  int gm = blockIdx.x / NG_, gn = blockIdx.x % NG_;
  int j = threadIdx.x;
  float z = grid[gm*3]*grid[gn*3] + grid[gm*3+1]*grid[gn*3+1] + grid[gm*3+2]*grid[gn*3+2];
  __shared__ float fs[128], hs[128];
  int jj = j & 63;
  float ang = 6.283185307179586f * (z * rff[jj]);
  fs[j] = (j<64) ? sinf(ang) : cosf(ang);
  __syncthreads();
  float acc = b1[j];
  for (int i=0;i<128;++i) acc = fmaf(fs[i], w1[i*128+j], acc);
  hs[j] = gelu_f(acc);
  __syncthreads();
  if (j < 64){
    float a2 = b2[j];
    for (int i=0;i<128;++i) a2 = fmaf(hs[i], w2[i*64+j], a2);
    kbR[(size_t)blockIdx.x*64 + j] = gelu_f(a2);
  }
}

// ---------------- K6: kR = kbR @ kR_w + b  [NG,NG,C] ----------------
__global__ __launch_bounds__(128) void k_kR(
    const float* __restrict__ kbR, const float* __restrict__ kRw, const float* __restrict__ kRb,
    float* __restrict__ kR){
  int pair = blockIdx.x; int c = threadIdx.x;
  __shared__ float kb[64];
  if (c<64) kb[c] = kbR[(size_t)pair*64 + c];
  __syncthreads();
  float acc = kRb[c];
  for (int d=0;d<64;++d) acc = fmaf(kb[d], kRw[d*128+c], acc);
  kR[(size_t)pair*128 + c] = acc;
}

// ---------------- K6b: split weights into transposed bf16 hi/lo ----------------
__global__ __launch_bounds__(256) void k_wsplit(
    const float* __restrict__ w1, const float* __restrict__ w2,
    const float* __restrict__ kxw1, const float* __restrict__ kxw2,
    ushort_t* __restrict__ w1hiT, ushort_t* __restrict__ w1loT,
    ushort_t* __restrict__ w2hiT, ushort_t* __restrict__ w2loT,
    ushort_t* __restrict__ x1hiT, ushort_t* __restrict__ x1loT,
    ushort_t* __restrict__ x2hiT, ushort_t* __restrict__ x2loT){
  int tid = blockIdx.x*256 + threadIdx.x;
  if (tid < 16384){
    int j = tid >> 7, k = tid & 127;
    float x = w1[k*128 + j];
    ushort_t hi = bf16_rne(x);
    float hif = __uint_as_float(((uint_t)hi)<<16);
    ushort_t lo = bf16_rne(x - hif);
    w1hiT[tid] = hi; w1loT[tid] = lo;
  }
  if (tid < 8192){
    int c = tid >> 7, j = tid & 127;
    float x = w2[j*64 + c];
    ushort_t hi = bf16_rne(x);
    float hif = __uint_as_float(((uint_t)hi)<<16);
    ushort_t lo = bf16_rne(x - hif);
    w2hiT[tid] = hi; w2loT[tid] = lo;
  }
  if (tid < 8192){
    int c = tid >> 6, d = tid & 63;   // out[c*64+d] = in[d*128+c]
    float xa = kxw1[d*128 + c];
    ushort_t hi = bf16_rne(xa);
    float hif = __uint_as_float(((uint_t)hi)<<16);
    ushort_t lo = bf16_rne(xa - hif);
    x1hiT[tid] = hi; x1loT[tid] = lo;
    float xb = kxw2[d*128 + c];
    ushort_t hi2 = bf16_rne(xb);
    float hif2 = __uint_as_float(((uint_t)hi2)<<16);
    ushort_t lo2 = bf16_rne(xb - hif2);
    x2hiT[tid] = hi2; x2loT[tid] = lo2;
  }
}

// ---------------- K7: kbx basis MLP via MFMA bf16 x3 (hi/lo split) ----------------
__global__ __launch_bounds__(256) void k_kbx(
    const float* __restrict__ ps, const int* __restrict__ nbr,
    const float* __restrict__ grid, const float* __restrict__ rff,
    const ushort_t* __restrict__ w1hiT, const ushort_t* __restrict__ w1loT,
    const ushort_t* __restrict__ w2hiT, const ushort_t* __restrict__ w2loT,
    const float* __restrict__ b1, const float* __restrict__ b2,
    float* __restrict__ kbx){
  __shared__ float z0s[128], z1s[128], rws[128];
  __shared__ float bounce[4][32*34];
  int tid = threadIdx.x;
  if (tid < 128){
    rws[tid] = rff[tid];
    int fid = blockIdx.x*128 + tid;
    int g = fid % NG_;
    int k = (fid/NG_) % K_;
    int bm = fid / (NG_*K_);
    int b = bm / M_;
    int nb = nbr[(size_t)bm*K_ + k];
    const float* pm = ps + (size_t)bm*3;
    const float* pn = ps + ((size_t)(b*M_) + nb)*3;
    float rx = pn[0]-pm[0], ry = pn[1]-pm[1], rz3 = pn[2]-pm[2];
    const float* gg = grid + g*3;
    float rz = rx*gg[0] + ry*gg[1] + rz3*gg[2];
    float vx = rx - rz*gg[0], vy = ry - rz*gg[1], vz = rz3 - rz*gg[2];
    float rxy = sqrtf(vx*vx + vy*vy + vz*vz + 1e-12f);
    z0s[tid]=rxy; z1s[tid]=rz;
  }
  __syncthreads();
  int wid = tid>>6, lane = tid&63;
  int ln = lane & 15, g = lane >> 4;

  short8 ahi[2][4], alo[2][4];
  #pragma unroll
  for (int rt=0; rt<2; ++rt){
    float z0 = z0s[wid*32 + rt*16 + ln];
    float z1 = z1s[wid*32 + rt*16 + ln];
    #pragma unroll
    for (int ks=0; ks<4; ++ks){
      #pragma unroll
      for (int e=0; e<8; ++e){
        int kd = ks*32 + g*8 + e;
        int kk = kd & 63;
        float t = z0*rws[kk] + z1*rws[64+kk];
        t = t - floorf(t);
        float v = (ks < 2) ? __builtin_amdgcn_sinf(t) : __builtin_amdgcn_cosf(t);
        ushort_t hi = bf16_rne(v);
        float hif = __uint_as_float(((uint_t)hi)<<16);
        ushort_t lo = bf16_rne(v - hif);
        ahi[rt][ks][e] = (short)hi;
        alo[rt][ks][e] = (short)lo;
      }
    }
  }

  floatx4 acc2[2][4];
  #pragma unroll
  for (int rt=0; rt<2; ++rt)
    #pragma unroll
    for (int ct=0; ct<4; ++ct)
      acc2[rt][ct] = (floatx4){0.f,0.f,0.f,0.f};

  float* bw = &bounce[wid][0];

  #pragma unroll
  for (int jp=0; jp<4; ++jp){
    floatx4 acc1[2][2];
    #pragma unroll
    for (int rt=0; rt<2; ++rt)
      #pragma unroll
      for (int jt=0; jt<2; ++jt)
        acc1[rt][jt] = (floatx4){0.f,0.f,0.f,0.f};
    #pragma unroll
    for (int ks=0; ks<4; ++ks){
      #pragma unroll
      for (int jt=0; jt<2; ++jt){
        int j = jp*32 + jt*16 + ln;
        short8 bhi = *(const short8*)&w1hiT[(size_t)j*128 + ks*32 + g*8];
        short8 blo = *(const short8*)&w1loT[(size_t)j*128 + ks*32 + g*8];
        #pragma unroll
        for (int rt=0; rt<2; ++rt){
          acc1[rt][jt] = __builtin_amdgcn_mfma_f32_16x16x32_bf16(ahi[rt][ks], bhi, acc1[rt][jt], 0,0,0);
          acc1[rt][jt] = __builtin_amdgcn_mfma_f32_16x16x32_bf16(alo[rt][ks], bhi, acc1[rt][jt], 0,0,0);
          acc1[rt][jt] = __builtin_amdgcn_mfma_f32_16x16x32_bf16(ahi[rt][ks], blo, acc1[rt][jt], 0,0,0);
        }
      }
    }
    #pragma unroll
    for (int jt=0; jt<2; ++jt){
      float bb = b1[jp*32 + jt*16 + ln];
      #pragma unroll
      for (int rt=0; rt<2; ++rt)
        #pragma unroll
        for (int i=0; i<4; ++i)
          bw[(rt*16 + g*4 + i)*34 + jt*16 + ln] = gelu_f(bb + acc1[rt][jt][i]);
    }
    #pragma unroll
    for (int rt=0; rt<2; ++rt){
      int base = (rt*16 + ln)*34 + g*8;
      float2 p0 = *(float2*)&bw[base+0];
      float2 p1 = *(float2*)&bw[base+2];
      float2 p2 = *(float2*)&bw[base+4];
      float2 p3 = *(float2*)&bw[base+6];
      float hv[8] = {p0.x,p0.y,p1.x,p1.y,p2.x,p2.y,p3.x,p3.y};
      short8 a2h, a2l;
      #pragma unroll
      for (int e=0; e<8; ++e){
        ushort_t hi = bf16_rne(hv[e]);
        float hif = __uint_as_float(((uint_t)hi)<<16);
        ushort_t lo = bf16_rne(hv[e] - hif);
        a2h[e] = (short)hi;
        a2l[e] = (short)lo;
      }
      #pragma unroll
      for (int ct=0; ct<4; ++ct){
        short8 b2h = *(const short8*)&w2hiT[(size_t)(ct*16+ln)*128 + jp*32 + g*8];
        short8 b2l = *(const short8*)&w2loT[(size_t)(ct*16+ln)*128 + jp*32 + g*8];
        acc2[rt][ct] = __builtin_amdgcn_mfma_f32_16x16x32_bf16(a2h, b2h, acc2[rt][ct], 0,0,0);
        acc2[rt][ct] = __builtin_amdgcn_mfma_f32_16x16x32_bf16(a2l, b2h, acc2[rt][ct], 0,0,0);
        acc2[rt][ct] = __builtin_amdgcn_mfma_f32_16x16x32_bf16(a2h, b2l, acc2[rt][ct], 0,0,0);
      }
    }
  }
  #pragma unroll
  for (int ct=0; ct<4; ++ct){
    float bb = b2[ct*16 + ln];
    #pragma unroll
    for (int rt=0; rt<2; ++rt)
      #pragma unroll
      for (int i=0; i<4; ++i){
        int row = wid*32 + rt*16 + g*4 + i;
        size_t fiber = (size_t)blockIdx.x*128 + row;
        kbx[fiber*64 + ct*16 + ln] = gelu_f(bb + acc2[rt][ct][i]);
      }
  }
}

// ---------------- K8: interaction layer, kx-apply via MFMA ----------------
// 256 thr = 4 waves. Per chunk of 4 k's: stage kbx rows -> LDS, MFMA
// [48x64]@[64x128] -> Ts (+bias), then agg += Ts * x[nbr] (global reads).
__global__ __launch_bounds__(256) void k_inter(
    const float* __restrict__ xin, const int* __restrict__ nbr,
    const float* __restrict__ kbx, const float* __restrict__ kR,
    const ushort_t* __restrict__ kxhT, const ushort_t* __restrict__ kxlT,
    const float* __restrict__ kxb,
    const float* __restrict__ mw, const float* __restrict__ mb,
    float* __restrict__ xout){
  int bm = blockIdx.x; int b = bm / M_;
  int tid = threadIdx.x;
  int wid = tid>>6, lane = tid&63, ln = lane&15, g4 = lane>>4;
  int c = tid & 127, gh = tid >> 7;
  __shared__ float kbsL[48][68];     // 12.75 KB, padded
  __shared__ float Ts[48][130];      // 24.4 KB, padded
  __shared__ float aggS[NG_][C_];    // 6 KB
  __shared__ float yS[NG_][C_];      // 6 KB

  // B-fragments (kxw^T hi/lo), fixed per wave: n-tiles wid*2, wid*2+1
  short8 bh[2][2], bl[2][2];
  float kxbv[2];
  #pragma unroll
  for (int nt=0; nt<2; ++nt){
    int cc_ = (wid*2+nt)*16 + ln;
    kxbv[nt] = kxb[cc_];
    #pragma unroll
    for (int ks=0; ks<2; ++ks){
      bh[nt][ks] = *(const short8*)&kxhT[(size_t)cc_*64 + ks*32 + g4*8];
      bl[nt][ks] = *(const short8*)&kxlT[(size_t)cc_*64 + ks*32 + g4*8];
    }
  }
  float accg[6] = {0,0,0,0,0,0};

  for (int cc=0; cc<4; ++cc){
    // stage 4k x 12g x 64d of kbx into LDS (coalesced float4)
    {
      const float4* src = (const float4*)(kbx + ((size_t)bm*192 + cc*48)*64);
      for (int idx=tid; idx<768; idx+=256){
        int r = idx >> 4, dq = idx & 15;
        *(float4*)&kbsL[r][dq*4] = src[idx];
      }
    }
    __syncthreads();
    // MFMA: T = kbs @ kxw  (3 M-tiles x 2 N-tiles x K=64)
    floatx4 acc[3][2];
    #pragma unroll
    for (int mt=0; mt<3; ++mt)
      #pragma unroll
      for (int nt=0; nt<2; ++nt)
        acc[mt][nt] = (floatx4){0.f,0.f,0.f,0.f};
    #pragma unroll
    for (int mt=0; mt<3; ++mt){
      short8 ah[2], al[2];
      #pragma unroll
      for (int ks=0; ks<2; ++ks){
        float4 p0 = *(const float4*)&kbsL[mt*16+ln][ks*32+g4*8];
        float4 p1 = *(const float4*)&kbsL[mt*16+ln][ks*32+g4*8+4];
        float hv[8] = {p0.x,p0.y,p0.z,p0.w,p1.x,p1.y,p1.z,p1.w};
        #pragma unroll
        for (int e=0; e<8; ++e){
          ushort_t hi = bf16_rne(hv[e]);
          float hif = __uint_as_float(((uint_t)hi)<<16);
          ushort_t lo = bf16_rne(hv[e] - hif);
          ah[ks][e] = (short)hi;
          al[ks][e] = (short)lo;
        }
      }
      #pragma unroll
      for (int nt=0; nt<2; ++nt)
        #pragma unroll
        for (int ks=0; ks<2; ++ks){
          acc[mt][nt] = __builtin_amdgcn_mfma_f32_16x16x32_bf16(ah[ks], bh[nt][ks], acc[mt][nt], 0,0,0);
          acc[mt][nt] = __builtin_amdgcn_mfma_f32_16x16x32_bf16(al[ks], bh[nt][ks], acc[mt][nt], 0,0,0);
          acc[mt][nt] = __builtin_amdgcn_mfma_f32_16x16x32_bf16(ah[ks], bl[nt][ks], acc[mt][nt], 0,0,0);
        }
    }
    // write Ts (+bias): D layout col=ln, row=g4*4+i
    #pragma unroll
    for (int mt=0; mt<3; ++mt)
      #pragma unroll
      for (int nt=0; nt<2; ++nt)
        #pragma unroll
        for (int i=0; i<4; ++i)
          Ts[mt*16 + g4*4 + i][(wid*2+nt)*16 + ln] = acc[mt][nt][i] + kxbv[nt];
    __syncthreads();
    // agg: accg[gi] += Ts[k*12+g][c] * x[nbr_k][g][c]
    #pragma unroll
    for (int kl=0; kl<4; ++kl){
      int nb = nbr[(size_t)bm*K_ + cc*4 + kl];
      const float* xr = xin + ((size_t)(b*M_) + nb)*(NG_*C_);
      #pragma unroll
      for (int gi=0; gi<6; ++gi){
        int g = gh*6 + gi;
        accg[gi] = fmaf(Ts[kl*12+g][c], xr[g*C_ + c], accg[gi]);
      }
    }
    __syncthreads();
  }
  #pragma unroll
  for (int gi=0; gi<6; ++gi)
    aggS[gh*6+gi][c] = accg[gi] * (1.0f/16.0f);
  __syncthreads();
  #pragma unroll
  for (int gi=0; gi<6; ++gi){
    int g = gh*6+gi;
    float yv = 0.f;
    #pragma unroll
    for (int n=0;n<NG_;++n) yv = fmaf(aggS[n][c], kR[((size_t)g*NG_+n)*C_ + c], yv);
    yS[g][c] = yv * (1.0f/12.0f);
  }
  __syncthreads();
  float m6[6] = {0,0,0,0,0,0};
  for (int i4=0;i4<32;++i4){
    float w0 = mw[(i4*4+0)*C_+c], w1 = mw[(i4*4+1)*C_+c],
          w2 = mw[(i4*4+2)*C_+c], w3 = mw[(i4*4+3)*C_+c];
    #pragma unroll
    for (int gi=0;gi<6;++gi){
      int g = gh*6+gi;
      float4 yv = *(const float4*)&yS[g][i4*4];
      m6[gi] = fmaf(yv.x,w0,fmaf(yv.y,w1,fmaf(yv.z,w2,fmaf(yv.w,w3,m6[gi]))));
    }
  }
  float mbc = mb[c];
  #pragma unroll
  for (int gi=0;gi<6;++gi){
    int g = gh*6+gi;
    size_t off = (size_t)bm*(NG_*C_) + g*C_ + c;
    xout[off] = xin[off] + gelu_f(m6[gi] + mbc);
  }
}

// ---------------- K9a: parallel partial reduction ----------------
__global__ __launch_bounds__(256) void k_reduce(
    const float* __restrict__ x, float* __restrict__ part){
  int blk = blockIdx.x;
  int b = blk >> 6, ch = blk & 63;
  int tid = threadIdx.x;
  int c = tid & 127, half = tid >> 7;
  const float* xb = x + (size_t)b*(M_*NG_)*C_;
  int r0 = ch*96;
  float acc = 0.f;
  for (int r = r0 + half; r < r0 + 96; r += 2)
    acc += xb[(size_t)r*C_ + c];
  __shared__ float red[256];
  red[tid] = acc;
  __syncthreads();
  if (half == 0)
    part[(size_t)blk*C_ + c] = red[c] + red[128 + c];
}

// ---------------- K9b: final reduce + MLP head ----------------
__global__ __launch_bounds__(256) void k_head(
    const float* __restrict__ part,
    const float* __restrict__ p1w, const float* __restrict__ p1b,
    const float* __restrict__ p2w, const float* __restrict__ p2b,
    const float* __restrict__ p3w, const float* __restrict__ p3b,
    float* __restrict__ out){
  int b = blockIdx.x, tid = threadIdx.x;
  __shared__ float gs[128];
  if (tid < 128){
    float a = 0.f;
    const float* pb = part + (size_t)b*64*C_;
    for (int ch = 0; ch < 64; ++ch) a += pb[(size_t)ch*C_ + tid];
    gs[tid] = a * (1.0f/(M_*NG_));
  }
  __syncthreads();
  __shared__ float h1[256];
  {
    float a = p1b[tid];
    for (int i=0;i<128;++i) a = fmaf(gs[i], p1w[i*256+tid], a);
    h1[tid] = gelu_f(a);
  }
  __syncthreads();
  __shared__ float h2[64];
  if (tid<64){
    float a = p2b[tid];
    for (int i=0;i<256;++i) a = fmaf(h1[i], p2w[i*64+tid], a);
    h2[tid] = gelu_f(a);
  }
  __syncthreads();
  if (tid==0){
    float a = p3b[0];
    for (int i=0;i<64;++i) a = fmaf(h2[i], p3w[i], a);
    out[b] = a;
  }
}

extern "C" void kernel_launch(void* const* d_in, const int* in_sizes, int n_in,
                              void* d_out, int out_size, void* d_ws, size_t ws_size,
                              hipStream_t stream){
  const float* pos    = (const float*)d_in[0];
  const float* normal = (const float*)d_in[1];
  const float* grid   = (const float*)d_in[2];
  const float* e1w = (const float*)d_in[3];  const float* e1b = (const float*)d_in[4];
  const float* e2w = (const float*)d_in[5];  const float* e2b = (const float*)d_in[6];
  const float* dww = (const float*)d_in[7];  const float* dwb = (const float*)d_in[8];
  const float* bx_rff = (const float*)d_in[9];
  const float* bx1w = (const float*)d_in[10]; const float* bx1b = (const float*)d_in[11];
  const float* bx2w = (const float*)d_in[12]; const float* bx2b = (const float*)d_in[13];
  const float* bR_rff = (const float*)d_in[14];
  const float* bR1w = (const float*)d_in[15]; const float* bR1b = (const float*)d_in[16];
  const float* bR2w = (const float*)d_in[17]; const float* bR2b = (const float*)d_in[18];
  const float* i1kxw = (const float*)d_in[19]; const float* i1kxb = (const float*)d_in[20];
  const float* i1kRw = (const float*)d_in[21]; const float* i1kRb = (const float*)d_in[22];
  const float* i1mw  = (const float*)d_in[23]; const float* i1mb  = (const float*)d_in[24];
  const float* i2kxw = (const float*)d_in[25]; const float* i2kxb = (const float*)d_in[26];
  const float* i2kRw = (const float*)d_in[27]; const float* i2kRb = (const float*)d_in[28];
  const float* i2mw  = (const float*)d_in[29]; const float* i2mb  = (const float*)d_in[30];
  const float* p1w = (const float*)d_in[31]; const float* p1b = (const float*)d_in[32];
  const float* p2w = (const float*)d_in[33]; const float* p2b = (const float*)d_in[34];
  const float* p3w = (const float*)d_in[35]; const float* p3b = (const float*)d_in[36];
  float* out = (float*)d_out;

  float* ws = (float*)d_ws;
  size_t o = 0;
  float* x1  = ws + o; o += (size_t)B_*N_*NG_*H_;       // 6,291,456
  float* psb = ws + o; o += (size_t)B_*M_*3;            // 6,144
  float* xA  = ws + o; o += (size_t)B_*M_*NG_*C_;       // 3,145,728
  float* xB  = ws + o; o += (size_t)B_*M_*NG_*C_;       // 3,145,728
  float* kbx = ws + o; o += (size_t)B_*M_*K_*NG_*BD_;   // 25,165,824
  float* kbR = ws + o; o += (size_t)NG_*NG_*BD_;        // 9,216
  float* kRb = ws + o; o += (size_t)NG_*NG_*C_;         // 18,432
  float* part = ws + o; o += (size_t)B_*64*C_;          // 32,768
  int* nbrD  = (int*)(ws + o); o += (size_t)B_*M_*K_;   // 32,768
  int* nbrS  = (int*)(ws + o); o += (size_t)B_*M_*K_;   // 32,768
  ushort_t* w1hiT = (ushort_t*)(ws + o); o += 8192;     // 16384 ushort
  ushort_t* w1loT = (ushort_t*)(ws + o); o += 8192;
  ushort_t* w2hiT = (ushort_t*)(ws + o); o += 4096;     // 8192 ushort
  ushort_t* w2loT = (ushort_t*)(ws + o); o += 4096;
  ushort_t* x1hiT = (ushort_t*)(ws + o); o += 4096;     // 8192 ushort
  ushort_t* x1loT = (ushort_t*)(ws + o); o += 4096;
  ushort_t* x2hiT = (ushort_t*)(ws + o); o += 4096;
  ushort_t* x2loT = (ushort_t*)(ws + o); o += 4096;

  k_lift<<<B_*N_*NG_/4, 256, 0, stream>>>(pos, normal, grid, e1w,e1b,e2w,e2b, x1);
  k_fps<<<B_, 256, 0, stream>>>(pos, psb);
  k_wsplit<<<64, 256, 0, stream>>>(bx1w, bx2w, i1kxw, i2kxw,
      w1hiT, w1loT, w2hiT, w2loT, x1hiT, x1loT, x2hiT, x2loT);
  k_knn<N_><<<B_*M_, 64, 0, stream>>>(psb, pos, nbrD);
  k_knn<M_><<<B_*M_, 64, 0, stream>>>(psb, psb, nbrS);
  k_downmax<<<B_*M_, 256, 0, stream>>>(x1, nbrD, dww, dwb, xA);
  k_kbR<<<NG_*NG_, 128, 0, stream>>>(grid, bR_rff, bR1w, bR1b, bR2w, bR2b, kbR);
  k_kbx<<<(B_*M_*K_*NG_)/128, 256, 0, stream>>>(psb, nbrS, grid, bx_rff,
      w1hiT, w1loT, w2hiT, w2loT, bx1b, bx2b, kbx);
  k_kR<<<NG_*NG_, 128, 0, stream>>>(kbR, i1kRw, i1kRb, kRb);
  k_inter<<<B_*M_, 256, 0, stream>>>(xA, nbrS, kbx, kRb, x1hiT, x1loT, i1kxb, i1mw, i1mb, xB);
  k_kR<<<NG_*NG_, 128, 0, stream>>>(kbR, i2kRw, i2kRb, kRb);
  k_inter<<<B_*M_, 256, 0, stream>>>(xB, nbrS, kbx, kRb, x2hiT, x2loT, i2kxb, i2mw, i2mb, xA);
  k_reduce<<<B_*64, 256, 0, stream>>>(xA, part);
  k_head<<<B_, 256, 0, stream>>>(part, p1w,p1b,p2w,p2b,p3w,p3b, out);
}

// Round 8
// 802.752 us; speedup vs baseline: 1.7521x; 1.2146x over previous
//
#include <hip/hip_runtime.h>
#include <hip/hip_bf16.h>
#include <cfloat>

#define B_ 4
#define N_ 2048
#define NG_ 12
#define K_ 16
#define H_ 64
#define C_ 128
#define BD_ 64
#define M_ 512

typedef __attribute__((ext_vector_type(8))) short short8;
typedef __attribute__((ext_vector_type(4))) float floatx4;
typedef unsigned short ushort_t;
typedef unsigned int uint_t;

__device__ __forceinline__ float gelu_f(float x){
  float s = 0.7978845608028654f*(x + 0.044715f*x*x*x);
  float e = __expf(2.0f*s);
  float t = 1.0f - 2.0f/(e + 1.0f);
  return 0.5f*x*(1.0f + t);
}

__device__ __forceinline__ ushort_t bf16_rne(float x){
  uint_t u = __float_as_uint(x);
  uint_t r = (u + 0x7fffu + ((u >> 16) & 1u)) >> 16;
  return (ushort_t)r;
}

#define DPP_AMAX(CTRL) { \
  int _vb = __float_as_int(v); \
  int _ov = __builtin_amdgcn_update_dpp(_vb, _vb, (CTRL), 0xF, 0xF, false); \
  int _oi = __builtin_amdgcn_update_dpp(vi, vi, (CTRL), 0xF, 0xF, false); \
  float _of = __int_as_float(_ov); \
  bool _tk = (_of > v) || (_of == v && _oi < vi); \
  v = _tk ? _of : v; vi = _tk ? _oi : vi; }

#define DPP_AMIN(CTRL) { \
  int _vb = __float_as_int(v); \
  int _ov = __builtin_amdgcn_update_dpp(_vb, _vb, (CTRL), 0xF, 0xF, false); \
  int _oi = __builtin_amdgcn_update_dpp(vi, vi, (CTRL), 0xF, 0xF, false); \
  float _of = __int_as_float(_ov); \
  bool _tk = (_of < v) || (_of == v && _oi < vi); \
  v = _tk ? _of : v; vi = _tk ? _oi : vi; }

// ============ MEGA-KERNEL 1: fps (blocks 0-3) + lift + wsplit + kbR ============
#define FPSB 4
#define LIFTB (B_*N_*NG_/4)      // 6144
#define WSB 64
#define KBRB (NG_*NG_)           // 144

__global__ __launch_bounds__(256) void k_mega1(
    const float* __restrict__ pos, const float* __restrict__ normal,
    const float* __restrict__ grid,
    const float* __restrict__ e1w, const float* __restrict__ e1b,
    const float* __restrict__ e2w, const float* __restrict__ e2b,
    float* __restrict__ x1, float* __restrict__ ps,
    const float* __restrict__ bx1w, const float* __restrict__ bx2w,
    const float* __restrict__ kxw1, const float* __restrict__ kxw2,
    const float* __restrict__ dww,
    ushort_t* __restrict__ w1hiT, ushort_t* __restrict__ w1loT,
    ushort_t* __restrict__ w2hiT, ushort_t* __restrict__ w2loT,
    ushort_t* __restrict__ x1hiT, ushort_t* __restrict__ x1loT,
    ushort_t* __restrict__ x2hiT, ushort_t* __restrict__ x2loT,
    ushort_t* __restrict__ dwThi, ushort_t* __restrict__ dwTlo,
    const float* __restrict__ bR_rff,
    const float* __restrict__ bR1w, const float* __restrict__ bR1b,
    const float* __restrict__ bR2w, const float* __restrict__ bR2b,
    float* __restrict__ kbR){
  __shared__ float4 posS4[N_];        // fps
  __shared__ float2 wred[2][4];       // fps
  __shared__ float ts4[4][64];        // lift
  __shared__ float fsb[128], hsb[128];// kbR
  int bid = blockIdx.x;
  int tid = threadIdx.x;

  if (bid < FPSB){
    // ---------------- FPS (r5 structure: 4 waves, DPP, 1 barrier/iter) --------
    int b = bid;
    for (int i=tid;i<N_;i+=256){
      const float* p = pos + (size_t)b*N_*3 + (size_t)i*3;
      posS4[i] = make_float4(p[0], p[1], p[2], 0.f);
    }
    __syncthreads();
    float px[8],py[8],pz[8],d[8];
    #pragma unroll
    for (int j=0;j<8;++j){
      float4 pt = posS4[tid + 256*j];
      px[j]=pt.x; py[j]=pt.y; pz[j]=pt.z;
      d[j]=1e10f;
    }
    int wave = tid>>6, lane = tid&63;
    int last = 0;
    for (int s=0;s<M_;++s){
      float4 lp = posS4[last];
      float lx=lp.x, ly=lp.y, lz=lp.z;
      if (tid==0){ float* o = ps + ((size_t)b*M_+s)*3; o[0]=lx;o[1]=ly;o[2]=lz; }
      #pragma unroll
      for (int j=0;j<8;++j){
        float dx=__fsub_rn(px[j],lx), dy=__fsub_rn(py[j],ly), dz=__fsub_rn(pz[j],lz);
        float dist=__fadd_rn(__fadd_rn(__fmul_rn(dx,dx),__fmul_rn(dy,dy)),__fmul_rn(dz,dz));
        d[j]=fminf(d[j],dist);
      }
      if (s==M_-1) break;
      float va = d[1]>d[0]?d[1]:d[0]; int ja = d[1]>d[0]?1:0;
      float vb = d[3]>d[2]?d[3]:d[2]; int jb = d[3]>d[2]?3:2;
      float vc = d[5]>d[4]?d[5]:d[4]; int jc = d[5]>d[4]?5:4;
      float vd = d[7]>d[6]?d[7]:d[6]; int jd = d[7]>d[6]?7:6;
      float ve = vb>va?vb:va; int je = vb>va?jb:ja;
      float vf = vd>vc?vd:vc; int jf = vd>vc?jd:jc;
      float v  = vf>ve?vf:ve; int jj = vf>ve?jf:je;
      int vi = tid + (jj<<8);
      DPP_AMAX(0x121); DPP_AMAX(0x122); DPP_AMAX(0x124); DPP_AMAX(0x128);
      DPP_AMAX(0x142); DPP_AMAX(0x143);
      int sv = __builtin_amdgcn_readlane(__float_as_int(v), 63);
      int si = __builtin_amdgcn_readlane(vi, 63);
      if (lane==0) wred[s&1][wave] = make_float2(__int_as_float(sv), __int_as_float(si));
      __syncthreads();
      float2 r0 = wred[s&1][0], r1 = wred[s&1][1], r2 = wred[s&1][2], r3 = wred[s&1][3];
      float bv = r0.x; int bi = __float_as_int(r0.y);
      int i1 = __float_as_int(r1.y); if (r1.x>bv || (r1.x==bv && i1<bi)){ bv=r1.x; bi=i1; }
      int i2 = __float_as_int(r2.y); if (r2.x>bv || (r2.x==bv && i2<bi)){ bv=r2.x; bi=i2; }
      int i3 = __float_as_int(r3.y); if (r3.x>bv || (r3.x==bv && i3<bi)){ bv=r3.x; bi=i3; }
      last = bi;
    }
  } else if (bid < FPSB + LIFTB){
    // ---------------- lift + embed ----------------
    int vbid = bid - FPSB;
    int q = tid>>6, lane = tid&63;
    int fid = vbid*4 + q;
    int g = fid % NG_;
    int n = (fid / NG_) % N_;
    int b = fid / (NG_*N_);
    const float* nm = normal + (size_t)(b*N_+n)*3;
    const float* pp = pos + (size_t)(b*N_+n)*3;
    const float* gg = grid + g*3;
    float f0 = nm[0]*gg[0] + nm[1]*gg[1] + nm[2]*gg[2];
    float t = e1b[lane] + f0*e1w[lane] + pp[0]*e1w[64+lane] + pp[1]*e1w[128+lane] + pp[2]*e1w[192+lane];
    ts4[q][lane] = gelu_f(t);
    __syncthreads();
    float acc = e2b[lane];
    #pragma unroll
    for (int i=0;i<64;++i) acc = fmaf(ts4[q][i], e2w[i*64+lane], acc);
    x1[(size_t)fid*64 + lane] = acc;
  } else if (bid < FPSB + LIFTB + WSB){
    // ---------------- weight split ----------------
    int tg = (bid - FPSB - LIFTB)*256 + tid;
    if (tg < 16384){
      int j = tg >> 7, k = tg & 127;
      float x = bx1w[k*128 + j];
      ushort_t hi = bf16_rne(x);
      float hif = __uint_as_float(((uint_t)hi)<<16);
      ushort_t lo = bf16_rne(x - hif);
      w1hiT[tg] = hi; w1loT[tg] = lo;
    }
    if (tg < 8192){
      int c = tg >> 7, j = tg & 127;
      float x = bx2w[j*64 + c];
      ushort_t hi = bf16_rne(x);
      float hif = __uint_as_float(((uint_t)hi)<<16);
      ushort_t lo = bf16_rne(x - hif);
      w2hiT[tg] = hi; w2loT[tg] = lo;
    }
    if (tg < 8192){
      int c = tg >> 6, d = tg & 63;
      float xa = kxw1[d*128 + c];
      ushort_t hi = bf16_rne(xa);
      float hif = __uint_as_float(((uint_t)hi)<<16);
      ushort_t lo = bf16_rne(xa - hif);
      x1hiT[tg] = hi; x1loT[tg] = lo;
      float xb = kxw2[d*128 + c];
      ushort_t hi2 = bf16_rne(xb);
      float hif2 = __uint_as_float(((uint_t)hi2)<<16);
      ushort_t lo2 = bf16_rne(xb - hif2);
      x2hiT[tg] = hi2; x2loT[tg] = lo2;
      float xd = dww[d*128 + c];
      ushort_t hi3 = bf16_rne(xd);
      float hif3 = __uint_as_float(((uint_t)hi3)<<16);
      ushort_t lo3 = bf16_rne(xd - hif3);
      dwThi[tg] = hi3; dwTlo[tg] = lo3;
    }
  } else {
    // ---------------- kbR basis MLP ----------------
    int vbid = bid - FPSB - LIFTB - WSB;
    int gm = vbid / NG_, gn = vbid % NG_;
    int j = tid;
    if (j < 128){
      float z = grid[gm*3]*grid[gn*3] + grid[gm*3+1]*grid[gn*3+1] + grid[gm*3+2]*grid[gn*3+2];
      float ang = 6.283185307179586f * (z * bR_rff[j & 63]);
      fsb[j] = (j<64) ? sinf(ang) : cosf(ang);
    }
    __syncthreads();
    if (j < 128){
      float acc = bR1b[j];
      for (int i=0;i<128;++i) acc = fmaf(fsb[i], bR1w[i*128+j], acc);
      hsb[j] = gelu_f(acc);
    }
    __syncthreads();
    if (j < 64){
      float a2 = bR2b[j];
      for (int i=0;i<128;++i) a2 = fmaf(hsb[i], bR2w[i*64+j], a2);
      kbR[(size_t)vbid*64 + j] = gelu_f(a2);
    }
  }
}

// ============ KNN (both graphs in one dispatch) ============
template<int NP>
__device__ __forceinline__ void knn_body(int qm, const float* __restrict__ qp,
                                         const float* __restrict__ pool, int* __restrict__ out){
  constexpr int R = NP/64;
  int lane = threadIdx.x;
  int b = qm / M_;
  const float* q = qp + (size_t)qm*3;
  float qx=q[0], qy=q[1], qz=q[2];
  float d2[R];
  #pragma unroll
  for (int j=0;j<R;++j){
    int n = lane + 64*j;
    const float* p = pool + ((size_t)b*NP + n)*3;
    float dx=__fsub_rn(qx,p[0]), dy=__fsub_rn(qy,p[1]), dz=__fsub_rn(qz,p[2]);
    d2[j]=__fadd_rn(__fadd_rn(__fmul_rn(dx,dx),__fmul_rn(dy,dy)),__fmul_rn(dz,dz));
  }
  for (int r=0;r<K_;++r){
    float v=FLT_MAX; int vi=0x7fffffff;
    #pragma unroll
    for (int j=0;j<R;++j){
      if (d2[j]<v){ v=d2[j]; vi=lane+64*j; }
    }
    DPP_AMIN(0x121); DPP_AMIN(0x122); DPP_AMIN(0x124); DPP_AMIN(0x128);
    DPP_AMIN(0x142); DPP_AMIN(0x143);
    int si = __builtin_amdgcn_readlane(vi, 63);
    if (lane==0) out[(size_t)qm*K_ + r] = si;
    #pragma unroll
    for (int j=0;j<R;++j){ if (si == lane + 64*j) d2[j] = FLT_MAX; }
  }
}

__global__ __launch_bounds__(64) void k_knn_all(const float* __restrict__ psb,
    const float* __restrict__ pos, int* __restrict__ nbrD, int* __restrict__ nbrS){
  int bid = blockIdx.x;
  if (bid < B_*M_) knn_body<N_>(bid, psb, pos, nbrD);
  else             knn_body<M_>(bid - B_*M_, psb, psb, nbrS);
}

// ============ kR (both layers in one dispatch) ============
__global__ __launch_bounds__(128) void k_kR2(
    const float* __restrict__ kbR,
    const float* __restrict__ w1, const float* __restrict__ b1,
    const float* __restrict__ w2, const float* __restrict__ b2,
    float* __restrict__ o1, float* __restrict__ o2){
  int bid = blockIdx.x;
  int pair = bid % KBRB;
  const float* w = (bid < KBRB) ? w1 : w2;
  const float* bb = (bid < KBRB) ? b1 : b2;
  float* oo = (bid < KBRB) ? o1 : o2;
  int c = threadIdx.x;
  __shared__ float kb[64];
  if (c<64) kb[c] = kbR[(size_t)pair*64 + c];
  __syncthreads();
  float acc = bb[c];
  for (int d=0;d<64;++d) acc = fmaf(kb[d], w[d*128+c], acc);
  oo[(size_t)pair*128 + c] = acc;
}

// ============ downmax (MFMA) + kbx in one dispatch ============
__device__ __forceinline__ void dm_body(float* um, int bm,
    const float* __restrict__ x1, const int* __restrict__ nbrD,
    const ushort_t* __restrict__ dwThi, const ushort_t* __restrict__ dwTlo,
    const float* __restrict__ db, float* __restrict__ xA){
  int b = bm / M_;
  int tid = threadIdx.x;
  float* xs = um;                       // [16][768], xor-swizzled granules
  int* nb = (int*)(um + 12288);
  if (tid < K_) nb[tid] = nbrD[(size_t)bm*K_ + tid];
  __syncthreads();
  for (int idx=tid; idx<3072; idx+=256){
    int k = idx / 192, qq = idx % 192;
    float4 vv = ((const float4*)&x1[((size_t)(b*N_) + nb[k])*(NG_*H_)])[qq];
    int gran = (qq >> 1) ^ (k & 7);
    *(float4*)&xs[k*768 + gran*8 + (qq&1)*4] = vv;
  }
  __syncthreads();
  int wid = tid>>6, lane = tid&63, ln = lane&15, g4 = lane>>4;
  short8 bh[2][2], bl[2][2];
  float dbv[2];
  #pragma unroll
  for (int nt=0; nt<2; ++nt){
    int col = wid*32 + nt*16 + ln;
    dbv[nt] = db[col];
    #pragma unroll
    for (int ks=0; ks<2; ++ks){
      bh[nt][ks] = *(const short8*)&dwThi[(size_t)col*64 + ks*32 + g4*8];
      bl[nt][ks] = *(const short8*)&dwTlo[(size_t)col*64 + ks*32 + g4*8];
    }
  }
  int xorl = ln & 7;
  #pragma unroll
  for (int g=0; g<NG_; ++g){
    short8 ah[2], al[2];
    #pragma unroll
    for (int ks=0; ks<2; ++ks){
      int col0 = g*64 + ks*32 + g4*8;
      int gran = (col0 >> 3) ^ xorl;
      const float* src = &xs[ln*768 + gran*8];
      float4 p0 = *(const float4*)src;
      float4 p1 = *(const float4*)(src+4);
      float hv[8] = {p0.x,p0.y,p0.z,p0.w,p1.x,p1.y,p1.z,p1.w};
      #pragma unroll
      for (int e=0; e<8; ++e){
        ushort_t hi = bf16_rne(hv[e]);
        float hif = __uint_as_float(((uint_t)hi)<<16);
        ushort_t lo = bf16_rne(hv[e]-hif);
        ah[ks][e] = (short)hi; al[ks][e] = (short)lo;
      }
    }
    floatx4 acc[2];
    acc[0] = (floatx4){0.f,0.f,0.f,0.f};
    acc[1] = (floatx4){0.f,0.f,0.f,0.f};
    #pragma unroll
    for (int nt=0; nt<2; ++nt)
      #pragma unroll
      for (int ks=0; ks<2; ++ks){
        acc[nt] = __builtin_amdgcn_mfma_f32_16x16x32_bf16(ah[ks], bh[nt][ks], acc[nt], 0,0,0);
        acc[nt] = __builtin_amdgcn_mfma_f32_16x16x32_bf16(al[ks], bh[nt][ks], acc[nt], 0,0,0);
        acc[nt] = __builtin_amdgcn_mfma_f32_16x16x32_bf16(ah[ks], bl[nt][ks], acc[nt], 0,0,0);
      }
    #pragma unroll
    for (int nt=0; nt<2; ++nt){
      float mx = fmaxf(fmaxf(acc[nt][0],acc[nt][1]), fmaxf(acc[nt][2],acc[nt][3]));
      mx = fmaxf(mx, __shfl_xor(mx, 16));
      mx = fmaxf(mx, __shfl_xor(mx, 32));
      if (g4 == 0)
        xA[(size_t)bm*(NG_*C_) + g*C_ + wid*32 + nt*16 + ln] = fmaxf(mx + dbv[nt], 0.0f);
    }
  }
}

__device__ __forceinline__ void kbx_body(float* um, int vbid,
    const float* __restrict__ ps, const int* __restrict__ nbr,
    const float* __restrict__ grid, const float* __restrict__ rff,
    const ushort_t* __restrict__ w1hiT, const ushort_t* __restrict__ w1loT,
    const ushort_t* __restrict__ w2hiT, const ushort_t* __restrict__ w2loT,
    const float* __restrict__ b1, const float* __restrict__ b2,
    float* __restrict__ kbx){
  float* z0s = um;
  float* z1s = um + 128;
  float* rws = um + 256;
  int tid = threadIdx.x;
  if (tid < 128){
    rws[tid] = rff[tid];
    int fid = vbid*128 + tid;
    int g = fid % NG_;
    int k = (fid/NG_) % K_;
    int bm = fid / (NG_*K_);
    int b = bm / M_;
    int nb = nbr[(size_t)bm*K_ + k];
    const float* pm = ps + (size_t)bm*3;
    const float* pn = ps + ((size_t)(b*M_) + nb)*3;
    float rx = pn[0]-pm[0], ry = pn[1]-pm[1], rz3 = pn[2]-pm[2];
    const float* gg = grid + g*3;
    float rz = rx*gg[0] + ry*gg[1] + rz3*gg[2];
    float vx = rx - rz*gg[0], vy = ry - rz*gg[1], vz = rz3 - rz*gg[2];
    float rxy = sqrtf(vx*vx + vy*vy + vz*vz + 1e-12f);
    z0s[tid]=rxy; z1s[tid]=rz;
  }
  __syncthreads();
  int wid = tid>>6, lane = tid&63;
  int ln = lane & 15, g = lane >> 4;
  float* bw = um + 384 + wid*1088;

  short8 ahi[2][4], alo[2][4];
  #pragma unroll
  for (int rt=0; rt<2; ++rt){
    float z0 = z0s[wid*32 + rt*16 + ln];
    float z1 = z1s[wid*32 + rt*16 + ln];
    #pragma unroll
    for (int ks=0; ks<4; ++ks){
      #pragma unroll
      for (int e=0; e<8; ++e){
        int kd = ks*32 + g*8 + e;
        int kk = kd & 63;
        float t = z0*rws[kk] + z1*rws[64+kk];
        t = t - floorf(t);
        float v = (ks < 2) ? __builtin_amdgcn_sinf(t) : __builtin_amdgcn_cosf(t);
        ushort_t hi = bf16_rne(v);
        float hif = __uint_as_float(((uint_t)hi)<<16);
        ushort_t lo = bf16_rne(v - hif);
        ahi[rt][ks][e] = (short)hi;
        alo[rt][ks][e] = (short)lo;
      }
    }
  }
  floatx4 acc2[2][4];
  #pragma unroll
  for (int rt=0; rt<2; ++rt)
    #pragma unroll
    for (int ct=0; ct<4; ++ct)
      acc2[rt][ct] = (floatx4){0.f,0.f,0.f,0.f};

  #pragma unroll
  for (int jp=0; jp<4; ++jp){
    floatx4 acc1[2][2];
    #pragma unroll
    for (int rt=0; rt<2; ++rt)
      #pragma unroll
      for (int jt=0; jt<2; ++jt)
        acc1[rt][jt] = (floatx4){0.f,0.f,0.f,0.f};
    #pragma unroll
    for (int ks=0; ks<4; ++ks){
      #pragma unroll
      for (int jt=0; jt<2; ++jt){
        int j = jp*32 + jt*16 + ln;
        short8 bhi = *(const short8*)&w1hiT[(size_t)j*128 + ks*32 + g*8];
        short8 blo = *(const short8*)&w1loT[(size_t)j*128 + ks*32 + g*8];
        #pragma unroll
        for (int rt=0; rt<2; ++rt){
          acc1[rt][jt] = __builtin_amdgcn_mfma_f32_16x16x32_bf16(ahi[rt][ks], bhi, acc1[rt][jt], 0,0,0);
          acc1[rt][jt] = __builtin_amdgcn_mfma_f32_16x16x32_bf16(alo[rt][ks], bhi, acc1[rt][jt], 0,0,0);
          acc1[rt][jt] = __builtin_amdgcn_mfma_f32_16x16x32_bf16(ahi[rt][ks], blo, acc1[rt][jt], 0,0,0);
        }
      }
    }
    #pragma unroll
    for (int jt=0; jt<2; ++jt){
      float bb = b1[jp*32 + jt*16 + ln];
      #pragma unroll
      for (int rt=0; rt<2; ++rt)
        #pragma unroll
        for (int i=0; i<4; ++i)
          bw[(rt*16 + g*4 + i)*34 + jt*16 + ln] = gelu_f(bb + acc1[rt][jt][i]);
    }
    #pragma unroll
    for (int rt=0; rt<2; ++rt){
      int base = (rt*16 + ln)*34 + g*8;
      float2 p0 = *(float2*)&bw[base+0];
      float2 p1 = *(float2*)&bw[base+2];
      float2 p2 = *(float2*)&bw[base+4];
      float2 p3 = *(float2*)&bw[base+6];
      float hv[8] = {p0.x,p0.y,p1.x,p1.y,p2.x,p2.y,p3.x,p3.y};
      short8 a2h, a2l;
      #pragma unroll
      for (int e=0; e<8; ++e){
        ushort_t hi = bf16_rne(hv[e]);
        float hif = __uint_as_float(((uint_t)hi)<<16);
        ushort_t lo = bf16_rne(hv[e] - hif);
        a2h[e] = (short)hi;
        a2l[e] = (short)lo;
      }
      #pragma unroll
      for (int ct=0; ct<4; ++ct){
        short8 b2h = *(const short8*)&w2hiT[(size_t)(ct*16+ln)*128 + jp*32 + g*8];
        short8 b2l = *(const short8*)&w2loT[(size_t)(ct*16+ln)*128 + jp*32 + g*8];
        acc2[rt][ct] = __builtin_amdgcn_mfma_f32_16x16x32_bf16(a2h, b2h, acc2[rt][ct], 0,0,0);
        acc2[rt][ct] = __builtin_amdgcn_mfma_f32_16x16x32_bf16(a2l, b2h, acc2[rt][ct], 0,0,0);
        acc2[rt][ct] = __builtin_amdgcn_mfma_f32_16x16x32_bf16(a2h, b2l, acc2[rt][ct], 0,0,0);
      }
    }
  }
  #pragma unroll
  for (int ct=0; ct<4; ++ct){
    float bb = b2[ct*16 + ln];
    #pragma unroll
    for (int rt=0; rt<2; ++rt)
      #pragma unroll
      for (int i=0; i<4; ++i){
        int row = wid*32 + rt*16 + g*4 + i;
        size_t fiber = (size_t)vbid*128 + row;
        kbx[fiber*64 + ct*16 + ln] = gelu_f(bb + acc2[rt][ct][i]);
      }
  }
}

__global__ __launch_bounds__(256) void k_dmkbx(
    const float* __restrict__ x1, const int* __restrict__ nbrD,
    const ushort_t* __restrict__ dwThi, const ushort_t* __restrict__ dwTlo,
    const float* __restrict__ db, float* __restrict__ xA,
    const float* __restrict__ ps, const int* __restrict__ nbrS,
    const float* __restrict__ grid, const float* __restrict__ rff,
    const ushort_t* __restrict__ w1hiT, const ushort_t* __restrict__ w1loT,
    const ushort_t* __restrict__ w2hiT, const ushort_t* __restrict__ w2loT,
    const float* __restrict__ b1, const float* __restrict__ b2,
    float* __restrict__ kbx){
  __shared__ __align__(16) float um[12384];   // 49.5 KB union
  int bid = blockIdx.x;
  if (bid < B_*M_)
    dm_body(um, bid, x1, nbrD, dwThi, dwTlo, db, xA);
  else
    kbx_body(um, bid - B_*M_, ps, nbrS, grid, rff, w1hiT, w1loT, w2hiT, w2loT, b1, b2, kbx);
}

// ============ interaction layer (MFMA kx-apply) ============
__global__ __launch_bounds__(256) void k_inter(
    const float* __restrict__ xin, const int* __restrict__ nbr,
    const float* __restrict__ kbx, const float* __restrict__ kR,
    const ushort_t* __restrict__ kxhT, const ushort_t* __restrict__ kxlT,
    const float* __restrict__ kxb,
    const float* __restrict__ mw, const float* __restrict__ mb,
    float* __restrict__ xout){
  int bm = blockIdx.x; int b = bm / M_;
  int tid = threadIdx.x;
  int wid = tid>>6, lane = tid&63, ln = lane&15, g4 = lane>>4;
  int c = tid & 127, gh = tid >> 7;
  __shared__ float kbsL[48][68];
  __shared__ float Ts[48][130];
  __shared__ float aggS[NG_][C_];
  __shared__ float yS[NG_][C_];
  short8 bh[2][2], bl[2][2];
  float kxbv[2];
  #pragma unroll
  for (int nt=0; nt<2; ++nt){
    int cc_ = (wid*2+nt)*16 + ln;
    kxbv[nt] = kxb[cc_];
    #pragma unroll
    for (int ks=0; ks<2; ++ks){
      bh[nt][ks] = *(const short8*)&kxhT[(size_t)cc_*64 + ks*32 + g4*8];
      bl[nt][ks] = *(const short8*)&kxlT[(size_t)cc_*64 + ks*32 + g4*8];
    }
  }
  float accg[6] = {0,0,0,0,0,0};
  for (int cc=0; cc<4; ++cc){
    {
      const float4* src = (const float4*)(kbx + ((size_t)bm*192 + cc*48)*64);
      for (int idx=tid; idx<768; idx+=256){
        int r = idx >> 4, dq = idx & 15;
        *(float4*)&kbsL[r][dq*4] = src[idx];
      }
    }
    __syncthreads();
    floatx4 acc[3][2];
    #pragma unroll
    for (int mt=0; mt<3; ++mt)
      #pragma unroll
      for (int nt=0; nt<2; ++nt)
        acc[mt][nt] = (floatx4){0.f,0.f,0.f,0.f};
    #pragma unroll
    for (int mt=0; mt<3; ++mt){
      short8 ah[2], al[2];
      #pragma unroll
      for (int ks=0; ks<2; ++ks){
        float4 p0 = *(const float4*)&kbsL[mt*16+ln][ks*32+g4*8];
        float4 p1 = *(const float4*)&kbsL[mt*16+ln][ks*32+g4*8+4];
        float hv[8] = {p0.x,p0.y,p0.z,p0.w,p1.x,p1.y,p1.z,p1.w};
        #pragma unroll
        for (int e=0; e<8; ++e){
          ushort_t hi = bf16_rne(hv[e]);
          float hif = __uint_as_float(((uint_t)hi)<<16);
          ushort_t lo = bf16_rne(hv[e] - hif);
          ah[ks][e] = (short)hi;
          al[ks][e] = (short)lo;
        }
      }
      #pragma unroll
      for (int nt=0; nt<2; ++nt)
        #pragma unroll
        for (int ks=0; ks<2; ++ks){
          acc[mt][nt] = __builtin_amdgcn_mfma_f32_16x16x32_bf16(ah[ks], bh[nt][ks], acc[mt][nt], 0,0,0);
          acc[mt][nt] = __builtin_amdgcn_mfma_f32_16x16x32_bf16(al[ks], bh[nt][ks], acc[mt][nt], 0,0,0);
          acc[mt][nt] = __builtin_amdgcn_mfma_f32_16x16x32_bf16(ah[ks], bl[nt][ks], acc[mt][nt], 0,0,0);
        }
    }
    #pragma unroll
    for (int mt=0; mt<3; ++mt)
      #pragma unroll
      for (int nt=0; nt<2; ++nt)
        #pragma unroll
        for (int i=0; i<4; ++i)
          Ts[mt*16 + g4*4 + i][(wid*2+nt)*16 + ln] = acc[mt][nt][i] + kxbv[nt];
    __syncthreads();
    #pragma unroll
    for (int kl=0; kl<4; ++kl){
      int nb = nbr[(size_t)bm*K_ + cc*4 + kl];
      const float* xr = xin + ((size_t)(b*M_) + nb)*(NG_*C_);
      #pragma unroll
      for (int gi=0; gi<6; ++gi){
        int g = gh*6 + gi;
        accg[gi] = fmaf(Ts[kl*12+g][c], xr[g*C_ + c], accg[gi]);
      }
    }
    __syncthreads();
  }
  #pragma unroll
  for (int gi=0; gi<6; ++gi)
    aggS[gh*6+gi][c] = accg[gi] * (1.0f/16.0f);
  __syncthreads();
  #pragma unroll
  for (int gi=0; gi<6; ++gi){
    int g = gh*6+gi;
    float yv = 0.f;
    #pragma unroll
    for (int n=0;n<NG_;++n) yv = fmaf(aggS[n][c], kR[((size_t)g*NG_+n)*C_ + c], yv);
    yS[g][c] = yv * (1.0f/12.0f);
  }
  __syncthreads();
  float m6[6] = {0,0,0,0,0,0};
  for (int i4=0;i4<32;++i4){
    float w0 = mw[(i4*4+0)*C_+c], w1 = mw[(i4*4+1)*C_+c],
          w2 = mw[(i4*4+2)*C_+c], w3 = mw[(i4*4+3)*C_+c];
    #pragma unroll
    for (int gi=0;gi<6;++gi){
      int g = gh*6+gi;
      float4 yv = *(const float4*)&yS[g][i4*4];
      m6[gi] = fmaf(yv.x,w0,fmaf(yv.y,w1,fmaf(yv.z,w2,fmaf(yv.w,w3,m6[gi]))));
    }
  }
  float mbc = mb[c];
  #pragma unroll
  for (int gi=0;gi<6;++gi){
    int g = gh*6+gi;
    size_t off = (size_t)bm*(NG_*C_) + g*C_ + c;
    xout[off] = xin[off] + gelu_f(m6[gi] + mbc);
  }
}

// ============ readout ============
__global__ __launch_bounds__(256) void k_reduce(
    const float* __restrict__ x, float* __restrict__ part){
  int blk = blockIdx.x;
  int b = blk >> 6, ch = blk & 63;
  int tid = threadIdx.x;
  int c = tid & 127, half = tid >> 7;
  const float* xb = x + (size_t)b*(M_*NG_)*C_;
  int r0 = ch*96;
  float acc = 0.f;
  for (int r = r0 + half; r < r0 + 96; r += 2)
    acc += xb[(size_t)r*C_ + c];
  __shared__ float red[256];
  red[tid] = acc;
  __syncthreads();
  if (half == 0)
    part[(size_t)blk*C_ + c] = red[c] + red[128 + c];
}

__global__ __launch_bounds__(256) void k_head(
    const float* __restrict__ part,
    const float* __restrict__ p1w, const float* __restrict__ p1b,
    const float* __restrict__ p2w, const float* __restrict__ p2b,
    const float* __restrict__ p3w, const float* __restrict__ p3b,
    float* __restrict__ out){
  int b = blockIdx.x, tid = threadIdx.x;
  __shared__ float gs[128];
  if (tid < 128){
    float a = 0.f;
    const float* pb = part + (size_t)b*64*C_;
    for (int ch = 0; ch < 64; ++ch) a += pb[(size_t)ch*C_ + tid];
    gs[tid] = a * (1.0f/(M_*NG_));
  }
  __syncthreads();
  __shared__ float h1[256];
  {
    float a = p1b[tid];
    for (int i=0;i<128;++i) a = fmaf(gs[i], p1w[i*256+tid], a);
    h1[tid] = gelu_f(a);
  }
  __syncthreads();
  __shared__ float h2[64];
  if (tid<64){
    float a = p2b[tid];
    for (int i=0;i<256;++i) a = fmaf(h1[i], p2w[i*64+tid], a);
    h2[tid] = gelu_f(a);
  }
  __syncthreads();
  if (tid==0){
    float a = p3b[0];
    for (int i=0;i<64;++i) a = fmaf(h2[i], p3w[i], a);
    out[b] = a;
  }
}

extern "C" void kernel_launch(void* const* d_in, const int* in_sizes, int n_in,
                              void* d_out, int out_size, void* d_ws, size_t ws_size,
                              hipStream_t stream){
  const float* pos    = (const float*)d_in[0];
  const float* normal = (const float*)d_in[1];
  const float* grid   = (const float*)d_in[2];
  const float* e1w = (const float*)d_in[3];  const float* e1b = (const float*)d_in[4];
  const float* e2w = (const float*)d_in[5];  const float* e2b = (const float*)d_in[6];
  const float* dww = (const float*)d_in[7];  const float* dwb = (const float*)d_in[8];
  const float* bx_rff = (const float*)d_in[9];
  const float* bx1w = (const float*)d_in[10]; const float* bx1b = (const float*)d_in[11];
  const float* bx2w = (const float*)d_in[12]; const float* bx2b = (const float*)d_in[13];
  const float* bR_rff = (const float*)d_in[14];
  const float* bR1w = (const float*)d_in[15]; const float* bR1b = (const float*)d_in[16];
  const float* bR2w = (const float*)d_in[17]; const float* bR2b = (const float*)d_in[18];
  const float* i1kxw = (const float*)d_in[19]; const float* i1kxb = (const float*)d_in[20];
  const float* i1kRw = (const float*)d_in[21]; const float* i1kRb = (const float*)d_in[22];
  const float* i1mw  = (const float*)d_in[23]; const float* i1mb  = (const float*)d_in[24];
  const float* i2kxw = (const float*)d_in[25]; const float* i2kxb = (const float*)d_in[26];
  const float* i2kRw = (const float*)d_in[27]; const float* i2kRb = (const float*)d_in[28];
  const float* i2mw  = (const float*)d_in[29]; const float* i2mb  = (const float*)d_in[30];
  const float* p1w = (const float*)d_in[31]; const float* p1b = (const float*)d_in[32];
  const float* p2w = (const float*)d_in[33]; const float* p2b = (const float*)d_in[34];
  const float* p3w = (const float*)d_in[35]; const float* p3b = (const float*)d_in[36];
  float* out = (float*)d_out;

  float* ws = (float*)d_ws;
  size_t o = 0;
  float* x1  = ws + o; o += (size_t)B_*N_*NG_*H_;
  float* psb = ws + o; o += (size_t)B_*M_*3;
  float* xA  = ws + o; o += (size_t)B_*M_*NG_*C_;
  float* xB  = ws + o; o += (size_t)B_*M_*NG_*C_;
  float* kbx = ws + o; o += (size_t)B_*M_*K_*NG_*BD_;
  float* kbR = ws + o; o += (size_t)NG_*NG_*BD_;
  float* kRb1 = ws + o; o += (size_t)NG_*NG_*C_;
  float* kRb2 = ws + o; o += (size_t)NG_*NG_*C_;
  float* part = ws + o; o += (size_t)B_*64*C_;
  int* nbrD  = (int*)(ws + o); o += (size_t)B_*M_*K_;
  int* nbrS  = (int*)(ws + o); o += (size_t)B_*M_*K_;
  ushort_t* w1hiT = (ushort_t*)(ws + o); o += 8192;
  ushort_t* w1loT = (ushort_t*)(ws + o); o += 8192;
  ushort_t* w2hiT = (ushort_t*)(ws + o); o += 4096;
  ushort_t* w2loT = (ushort_t*)(ws + o); o += 4096;
  ushort_t* x1hiT = (ushort_t*)(ws + o); o += 4096;
  ushort_t* x1loT = (ushort_t*)(ws + o); o += 4096;
  ushort_t* x2hiT = (ushort_t*)(ws + o); o += 4096;
  ushort_t* x2loT = (ushort_t*)(ws + o); o += 4096;
  ushort_t* dwThi = (ushort_t*)(ws + o); o += 4096;
  ushort_t* dwTlo = (ushort_t*)(ws + o); o += 4096;

  k_mega1<<<FPSB + LIFTB + WSB + KBRB, 256, 0, stream>>>(
      pos, normal, grid, e1w, e1b, e2w, e2b, x1, psb,
      bx1w, bx2w, i1kxw, i2kxw, dww,
      w1hiT, w1loT, w2hiT, w2loT, x1hiT, x1loT, x2hiT, x2loT, dwThi, dwTlo,
      bR_rff, bR1w, bR1b, bR2w, bR2b, kbR);
  k_knn_all<<<2*B_*M_, 64, 0, stream>>>(psb, pos, nbrD, nbrS);
  k_kR2<<<2*KBRB, 128, 0, stream>>>(kbR, i1kRw, i1kRb, i2kRw, i2kRb, kRb1, kRb2);
  k_dmkbx<<<B_*M_ + (B_*M_*K_*NG_)/128, 256, 0, stream>>>(
      x1, nbrD, dwThi, dwTlo, dwb, xA,
      psb, nbrS, grid, bx_rff, w1hiT, w1loT, w2hiT, w2loT, bx1b, bx2b, kbx);
  k_inter<<<B_*M_, 256, 0, stream>>>(xA, nbrS, kbx, kRb1, x1hiT, x1loT, i1kxb, i1mw, i1mb, xB);
  k_inter<<<B_*M_, 256, 0, stream>>>(xB, nbrS, kbx, kRb2, x2hiT, x2loT, i2kxb, i2mw, i2mb, xA);
  k_reduce<<<B_*64, 256, 0, stream>>>(xA, part);
  k_head<<<B_, 256, 0, stream>>>(part, p1w, p1b, p2w, p2b, p3w, p3b, out);
}

// Round 9
// 793.698 us; speedup vs baseline: 1.7721x; 1.0114x over previous
//
#include <hip/hip_runtime.h>
#include <hip/hip_bf16.h>
#include <cfloat>

#define B_ 4
#define N_ 2048
#define NG_ 12
#define K_ 16
#define H_ 64
#define C_ 128
#define BD_ 64
#define M_ 512

typedef __attribute__((ext_vector_type(8))) short short8;
typedef __attribute__((ext_vector_type(4))) float floatx4;
typedef unsigned short ushort_t;
typedef unsigned int uint_t;

__device__ __forceinline__ float gelu_f(float x){
  float s = 0.7978845608028654f*(x + 0.044715f*x*x*x);
  float e = __expf(2.0f*s);
  float t = 1.0f - 2.0f/(e + 1.0f);
  return 0.5f*x*(1.0f + t);
}

__device__ __forceinline__ ushort_t bf16_rne(float x){
  uint_t u = __float_as_uint(x);
  uint_t r = (u + 0x7fffu + ((u >> 16) & 1u)) >> 16;
  return (ushort_t)r;
}

// pack fp32 -> (hi bf16) | (lo bf16 << 16)
__device__ __forceinline__ uint_t pack_hl(float x){
  ushort_t hi = bf16_rne(x);
  float hif = __uint_as_float(((uint_t)hi)<<16);
  ushort_t lo = bf16_rne(x - hif);
  return (uint_t)hi | ((uint_t)lo << 16);
}

// from packed uints a=(elem e+1), b=(elem e): lo16 halves -> hi-bf16 pair; hi16 halves -> lo-bf16 pair
__device__ __forceinline__ uint_t perm_lo16(uint_t a, uint_t b){ return __builtin_amdgcn_perm(a, b, 0x05040100u); }
__device__ __forceinline__ uint_t perm_hi16(uint_t a, uint_t b){ return __builtin_amdgcn_perm(a, b, 0x07060302u); }

#define UNPACK8(Q0, Q1, AH, AL) { \
  uint_t* _ap = (uint_t*)&(AH); uint_t* _lp = (uint_t*)&(AL); \
  _ap[0] = perm_lo16((Q0).y, (Q0).x); _ap[1] = perm_lo16((Q0).w, (Q0).z); \
  _ap[2] = perm_lo16((Q1).y, (Q1).x); _ap[3] = perm_lo16((Q1).w, (Q1).z); \
  _lp[0] = perm_hi16((Q0).y, (Q0).x); _lp[1] = perm_hi16((Q0).w, (Q0).z); \
  _lp[2] = perm_hi16((Q1).y, (Q1).x); _lp[3] = perm_hi16((Q1).w, (Q1).z); }

#define DPP_AMAX(CTRL) { \
  int _vb = __float_as_int(v); \
  int _ov = __builtin_amdgcn_update_dpp(_vb, _vb, (CTRL), 0xF, 0xF, false); \
  int _oi = __builtin_amdgcn_update_dpp(vi, vi, (CTRL), 0xF, 0xF, false); \
  float _of = __int_as_float(_ov); \
  bool _tk = (_of > v) || (_of == v && _oi < vi); \
  v = _tk ? _of : v; vi = _tk ? _oi : vi; }

#define DPP_AMIN(CTRL) { \
  int _vb = __float_as_int(v); \
  int _ov = __builtin_amdgcn_update_dpp(_vb, _vb, (CTRL), 0xF, 0xF, false); \
  int _oi = __builtin_amdgcn_update_dpp(vi, vi, (CTRL), 0xF, 0xF, false); \
  float _of = __int_as_float(_ov); \
  bool _tk = (_of < v) || (_of == v && _oi < vi); \
  v = _tk ? _of : v; vi = _tk ? _oi : vi; }

// ============ MEGA-KERNEL 1: fps + lift + wsplit + kbR/kR ============
#define FPSB 4
#define LIFTB (B_*N_*NG_/4)      // 6144
#define WSB 64
#define KBRB (NG_*NG_)           // 144

__global__ __launch_bounds__(256) void k_mega1(
    const float* __restrict__ pos, const float* __restrict__ normal,
    const float* __restrict__ grid,
    const float* __restrict__ e1w, const float* __restrict__ e1b,
    const float* __restrict__ e2w, const float* __restrict__ e2b,
    uint_t* __restrict__ x1p, float* __restrict__ ps,
    const float* __restrict__ bx1w, const float* __restrict__ bx2w,
    const float* __restrict__ kxw1, const float* __restrict__ kxw2,
    const float* __restrict__ dww,
    ushort_t* __restrict__ w1hiT, ushort_t* __restrict__ w1loT,
    ushort_t* __restrict__ w2hiT, ushort_t* __restrict__ w2loT,
    ushort_t* __restrict__ x1hiT, ushort_t* __restrict__ x1loT,
    ushort_t* __restrict__ x2hiT, ushort_t* __restrict__ x2loT,
    ushort_t* __restrict__ dwThi, ushort_t* __restrict__ dwTlo,
    const float* __restrict__ bR_rff,
    const float* __restrict__ bR1w, const float* __restrict__ bR1b,
    const float* __restrict__ bR2w, const float* __restrict__ bR2b,
    const float* __restrict__ kR1w, const float* __restrict__ kR1b,
    const float* __restrict__ kR2w, const float* __restrict__ kR2b,
    float* __restrict__ kRb1, float* __restrict__ kRb2){
  __shared__ float4 posS4[N_];        // fps
  __shared__ float2 wred[2][4];       // fps
  __shared__ float ts4[4][64];        // lift
  __shared__ float fsb[128], hsb[128];// kbR
  int bid = blockIdx.x;
  int tid = threadIdx.x;

  if (bid < FPSB){
    int b = bid;
    for (int i=tid;i<N_;i+=256){
      const float* p = pos + (size_t)b*N_*3 + (size_t)i*3;
      posS4[i] = make_float4(p[0], p[1], p[2], 0.f);
    }
    __syncthreads();
    float px[8],py[8],pz[8],d[8];
    #pragma unroll
    for (int j=0;j<8;++j){
      float4 pt = posS4[tid + 256*j];
      px[j]=pt.x; py[j]=pt.y; pz[j]=pt.z;
      d[j]=1e10f;
    }
    int wave = tid>>6, lane = tid&63;
    int last = 0;
    for (int s=0;s<M_;++s){
      float4 lp = posS4[last];
      float lx=lp.x, ly=lp.y, lz=lp.z;
      if (tid==0){ float* o = ps + ((size_t)b*M_+s)*3; o[0]=lx;o[1]=ly;o[2]=lz; }
      #pragma unroll
      for (int j=0;j<8;++j){
        float dx=__fsub_rn(px[j],lx), dy=__fsub_rn(py[j],ly), dz=__fsub_rn(pz[j],lz);
        float dist=__fadd_rn(__fadd_rn(__fmul_rn(dx,dx),__fmul_rn(dy,dy)),__fmul_rn(dz,dz));
        d[j]=fminf(d[j],dist);
      }
      if (s==M_-1) break;
      float va = d[1]>d[0]?d[1]:d[0]; int ja = d[1]>d[0]?1:0;
      float vb = d[3]>d[2]?d[3]:d[2]; int jb = d[3]>d[2]?3:2;
      float vc = d[5]>d[4]?d[5]:d[4]; int jc = d[5]>d[4]?5:4;
      float vd = d[7]>d[6]?d[7]:d[6]; int jd = d[7]>d[6]?7:6;
      float ve = vb>va?vb:va; int je = vb>va?jb:ja;
      float vf = vd>vc?vd:vc; int jf = vd>vc?jd:jc;
      float v  = vf>ve?vf:ve; int jj = vf>ve?jf:je;
      int vi = tid + (jj<<8);
      DPP_AMAX(0x121); DPP_AMAX(0x122); DPP_AMAX(0x124); DPP_AMAX(0x128);
      DPP_AMAX(0x142); DPP_AMAX(0x143);
      int sv = __builtin_amdgcn_readlane(__float_as_int(v), 63);
      int si = __builtin_amdgcn_readlane(vi, 63);
      if (lane==0) wred[s&1][wave] = make_float2(__int_as_float(sv), __int_as_float(si));
      __syncthreads();
      float2 r0 = wred[s&1][0], r1 = wred[s&1][1], r2 = wred[s&1][2], r3 = wred[s&1][3];
      float bv = r0.x; int bi = __float_as_int(r0.y);
      int i1 = __float_as_int(r1.y); if (r1.x>bv || (r1.x==bv && i1<bi)){ bv=r1.x; bi=i1; }
      int i2 = __float_as_int(r2.y); if (r2.x>bv || (r2.x==bv && i2<bi)){ bv=r2.x; bi=i2; }
      int i3 = __float_as_int(r3.y); if (r3.x>bv || (r3.x==bv && i3<bi)){ bv=r3.x; bi=i3; }
      last = bi;
    }
  } else if (bid < FPSB + LIFTB){
    int vbid = bid - FPSB;
    int q = tid>>6, lane = tid&63;
    int fid = vbid*4 + q;
    int g = fid % NG_;
    int n = (fid / NG_) % N_;
    int b = fid / (NG_*N_);
    const float* nm = normal + (size_t)(b*N_+n)*3;
    const float* pp = pos + (size_t)(b*N_+n)*3;
    const float* gg = grid + g*3;
    float f0 = nm[0]*gg[0] + nm[1]*gg[1] + nm[2]*gg[2];
    float t = e1b[lane] + f0*e1w[lane] + pp[0]*e1w[64+lane] + pp[1]*e1w[128+lane] + pp[2]*e1w[192+lane];
    ts4[q][lane] = gelu_f(t);
    __syncthreads();
    float acc = e2b[lane];
    #pragma unroll
    for (int i=0;i<64;++i) acc = fmaf(ts4[q][i], e2w[i*64+lane], acc);
    x1p[(size_t)fid*64 + lane] = pack_hl(acc);
  } else if (bid < FPSB + LIFTB + WSB){
    int tg = (bid - FPSB - LIFTB)*256 + tid;
    if (tg < 16384){
      int j = tg >> 7, k = tg & 127;
      float x = bx1w[k*128 + j];
      ushort_t hi = bf16_rne(x);
      float hif = __uint_as_float(((uint_t)hi)<<16);
      ushort_t lo = bf16_rne(x - hif);
      w1hiT[tg] = hi; w1loT[tg] = lo;
    }
    if (tg < 8192){
      int c = tg >> 7, j = tg & 127;
      float x = bx2w[j*64 + c];
      ushort_t hi = bf16_rne(x);
      float hif = __uint_as_float(((uint_t)hi)<<16);
      ushort_t lo = bf16_rne(x - hif);
      w2hiT[tg] = hi; w2loT[tg] = lo;
    }
    if (tg < 8192){
      int c = tg >> 6, d = tg & 63;
      float xa = kxw1[d*128 + c];
      ushort_t hi = bf16_rne(xa);
      float hif = __uint_as_float(((uint_t)hi)<<16);
      ushort_t lo = bf16_rne(xa - hif);
      x1hiT[tg] = hi; x1loT[tg] = lo;
      float xb = kxw2[d*128 + c];
      ushort_t hi2 = bf16_rne(xb);
      float hif2 = __uint_as_float(((uint_t)hi2)<<16);
      ushort_t lo2 = bf16_rne(xb - hif2);
      x2hiT[tg] = hi2; x2loT[tg] = lo2;
      float xd = dww[d*128 + c];
      ushort_t hi3 = bf16_rne(xd);
      float hif3 = __uint_as_float(((uint_t)hi3)<<16);
      ushort_t lo3 = bf16_rne(xd - hif3);
      dwThi[tg] = hi3; dwTlo[tg] = lo3;
    }
  } else {
    // kbR basis MLP + both kR layers (pair-local)
    int vbid = bid - FPSB - LIFTB - WSB;
    int gm = vbid / NG_, gn = vbid % NG_;
    int j = tid;
    if (j < 128){
      float z = grid[gm*3]*grid[gn*3] + grid[gm*3+1]*grid[gn*3+1] + grid[gm*3+2]*grid[gn*3+2];
      float ang = 6.283185307179586f * (z * bR_rff[j & 63]);
      fsb[j] = (j<64) ? sinf(ang) : cosf(ang);
    }
    __syncthreads();
    if (j < 128){
      float acc = bR1b[j];
      for (int i=0;i<128;++i) acc = fmaf(fsb[i], bR1w[i*128+j], acc);
      hsb[j] = gelu_f(acc);
    }
    __syncthreads();
    if (j < 64){
      float a2 = bR2b[j];
      for (int i=0;i<128;++i) a2 = fmaf(hsb[i], bR2w[i*64+j], a2);
      fsb[j] = gelu_f(a2);       // fsb reused: final kbR vector for this pair
    }
    __syncthreads();
    if (j < 128){
      float a1 = kR1b[j], a2v = kR2b[j];
      for (int d=0; d<64; ++d){
        float kv = fsb[d];
        a1  = fmaf(kv, kR1w[d*128+j], a1);
        a2v = fmaf(kv, kR2w[d*128+j], a2v);
      }
      kRb1[(size_t)vbid*128 + j] = a1;
      kRb2[(size_t)vbid*128 + j] = a2v;
    }
  }
}

// ============ KNN (both graphs in one dispatch) ============
template<int NP>
__device__ __forceinline__ void knn_body(int qm, const float* __restrict__ qp,
                                         const float* __restrict__ pool, int* __restrict__ out){
  constexpr int R = NP/64;
  int lane = threadIdx.x;
  int b = qm / M_;
  const float* q = qp + (size_t)qm*3;
  float qx=q[0], qy=q[1], qz=q[2];
  float d2[R];
  #pragma unroll
  for (int j=0;j<R;++j){
    int n = lane + 64*j;
    const float* p = pool + ((size_t)b*NP + n)*3;
    float dx=__fsub_rn(qx,p[0]), dy=__fsub_rn(qy,p[1]), dz=__fsub_rn(qz,p[2]);
    d2[j]=__fadd_rn(__fadd_rn(__fmul_rn(dx,dx),__fmul_rn(dy,dy)),__fmul_rn(dz,dz));
  }
  for (int r=0;r<K_;++r){
    float v=FLT_MAX; int vi=0x7fffffff;
    #pragma unroll
    for (int j=0;j<R;++j){
      if (d2[j]<v){ v=d2[j]; vi=lane+64*j; }
    }
    DPP_AMIN(0x121); DPP_AMIN(0x122); DPP_AMIN(0x124); DPP_AMIN(0x128);
    DPP_AMIN(0x142); DPP_AMIN(0x143);
    int si = __builtin_amdgcn_readlane(vi, 63);
    if (lane==0) out[(size_t)qm*K_ + r] = si;
    #pragma unroll
    for (int j=0;j<R;++j){ if (si == lane + 64*j) d2[j] = FLT_MAX; }
  }
}

__global__ __launch_bounds__(64) void k_knn_all(const float* __restrict__ psb,
    const float* __restrict__ pos, int* __restrict__ nbrD, int* __restrict__ nbrS){
  int bid = blockIdx.x;
  if (bid < B_*M_) knn_body<N_>(bid, psb, pos, nbrD);
  else             knn_body<M_>(bid - B_*M_, psb, psb, nbrS);
}

// ============ downmax (MFMA, packed x1) + kbx in one dispatch ============
__device__ __forceinline__ void dm_body(uint_t* um, int bm,
    const uint_t* __restrict__ x1p, const int* __restrict__ nbrD,
    const ushort_t* __restrict__ dwThi, const ushort_t* __restrict__ dwTlo,
    const float* __restrict__ db, float* __restrict__ xA){
  int b = bm / M_;
  int tid = threadIdx.x;
  uint_t* xs = um;                       // [16][768] packed, xor-swizzled granules
  int* nb = (int*)(um + 12288);
  if (tid < K_) nb[tid] = nbrD[(size_t)bm*K_ + tid];
  __syncthreads();
  for (int idx=tid; idx<3072; idx+=256){
    int k = idx / 192, qq = idx % 192;
    uint4 vv = ((const uint4*)&x1p[((size_t)(b*N_) + nb[k])*(NG_*H_)])[qq];
    int gran = (qq >> 1) ^ (k & 7);
    *(uint4*)&xs[k*768 + gran*8 + (qq&1)*4] = vv;
  }
  __syncthreads();
  int wid = tid>>6, lane = tid&63, ln = lane&15, g4 = lane>>4;
  short8 bh[2][2], bl[2][2];
  float dbv[2];
  #pragma unroll
  for (int nt=0; nt<2; ++nt){
    int col = wid*32 + nt*16 + ln;
    dbv[nt] = db[col];
    #pragma unroll
    for (int ks=0; ks<2; ++ks){
      bh[nt][ks] = *(const short8*)&dwThi[(size_t)col*64 + ks*32 + g4*8];
      bl[nt][ks] = *(const short8*)&dwTlo[(size_t)col*64 + ks*32 + g4*8];
    }
  }
  int xorl = ln & 7;
  #pragma unroll
  for (int g=0; g<NG_; ++g){
    short8 ah[2], al[2];
    #pragma unroll
    for (int ks=0; ks<2; ++ks){
      int col0 = g*64 + ks*32 + g4*8;
      int gran = (col0 >> 3) ^ xorl;
      const uint_t* src = &xs[ln*768 + gran*8];
      uint4 q0 = *(const uint4*)src;
      uint4 q1 = *(const uint4*)(src+4);
      UNPACK8(q0, q1, ah[ks], al[ks]);
    }
    floatx4 acc[2];
    acc[0] = (floatx4){0.f,0.f,0.f,0.f};
    acc[1] = (floatx4){0.f,0.f,0.f,0.f};
    #pragma unroll
    for (int nt=0; nt<2; ++nt)
      #pragma unroll
      for (int ks=0; ks<2; ++ks){
        acc[nt] = __builtin_amdgcn_mfma_f32_16x16x32_bf16(ah[ks], bh[nt][ks], acc[nt], 0,0,0);
        acc[nt] = __builtin_amdgcn_mfma_f32_16x16x32_bf16(al[ks], bh[nt][ks], acc[nt], 0,0,0);
        acc[nt] = __builtin_amdgcn_mfma_f32_16x16x32_bf16(ah[ks], bl[nt][ks], acc[nt], 0,0,0);
      }
    #pragma unroll
    for (int nt=0; nt<2; ++nt){
      float mx = fmaxf(fmaxf(acc[nt][0],acc[nt][1]), fmaxf(acc[nt][2],acc[nt][3]));
      mx = fmaxf(mx, __shfl_xor(mx, 16));
      mx = fmaxf(mx, __shfl_xor(mx, 32));
      if (g4 == 0)
        xA[(size_t)bm*(NG_*C_) + g*C_ + wid*32 + nt*16 + ln] = fmaxf(mx + dbv[nt], 0.0f);
    }
  }
}

__device__ __forceinline__ void kbx_body(float* um, int vbid,
    const float* __restrict__ ps, const int* __restrict__ nbr,
    const float* __restrict__ grid, const float* __restrict__ rff,
    const ushort_t* __restrict__ w1hiT, const ushort_t* __restrict__ w1loT,
    const ushort_t* __restrict__ w2hiT, const ushort_t* __restrict__ w2loT,
    const float* __restrict__ b1, const float* __restrict__ b2,
    uint_t* __restrict__ kbxp){
  float* z0s = um;
  float* z1s = um + 128;
  float* rws = um + 256;
  int tid = threadIdx.x;
  if (tid < 128){
    rws[tid] = rff[tid];
    int fid = vbid*128 + tid;
    int g = fid % NG_;
    int k = (fid/NG_) % K_;
    int bm = fid / (NG_*K_);
    int b = bm / M_;
    int nb = nbr[(size_t)bm*K_ + k];
    const float* pm = ps + (size_t)bm*3;
    const float* pn = ps + ((size_t)(b*M_) + nb)*3;
    float rx = pn[0]-pm[0], ry = pn[1]-pm[1], rz3 = pn[2]-pm[2];
    const float* gg = grid + g*3;
    float rz = rx*gg[0] + ry*gg[1] + rz3*gg[2];
    float vx = rx - rz*gg[0], vy = ry - rz*gg[1], vz = rz3 - rz*gg[2];
    float rxy = sqrtf(vx*vx + vy*vy + vz*vz + 1e-12f);
    z0s[tid]=rxy; z1s[tid]=rz;
  }
  __syncthreads();
  int wid = tid>>6, lane = tid&63;
  int ln = lane & 15, g = lane >> 4;
  float* bw = um + 384 + wid*1088;

  short8 ahi[2][4], alo[2][4];
  #pragma unroll
  for (int rt=0; rt<2; ++rt){
    float z0 = z0s[wid*32 + rt*16 + ln];
    float z1 = z1s[wid*32 + rt*16 + ln];
    #pragma unroll
    for (int ks=0; ks<4; ++ks){
      #pragma unroll
      for (int e=0; e<8; ++e){
        int kd = ks*32 + g*8 + e;
        int kk = kd & 63;
        float t = z0*rws[kk] + z1*rws[64+kk];
        t = t - floorf(t);
        float v = (ks < 2) ? __builtin_amdgcn_sinf(t) : __builtin_amdgcn_cosf(t);
        ushort_t hi = bf16_rne(v);
        float hif = __uint_as_float(((uint_t)hi)<<16);
        ushort_t lo = bf16_rne(v - hif);
        ahi[rt][ks][e] = (short)hi;
        alo[rt][ks][e] = (short)lo;
      }
    }
  }
  floatx4 acc2[2][4];
  #pragma unroll
  for (int rt=0; rt<2; ++rt)
    #pragma unroll
    for (int ct=0; ct<4; ++ct)
      acc2[rt][ct] = (floatx4){0.f,0.f,0.f,0.f};

  #pragma unroll
  for (int jp=0; jp<4; ++jp){
    floatx4 acc1[2][2];
    #pragma unroll
    for (int rt=0; rt<2; ++rt)
      #pragma unroll
      for (int jt=0; jt<2; ++jt)
        acc1[rt][jt] = (floatx4){0.f,0.f,0.f,0.f};
    #pragma unroll
    for (int ks=0; ks<4; ++ks){
      #pragma unroll
      for (int jt=0; jt<2; ++jt){
        int j = jp*32 + jt*16 + ln;
        short8 bhi = *(const short8*)&w1hiT[(size_t)j*128 + ks*32 + g*8];
        short8 blo = *(const short8*)&w1loT[(size_t)j*128 + ks*32 + g*8];
        #pragma unroll
        for (int rt=0; rt<2; ++rt){
          acc1[rt][jt] = __builtin_amdgcn_mfma_f32_16x16x32_bf16(ahi[rt][ks], bhi, acc1[rt][jt], 0,0,0);
          acc1[rt][jt] = __builtin_amdgcn_mfma_f32_16x16x32_bf16(alo[rt][ks], bhi, acc1[rt][jt], 0,0,0);
          acc1[rt][jt] = __builtin_amdgcn_mfma_f32_16x16x32_bf16(ahi[rt][ks], blo, acc1[rt][jt], 0,0,0);
        }
      }
    }
    #pragma unroll
    for (int jt=0; jt<2; ++jt){
      float bb = b1[jp*32 + jt*16 + ln];
      #pragma unroll
      for (int rt=0; rt<2; ++rt)
        #pragma unroll
        for (int i=0; i<4; ++i)
          bw[(rt*16 + g*4 + i)*34 + jt*16 + ln] = gelu_f(bb + acc1[rt][jt][i]);
    }
    #pragma unroll
    for (int rt=0; rt<2; ++rt){
      int base = (rt*16 + ln)*34 + g*8;
      float2 p0 = *(float2*)&bw[base+0];
      float2 p1 = *(float2*)&bw[base+2];
      float2 p2 = *(float2*)&bw[base+4];
      float2 p3 = *(float2*)&bw[base+6];
      float hv[8] = {p0.x,p0.y,p1.x,p1.y,p2.x,p2.y,p3.x,p3.y};
      short8 a2h, a2l;
      #pragma unroll
      for (int e=0; e<8; ++e){
        ushort_t hi = bf16_rne(hv[e]);
        float hif = __uint_as_float(((uint_t)hi)<<16);
        ushort_t lo = bf16_rne(hv[e] - hif);
        a2h[e] = (short)hi;
        a2l[e] = (short)lo;
      }
      #pragma unroll
      for (int ct=0; ct<4; ++ct){
        short8 b2h = *(const short8*)&w2hiT[(size_t)(ct*16+ln)*128 + jp*32 + g*8];
        short8 b2l = *(const short8*)&w2loT[(size_t)(ct*16+ln)*128 + jp*32 + g*8];
        acc2[rt][ct] = __builtin_amdgcn_mfma_f32_16x16x32_bf16(a2h, b2h, acc2[rt][ct], 0,0,0);
        acc2[rt][ct] = __builtin_amdgcn_mfma_f32_16x16x32_bf16(a2l, b2h, acc2[rt][ct], 0,0,0);
        acc2[rt][ct] = __builtin_amdgcn_mfma_f32_16x16x32_bf16(a2h, b2l, acc2[rt][ct], 0,0,0);
      }
    }
  }
  #pragma unroll
  for (int ct=0; ct<4; ++ct){
    float bb = b2[ct*16 + ln];
    #pragma unroll
    for (int rt=0; rt<2; ++rt)
      #pragma unroll
      for (int i=0; i<4; ++i){
        int row = wid*32 + rt*16 + g*4 + i;
        size_t fiber = (size_t)vbid*128 + row;
        kbxp[fiber*64 + ct*16 + ln] = pack_hl(gelu_f(bb + acc2[rt][ct][i]));
      }
  }
}

__global__ __launch_bounds__(256) void k_dmkbx(
    const uint_t* __restrict__ x1p, const int* __restrict__ nbrD,
    const ushort_t* __restrict__ dwThi, const ushort_t* __restrict__ dwTlo,
    const float* __restrict__ db, float* __restrict__ xA,
    const float* __restrict__ ps, const int* __restrict__ nbrS,
    const float* __restrict__ grid, const float* __restrict__ rff,
    const ushort_t* __restrict__ w1hiT, const ushort_t* __restrict__ w1loT,
    const ushort_t* __restrict__ w2hiT, const ushort_t* __restrict__ w2loT,
    const float* __restrict__ b1, const float* __restrict__ b2,
    uint_t* __restrict__ kbxp){
  __shared__ __align__(16) uint_t um[12384];   // 49.5 KB union
  int bid = blockIdx.x;
  if (bid < B_*M_)
    dm_body(um, bid, x1p, nbrD, dwThi, dwTlo, db, xA);
  else
    kbx_body((float*)um, bid - B_*M_, ps, nbrS, grid, rff, w1hiT, w1loT, w2hiT, w2loT, b1, b2, kbxp);
}

// ============ interaction layer (MFMA kx-apply, packed kbx) ============
__global__ __launch_bounds__(256) void k_inter(
    const float* __restrict__ xin, const int* __restrict__ nbr,
    const uint_t* __restrict__ kbxp, const float* __restrict__ kR,
    const ushort_t* __restrict__ kxhT, const ushort_t* __restrict__ kxlT,
    const float* __restrict__ kxb,
    const float* __restrict__ mw, const float* __restrict__ mb,
    float* __restrict__ xout, float* __restrict__ part){
  int bm = blockIdx.x; int b = bm / M_;
  int tid = threadIdx.x;
  int wid = tid>>6, lane = tid&63, ln = lane&15, g4 = lane>>4;
  int c = tid & 127, gh = tid >> 7;
  __shared__ uint_t kbsL[48][68];
  __shared__ float Ts[48][130];
  __shared__ float aggS[NG_][C_];
  __shared__ float yS[NG_][C_];
  __shared__ float psumS[2][C_];
  short8 bh[2][2], bl[2][2];
  float kxbv[2];
  #pragma unroll
  for (int nt=0; nt<2; ++nt){
    int cc_ = (wid*2+nt)*16 + ln;
    kxbv[nt] = kxb[cc_];
    #pragma unroll
    for (int ks=0; ks<2; ++ks){
      bh[nt][ks] = *(const short8*)&kxhT[(size_t)cc_*64 + ks*32 + g4*8];
      bl[nt][ks] = *(const short8*)&kxlT[(size_t)cc_*64 + ks*32 + g4*8];
    }
  }
  float accg[6] = {0,0,0,0,0,0};
  for (int cc=0; cc<4; ++cc){
    {
      const uint4* src = (const uint4*)(kbxp + ((size_t)bm*192 + cc*48)*64);
      for (int idx=tid; idx<768; idx+=256){
        int r = idx >> 4, dq = idx & 15;
        *(uint4*)&kbsL[r][dq*4] = src[idx];
      }
    }
    __syncthreads();
    floatx4 acc[3][2];
    #pragma unroll
    for (int mt=0; mt<3; ++mt)
      #pragma unroll
      for (int nt=0; nt<2; ++nt)
        acc[mt][nt] = (floatx4){0.f,0.f,0.f,0.f};
    #pragma unroll
    for (int mt=0; mt<3; ++mt){
      short8 ah[2], al[2];
      #pragma unroll
      for (int ks=0; ks<2; ++ks){
        const uint_t* src = &kbsL[mt*16+ln][ks*32+g4*8];
        uint4 q0 = *(const uint4*)src;
        uint4 q1 = *(const uint4*)(src+4);
        UNPACK8(q0, q1, ah[ks], al[ks]);
      }
      #pragma unroll
      for (int nt=0; nt<2; ++nt)
        #pragma unroll
        for (int ks=0; ks<2; ++ks){
          acc[mt][nt] = __builtin_amdgcn_mfma_f32_16x16x32_bf16(ah[ks], bh[nt][ks], acc[mt][nt], 0,0,0);
          acc[mt][nt] = __builtin_amdgcn_mfma_f32_16x16x32_bf16(al[ks], bh[nt][ks], acc[mt][nt], 0,0,0);
          acc[mt][nt] = __builtin_amdgcn_mfma_f32_16x16x32_bf16(ah[ks], bl[nt][ks], acc[mt][nt], 0,0,0);
        }
    }
    #pragma unroll
    for (int mt=0; mt<3; ++mt)
      #pragma unroll
      for (int nt=0; nt<2; ++nt)
        #pragma unroll
        for (int i=0; i<4; ++i)
          Ts[mt*16 + g4*4 + i][(wid*2+nt)*16 + ln] = acc[mt][nt][i] + kxbv[nt];
    __syncthreads();
    #pragma unroll
    for (int kl=0; kl<4; ++kl){
      int nb = nbr[(size_t)bm*K_ + cc*4 + kl];
      const float* xr = xin + ((size_t)(b*M_) + nb)*(NG_*C_);
      #pragma unroll
      for (int gi=0; gi<6; ++gi){
        int g = gh*6 + gi;
        accg[gi] = fmaf(Ts[kl*12+g][c], xr[g*C_ + c], accg[gi]);
      }
    }
    __syncthreads();
  }
  #pragma unroll
  for (int gi=0; gi<6; ++gi)
    aggS[gh*6+gi][c] = accg[gi] * (1.0f/16.0f);
  __syncthreads();
  #pragma unroll
  for (int gi=0; gi<6; ++gi){
    int g = gh*6+gi;
    float yv = 0.f;
    #pragma unroll
    for (int n=0;n<NG_;++n) yv = fmaf(aggS[n][c], kR[((size_t)g*NG_+n)*C_ + c], yv);
    yS[g][c] = yv * (1.0f/12.0f);
  }
  __syncthreads();
  float m6[6] = {0,0,0,0,0,0};
  for (int i4=0;i4<32;++i4){
    float w0 = mw[(i4*4+0)*C_+c], w1 = mw[(i4*4+1)*C_+c],
          w2 = mw[(i4*4+2)*C_+c], w3 = mw[(i4*4+3)*C_+c];
    #pragma unroll
    for (int gi=0;gi<6;++gi){
      int g = gh*6+gi;
      float4 yv = *(const float4*)&yS[g][i4*4];
      m6[gi] = fmaf(yv.x,w0,fmaf(yv.y,w1,fmaf(yv.z,w2,fmaf(yv.w,w3,m6[gi]))));
    }
  }
  float mbc = mb[c];
  float psum = 0.f;
  #pragma unroll
  for (int gi=0;gi<6;++gi){
    int g = gh*6+gi;
    size_t off = (size_t)bm*(NG_*C_) + g*C_ + c;
    float val = xin[off] + gelu_f(m6[gi] + mbc);
    xout[off] = val;
    psum += val;
  }
  if (part){
    psumS[gh][c] = psum;
    __syncthreads();
    if (gh == 0)
      part[(size_t)bm*C_ + c] = psumS[0][c] + psumS[1][c];
  }
}

// ============ head: 512-row reduce + MLP ============
__global__ __launch_bounds__(256) void k_head(
    const float* __restrict__ part,
    const float* __restrict__ p1w, const float* __restrict__ p1b,
    const float* __restrict__ p2w, const float* __restrict__ p2b,
    const float* __restrict__ p3w, const float* __restrict__ p3b,
    float* __restrict__ out){
  int b = blockIdx.x, tid = threadIdx.x;
  int c = tid & 127, half = tid >> 7;
  __shared__ float red[256];
  __shared__ float gs[128];
  {
    const float* pb = part + (size_t)b*M_*C_;
    float a0=0.f,a1=0.f,a2=0.f,a3=0.f;
    for (int r = half*4; r < M_; r += 8){
      a0 += pb[(size_t)(r+0)*C_ + c];
      a1 += pb[(size_t)(r+1)*C_ + c];
      a2 += pb[(size_t)(r+2)*C_ + c];
      a3 += pb[(size_t)(r+3)*C_ + c];
    }
    red[tid] = (a0+a1)+(a2+a3);
  }
  __syncthreads();
  if (half==0) gs[c] = (red[c] + red[128+c]) * (1.0f/(M_*NG_));
  __syncthreads();
  __shared__ float h1[256];
  {
    float a = p1b[tid];
    for (int i=0;i<128;++i) a = fmaf(gs[i], p1w[i*256+tid], a);
    h1[tid] = gelu_f(a);
  }
  __syncthreads();
  __shared__ float h2[64];
  if (tid<64){
    float a = p2b[tid];
    for (int i=0;i<256;++i) a = fmaf(h1[i], p2w[i*64+tid], a);
    h2[tid] = gelu_f(a);
  }
  __syncthreads();
  if (tid==0){
    float a = p3b[0];
    for (int i=0;i<64;++i) a = fmaf(h2[i], p3w[i], a);
    out[b] = a;
  }
}

extern "C" void kernel_launch(void* const* d_in, const int* in_sizes, int n_in,
                              void* d_out, int out_size, void* d_ws, size_t ws_size,
                              hipStream_t stream){
  const float* pos    = (const float*)d_in[0];
  const float* normal = (const float*)d_in[1];
  const float* grid   = (const float*)d_in[2];
  const float* e1w = (const float*)d_in[3];  const float* e1b = (const float*)d_in[4];
  const float* e2w = (const float*)d_in[5];  const float* e2b = (const float*)d_in[6];
  const float* dww = (const float*)d_in[7];  const float* dwb = (const float*)d_in[8];
  const float* bx_rff = (const float*)d_in[9];
  const float* bx1w = (const float*)d_in[10]; const float* bx1b = (const float*)d_in[11];
  const float* bx2w = (const float*)d_in[12]; const float* bx2b = (const float*)d_in[13];
  const float* bR_rff = (const float*)d_in[14];
  const float* bR1w = (const float*)d_in[15]; const float* bR1b = (const float*)d_in[16];
  const float* bR2w = (const float*)d_in[17]; const float* bR2b = (const float*)d_in[18];
  const float* i1kxw = (const float*)d_in[19]; const float* i1kxb = (const float*)d_in[20];
  const float* i1kRw = (const float*)d_in[21]; const float* i1kRb = (const float*)d_in[22];
  const float* i1mw  = (const float*)d_in[23]; const float* i1mb  = (const float*)d_in[24];
  const float* i2kxw = (const float*)d_in[25]; const float* i2kxb = (const float*)d_in[26];
  const float* i2kRw = (const float*)d_in[27]; const float* i2kRb = (const float*)d_in[28];
  const float* i2mw  = (const float*)d_in[29]; const float* i2mb  = (const float*)d_in[30];
  const float* p1w = (const float*)d_in[31]; const float* p1b = (const float*)d_in[32];
  const float* p2w = (const float*)d_in[33]; const float* p2b = (const float*)d_in[34];
  const float* p3w = (const float*)d_in[35]; const float* p3b = (const float*)d_in[36];
  float* out = (float*)d_out;

  float* ws = (float*)d_ws;
  size_t o = 0;
  uint_t* x1p = (uint_t*)(ws + o); o += (size_t)B_*N_*NG_*H_;     // packed bf16 hi/lo
  float* psb = ws + o; o += (size_t)B_*M_*3;
  float* xA  = ws + o; o += (size_t)B_*M_*NG_*C_;
  float* xB  = ws + o; o += (size_t)B_*M_*NG_*C_;
  uint_t* kbxp = (uint_t*)(ws + o); o += (size_t)B_*M_*K_*NG_*BD_; // packed
  float* kRb1 = ws + o; o += (size_t)NG_*NG_*C_;
  float* kRb2 = ws + o; o += (size_t)NG_*NG_*C_;
  float* part = ws + o; o += (size_t)B_*M_*C_;                     // 262144
  int* nbrD  = (int*)(ws + o); o += (size_t)B_*M_*K_;
  int* nbrS  = (int*)(ws + o); o += (size_t)B_*M_*K_;
  ushort_t* w1hiT = (ushort_t*)(ws + o); o += 8192;
  ushort_t* w1loT = (ushort_t*)(ws + o); o += 8192;
  ushort_t* w2hiT = (ushort_t*)(ws + o); o += 4096;
  ushort_t* w2loT = (ushort_t*)(ws + o); o += 4096;
  ushort_t* x1hiT = (ushort_t*)(ws + o); o += 4096;
  ushort_t* x1loT = (ushort_t*)(ws + o); o += 4096;
  ushort_t* x2hiT = (ushort_t*)(ws + o); o += 4096;
  ushort_t* x2loT = (ushort_t*)(ws + o); o += 4096;
  ushort_t* dwThi = (ushort_t*)(ws + o); o += 4096;
  ushort_t* dwTlo = (ushort_t*)(ws + o); o += 4096;

  k_mega1<<<FPSB + LIFTB + WSB + KBRB, 256, 0, stream>>>(
      pos, normal, grid, e1w, e1b, e2w, e2b, x1p, psb,
      bx1w, bx2w, i1kxw, i2kxw, dww,
      w1hiT, w1loT, w2hiT, w2loT, x1hiT, x1loT, x2hiT, x2loT, dwThi, dwTlo,
      bR_rff, bR1w, bR1b, bR2w, bR2b,
      i1kRw, i1kRb, i2kRw, i2kRb, kRb1, kRb2);
  k_knn_all<<<2*B_*M_, 64, 0, stream>>>(psb, pos, nbrD, nbrS);
  k_dmkbx<<<B_*M_ + (B_*M_*K_*NG_)/128, 256, 0, stream>>>(
      x1p, nbrD, dwThi, dwTlo, dwb, xA,
      psb, nbrS, grid, bx_rff, w1hiT, w1loT, w2hiT, w2loT, bx1b, bx2b, kbxp);
  k_inter<<<B_*M_, 256, 0, stream>>>(xA, nbrS, kbxp, kRb1, x1hiT, x1loT, i1kxb, i1mw, i1mb, xB, nullptr);
  k_inter<<<B_*M_, 256, 0, stream>>>(xB, nbrS, kbxp, kRb2, x2hiT, x2loT, i2kxb, i2mw, i2mb, xA, part);
  k_head<<<B_, 256, 0, stream>>>(part, p1w, p1b, p2w, p2b, p3w, p3b, out);
}

// Round 10
// 750.577 us; speedup vs baseline: 1.8739x; 1.0575x over previous
//
#include <hip/hip_runtime.h>
#include <hip/hip_bf16.h>
#include <cfloat>

#define B_ 4
#define N_ 2048
#define NG_ 12
#define K_ 16
#define H_ 64
#define C_ 128
#define BD_ 64
#define M_ 512

typedef __attribute__((ext_vector_type(8))) short short8;
typedef __attribute__((ext_vector_type(4))) float floatx4;
typedef unsigned short ushort_t;
typedef unsigned int uint_t;

__device__ __forceinline__ float gelu_f(float x){
  float s = 0.7978845608028654f*(x + 0.044715f*x*x*x);
  float e = __expf(2.0f*s);
  float t = 1.0f - 2.0f/(e + 1.0f);
  return 0.5f*x*(1.0f + t);
}

__device__ __forceinline__ ushort_t bf16_rne(float x){
  uint_t u = __float_as_uint(x);
  uint_t r = (u + 0x7fffu + ((u >> 16) & 1u)) >> 16;
  return (ushort_t)r;
}

// pack fp32 -> (hi bf16) | (lo bf16 << 16)
__device__ __forceinline__ uint_t pack_hl(float x){
  ushort_t hi = bf16_rne(x);
  float hif = __uint_as_float(((uint_t)hi)<<16);
  ushort_t lo = bf16_rne(x - hif);
  return (uint_t)hi | ((uint_t)lo << 16);
}

__device__ __forceinline__ uint_t perm_lo16(uint_t a, uint_t b){ return __builtin_amdgcn_perm(a, b, 0x05040100u); }
__device__ __forceinline__ uint_t perm_hi16(uint_t a, uint_t b){ return __builtin_amdgcn_perm(a, b, 0x07060302u); }

#define UNPACK8(Q0, Q1, AH, AL) { \
  uint_t* _ap = (uint_t*)&(AH); uint_t* _lp = (uint_t*)&(AL); \
  _ap[0] = perm_lo16((Q0).y, (Q0).x); _ap[1] = perm_lo16((Q0).w, (Q0).z); \
  _ap[2] = perm_lo16((Q1).y, (Q1).x); _ap[3] = perm_lo16((Q1).w, (Q1).z); \
  _lp[0] = perm_hi16((Q0).y, (Q0).x); _lp[1] = perm_hi16((Q0).w, (Q0).z); \
  _lp[2] = perm_hi16((Q1).y, (Q1).x); _lp[3] = perm_hi16((Q1).w, (Q1).z); }

#define DPP_AMAX(CTRL) { \
  int _vb = __float_as_int(v); \
  int _ov = __builtin_amdgcn_update_dpp(_vb, _vb, (CTRL), 0xF, 0xF, false); \
  int _oi = __builtin_amdgcn_update_dpp(vi, vi, (CTRL), 0xF, 0xF, false); \
  float _of = __int_as_float(_ov); \
  bool _tk = (_of > v) || (_of == v && _oi < vi); \
  v = _tk ? _of : v; vi = _tk ? _oi : vi; }

#define DPP_AMIN(CTRL) { \
  int _vb = __float_as_int(v); \
  int _ov = __builtin_amdgcn_update_dpp(_vb, _vb, (CTRL), 0xF, 0xF, false); \
  int _oi = __builtin_amdgcn_update_dpp(vi, vi, (CTRL), 0xF, 0xF, false); \
  float _of = __int_as_float(_ov); \
  bool _tk = (_of < v) || (_of == v && _oi < vi); \
  v = _tk ? _of : v; vi = _tk ? _oi : vi; }

// ============ MEGA-KERNEL 1: fps + lift + wsplit + kbR/kR ============
#define FPSB 4
#define LIFTB (B_*N_*NG_/4)      // 6144
#define WSB 64
#define KBRB (NG_*NG_)           // 144

__global__ __launch_bounds__(256) void k_mega1(
    const float* __restrict__ pos, const float* __restrict__ normal,
    const float* __restrict__ grid,
    const float* __restrict__ e1w, const float* __restrict__ e1b,
    const float* __restrict__ e2w, const float* __restrict__ e2b,
    uint_t* __restrict__ x1p, float* __restrict__ ps,
    const float* __restrict__ bx1w, const float* __restrict__ bx2w,
    const float* __restrict__ kxw1, const float* __restrict__ kxw2,
    const float* __restrict__ dww,
    ushort_t* __restrict__ w1hiT, ushort_t* __restrict__ w1loT,
    ushort_t* __restrict__ w2hiT, ushort_t* __restrict__ w2loT,
    ushort_t* __restrict__ x1hiT, ushort_t* __restrict__ x1loT,
    ushort_t* __restrict__ x2hiT, ushort_t* __restrict__ x2loT,
    ushort_t* __restrict__ dwThi, ushort_t* __restrict__ dwTlo,
    const float* __restrict__ bR_rff,
    const float* __restrict__ bR1w, const float* __restrict__ bR1b,
    const float* __restrict__ bR2w, const float* __restrict__ bR2b,
    const float* __restrict__ kR1w, const float* __restrict__ kR1b,
    const float* __restrict__ kR2w, const float* __restrict__ kR2b,
    float* __restrict__ kRb1, float* __restrict__ kRb2){
  __shared__ float4 posS4[N_];        // fps
  __shared__ float2 wred[2][4];       // fps
  __shared__ int sidxS[M_];           // fps sample indices (2 KB)
  __shared__ float ts4[4][64];        // lift
  __shared__ float fsb[128], hsb[128];// kbR
  int bid = blockIdx.x;
  int tid = threadIdx.x;

  if (bid < FPSB){
    // ---- FPS: NO global memory ops inside the loop (barrier drains stay cheap)
    int b = bid;
    for (int i=tid;i<N_;i+=256){
      const float* p = pos + (size_t)b*N_*3 + (size_t)i*3;
      posS4[i] = make_float4(p[0], p[1], p[2], 0.f);
    }
    __syncthreads();
    float px[8],py[8],pz[8],d[8];
    #pragma unroll
    for (int j=0;j<8;++j){
      float4 pt = posS4[tid + 256*j];
      px[j]=pt.x; py[j]=pt.y; pz[j]=pt.z;
      d[j]=1e10f;
    }
    int wave = tid>>6, lane = tid&63;
    int last = 0;
    for (int s=0;s<M_;++s){
      if (tid==0) sidxS[s] = last;
      if (s==M_-1) break;
      float4 lp = posS4[last];
      float lx=lp.x, ly=lp.y, lz=lp.z;
      #pragma unroll
      for (int j=0;j<8;++j){
        float dx=__fsub_rn(px[j],lx), dy=__fsub_rn(py[j],ly), dz=__fsub_rn(pz[j],lz);
        float dist=__fadd_rn(__fadd_rn(__fmul_rn(dx,dx),__fmul_rn(dy,dy)),__fmul_rn(dz,dz));
        d[j]=fminf(d[j],dist);
      }
      float va = d[1]>d[0]?d[1]:d[0]; int ja = d[1]>d[0]?1:0;
      float vb = d[3]>d[2]?d[3]:d[2]; int jb = d[3]>d[2]?3:2;
      float vc = d[5]>d[4]?d[5]:d[4]; int jc = d[5]>d[4]?5:4;
      float vd = d[7]>d[6]?d[7]:d[6]; int jd = d[7]>d[6]?7:6;
      float ve = vb>va?vb:va; int je = vb>va?jb:ja;
      float vf = vd>vc?vd:vc; int jf = vd>vc?jd:jc;
      float v  = vf>ve?vf:ve; int jj = vf>ve?jf:je;
      int vi = tid + (jj<<8);
      DPP_AMAX(0x121); DPP_AMAX(0x122); DPP_AMAX(0x124); DPP_AMAX(0x128);
      DPP_AMAX(0x142); DPP_AMAX(0x143);
      int sv = __builtin_amdgcn_readlane(__float_as_int(v), 63);
      int si = __builtin_amdgcn_readlane(vi, 63);
      if (lane==0) wred[s&1][wave] = make_float2(__int_as_float(sv), __int_as_float(si));
      __syncthreads();
      float2 r0 = wred[s&1][0], r1 = wred[s&1][1], r2 = wred[s&1][2], r3 = wred[s&1][3];
      float bv = r0.x; int bi = __float_as_int(r0.y);
      int i1 = __float_as_int(r1.y); if (r1.x>bv || (r1.x==bv && i1<bi)){ bv=r1.x; bi=i1; }
      int i2 = __float_as_int(r2.y); if (r2.x>bv || (r2.x==bv && i2<bi)){ bv=r2.x; bi=i2; }
      int i3 = __float_as_int(r3.y); if (r3.x>bv || (r3.x==bv && i3<bi)){ bv=r3.x; bi=i3; }
      last = bi;
    }
    __syncthreads();
    // bulk write of sample coordinates
    for (int i=tid; i<M_; i+=256){
      float4 p = posS4[sidxS[i]];
      float* o = ps + ((size_t)b*M_+i)*3;
      o[0]=p.x; o[1]=p.y; o[2]=p.z;
    }
  } else if (bid < FPSB + LIFTB){
    int vbid = bid - FPSB;
    int q = tid>>6, lane = tid&63;
    int fid = vbid*4 + q;
    int g = fid % NG_;
    int n = (fid / NG_) % N_;
    int b = fid / (NG_*N_);
    const float* nm = normal + (size_t)(b*N_+n)*3;
    const float* pp = pos + (size_t)(b*N_+n)*3;
    const float* gg = grid + g*3;
    float f0 = nm[0]*gg[0] + nm[1]*gg[1] + nm[2]*gg[2];
    float t = e1b[lane] + f0*e1w[lane] + pp[0]*e1w[64+lane] + pp[1]*e1w[128+lane] + pp[2]*e1w[192+lane];
    ts4[q][lane] = gelu_f(t);
    __syncthreads();
    float acc = e2b[lane];
    #pragma unroll
    for (int i=0;i<64;++i) acc = fmaf(ts4[q][i], e2w[i*64+lane], acc);
    x1p[(size_t)fid*64 + lane] = pack_hl(acc);
  } else if (bid < FPSB + LIFTB + WSB){
    int tg = (bid - FPSB - LIFTB)*256 + tid;
    if (tg < 16384){
      int j = tg >> 7, k = tg & 127;
      float x = bx1w[k*128 + j];
      ushort_t hi = bf16_rne(x);
      float hif = __uint_as_float(((uint_t)hi)<<16);
      ushort_t lo = bf16_rne(x - hif);
      w1hiT[tg] = hi; w1loT[tg] = lo;
    }
    if (tg < 8192){
      int c = tg >> 7, j = tg & 127;
      float x = bx2w[j*64 + c];
      ushort_t hi = bf16_rne(x);
      float hif = __uint_as_float(((uint_t)hi)<<16);
      ushort_t lo = bf16_rne(x - hif);
      w2hiT[tg] = hi; w2loT[tg] = lo;
    }
    if (tg < 8192){
      int c = tg >> 6, d = tg & 63;
      float xa = kxw1[d*128 + c];
      ushort_t hi = bf16_rne(xa);
      float hif = __uint_as_float(((uint_t)hi)<<16);
      ushort_t lo = bf16_rne(xa - hif);
      x1hiT[tg] = hi; x1loT[tg] = lo;
      float xb = kxw2[d*128 + c];
      ushort_t hi2 = bf16_rne(xb);
      float hif2 = __uint_as_float(((uint_t)hi2)<<16);
      ushort_t lo2 = bf16_rne(xb - hif2);
      x2hiT[tg] = hi2; x2loT[tg] = lo2;
      float xd = dww[d*128 + c];
      ushort_t hi3 = bf16_rne(xd);
      float hif3 = __uint_as_float(((uint_t)hi3)<<16);
      ushort_t lo3 = bf16_rne(xd - hif3);
      dwThi[tg] = hi3; dwTlo[tg] = lo3;
    }
  } else {
    // kbR basis MLP + both kR layers (pair-local)
    int vbid = bid - FPSB - LIFTB - WSB;
    int gm = vbid / NG_, gn = vbid % NG_;
    int j = tid;
    if (j < 128){
      float z = grid[gm*3]*grid[gn*3] + grid[gm*3+1]*grid[gn*3+1] + grid[gm*3+2]*grid[gn*3+2];
      float ang = 6.283185307179586f * (z * bR_rff[j & 63]);
      fsb[j] = (j<64) ? sinf(ang) : cosf(ang);
    }
    __syncthreads();
    if (j < 128){
      float acc = bR1b[j];
      for (int i=0;i<128;++i) acc = fmaf(fsb[i], bR1w[i*128+j], acc);
      hsb[j] = gelu_f(acc);
    }
    __syncthreads();
    if (j < 64){
      float a2 = bR2b[j];
      for (int i=0;i<128;++i) a2 = fmaf(hsb[i], bR2w[i*64+j], a2);
      fsb[j] = gelu_f(a2);       // fsb reused: final kbR vector for this pair
    }
    __syncthreads();
    if (j < 128){
      float a1 = kR1b[j], a2v = kR2b[j];
      for (int d=0; d<64; ++d){
        float kv = fsb[d];
        a1  = fmaf(kv, kR1w[d*128+j], a1);
        a2v = fmaf(kv, kR2w[d*128+j], a2v);
      }
      kRb1[(size_t)vbid*128 + j] = a1;
      kRb2[(size_t)vbid*128 + j] = a2v;
    }
  }
}

// ============ KNN (both graphs in one dispatch) ============
template<int NP>
__device__ __forceinline__ void knn_body(int qm, const float* __restrict__ qp,
                                         const float* __restrict__ pool, int* __restrict__ out){
  constexpr int R = NP/64;
  int lane = threadIdx.x;
  int b = qm / M_;
  const float* q = qp + (size_t)qm*3;
  float qx=q[0], qy=q[1], qz=q[2];
  float d2[R];
  #pragma unroll
  for (int j=0;j<R;++j){
    int n = lane + 64*j;
    const float* p = pool + ((size_t)b*NP + n)*3;
    float dx=__fsub_rn(qx,p[0]), dy=__fsub_rn(qy,p[1]), dz=__fsub_rn(qz,p[2]);
    d2[j]=__fadd_rn(__fadd_rn(__fmul_rn(dx,dx),__fmul_rn(dy,dy)),__fmul_rn(dz,dz));
  }
  for (int r=0;r<K_;++r){
    float v=FLT_MAX; int vi=0x7fffffff;
    #pragma unroll
    for (int j=0;j<R;++j){
      if (d2[j]<v){ v=d2[j]; vi=lane+64*j; }
    }
    DPP_AMIN(0x121); DPP_AMIN(0x122); DPP_AMIN(0x124); DPP_AMIN(0x128);
    DPP_AMIN(0x142); DPP_AMIN(0x143);
    int si = __builtin_amdgcn_readlane(vi, 63);
    if (lane==0) out[(size_t)qm*K_ + r] = si;
    #pragma unroll
    for (int j=0;j<R;++j){ if (si == lane + 64*j) d2[j] = FLT_MAX; }
  }
}

__global__ __launch_bounds__(64) void k_knn_all(const float* __restrict__ psb,
    const float* __restrict__ pos, int* __restrict__ nbrD, int* __restrict__ nbrS){
  int bid = blockIdx.x;
  if (bid < B_*M_) knn_body<N_>(bid, psb, pos, nbrD);
  else             knn_body<M_>(bid - B_*M_, psb, psb, nbrS);
}

// ============ downmax (MFMA, packed x1) + kbx in one dispatch ============
__device__ __forceinline__ void dm_body(uint_t* um, int bm,
    const uint_t* __restrict__ x1p, const int* __restrict__ nbrD,
    const ushort_t* __restrict__ dwThi, const ushort_t* __restrict__ dwTlo,
    const float* __restrict__ db, float* __restrict__ xA){
  int b = bm / M_;
  int tid = threadIdx.x;
  uint_t* xs = um;                       // [16][768] packed, xor-swizzled granules
  int* nb = (int*)(um + 12288);
  if (tid < K_) nb[tid] = nbrD[(size_t)bm*K_ + tid];
  __syncthreads();
  for (int idx=tid; idx<3072; idx+=256){
    int k = idx / 192, qq = idx % 192;
    uint4 vv = ((const uint4*)&x1p[((size_t)(b*N_) + nb[k])*(NG_*H_)])[qq];
    int gran = (qq >> 1) ^ (k & 7);
    *(uint4*)&xs[k*768 + gran*8 + (qq&1)*4] = vv;
  }
  __syncthreads();
  int wid = tid>>6, lane = tid&63, ln = lane&15, g4 = lane>>4;
  short8 bh[2][2], bl[2][2];
  float dbv[2];
  #pragma unroll
  for (int nt=0; nt<2; ++nt){
    int col = wid*32 + nt*16 + ln;
    dbv[nt] = db[col];
    #pragma unroll
    for (int ks=0; ks<2; ++ks){
      bh[nt][ks] = *(const short8*)&dwThi[(size_t)col*64 + ks*32 + g4*8];
      bl[nt][ks] = *(const short8*)&dwTlo[(size_t)col*64 + ks*32 + g4*8];
    }
  }
  int xorl = ln & 7;
  #pragma unroll
  for (int g=0; g<NG_; ++g){
    short8 ah[2], al[2];
    #pragma unroll
    for (int ks=0; ks<2; ++ks){
      int col0 = g*64 + ks*32 + g4*8;
      int gran = (col0 >> 3) ^ xorl;
      const uint_t* src = &xs[ln*768 + gran*8];
      uint4 q0 = *(const uint4*)src;
      uint4 q1 = *(const uint4*)(src+4);
      UNPACK8(q0, q1, ah[ks], al[ks]);
    }
    floatx4 acc[2];
    acc[0] = (floatx4){0.f,0.f,0.f,0.f};
    acc[1] = (floatx4){0.f,0.f,0.f,0.f};
    #pragma unroll
    for (int nt=0; nt<2; ++nt)
      #pragma unroll
      for (int ks=0; ks<2; ++ks){
        acc[nt] = __builtin_amdgcn_mfma_f32_16x16x32_bf16(ah[ks], bh[nt][ks], acc[nt], 0,0,0);
        acc[nt] = __builtin_amdgcn_mfma_f32_16x16x32_bf16(al[ks], bh[nt][ks], acc[nt], 0,0,0);
        acc[nt] = __builtin_amdgcn_mfma_f32_16x16x32_bf16(ah[ks], bl[nt][ks], acc[nt], 0,0,0);
      }
    #pragma unroll
    for (int nt=0; nt<2; ++nt){
      float mx = fmaxf(fmaxf(acc[nt][0],acc[nt][1]), fmaxf(acc[nt][2],acc[nt][3]));
      mx = fmaxf(mx, __shfl_xor(mx, 16));
      mx = fmaxf(mx, __shfl_xor(mx, 32));
      if (g4 == 0)
        xA[(size_t)bm*(NG_*C_) + g*C_ + wid*32 + nt*16 + ln] = fmaxf(mx + dbv[nt], 0.0f);
    }
  }
}

__device__ __forceinline__ void kbx_body(float* um, int vbid,
    const float* __restrict__ ps, const int* __restrict__ nbr,
    const float* __restrict__ grid, const float* __restrict__ rff,
    const ushort_t* __restrict__ w1hiT, const ushort_t* __restrict__ w1loT,
    const ushort_t* __restrict__ w2hiT, const ushort_t* __restrict__ w2loT,
    const float* __restrict__ b1, const float* __restrict__ b2,
    uint_t* __restrict__ kbxp){
  float* z0s = um;
  float* z1s = um + 128;
  float* rws = um + 256;
  int tid = threadIdx.x;
  if (tid < 128){
    rws[tid] = rff[tid];
    int fid = vbid*128 + tid;
    int g = fid % NG_;
    int k = (fid/NG_) % K_;
    int bm = fid / (NG_*K_);
    int b = bm / M_;
    int nb = nbr[(size_t)bm*K_ + k];
    const float* pm = ps + (size_t)bm*3;
    const float* pn = ps + ((size_t)(b*M_) + nb)*3;
    float rx = pn[0]-pm[0], ry = pn[1]-pm[1], rz3 = pn[2]-pm[2];
    const float* gg = grid + g*3;
    float rz = rx*gg[0] + ry*gg[1] + rz3*gg[2];
    float vx = rx - rz*gg[0], vy = ry - rz*gg[1], vz = rz3 - rz*gg[2];
    float rxy = sqrtf(vx*vx + vy*vy + vz*vz + 1e-12f);
    z0s[tid]=rxy; z1s[tid]=rz;
  }
  __syncthreads();
  int wid = tid>>6, lane = tid&63;
  int ln = lane & 15, g = lane >> 4;
  float* bw = um + 384 + wid*1088;

  short8 ahi[2][4], alo[2][4];
  #pragma unroll
  for (int rt=0; rt<2; ++rt){
    float z0 = z0s[wid*32 + rt*16 + ln];
    float z1 = z1s[wid*32 + rt*16 + ln];
    #pragma unroll
    for (int ks=0; ks<4; ++ks){
      #pragma unroll
      for (int e=0; e<8; ++e){
        int kd = ks*32 + g*8 + e;
        int kk = kd & 63;
        float t = z0*rws[kk] + z1*rws[64+kk];
        t = t - floorf(t);
        float v = (ks < 2) ? __builtin_amdgcn_sinf(t) : __builtin_amdgcn_cosf(t);
        ushort_t hi = bf16_rne(v);
        float hif = __uint_as_float(((uint_t)hi)<<16);
        ushort_t lo = bf16_rne(v - hif);
        ahi[rt][ks][e] = (short)hi;
        alo[rt][ks][e] = (short)lo;
      }
    }
  }
  floatx4 acc2[2][4];
  #pragma unroll
  for (int rt=0; rt<2; ++rt)
    #pragma unroll
    for (int ct=0; ct<4; ++ct)
      acc2[rt][ct] = (floatx4){0.f,0.f,0.f,0.f};

  #pragma unroll
  for (int jp=0; jp<4; ++jp){
    floatx4 acc1[2][2];
    #pragma unroll
    for (int rt=0; rt<2; ++rt)
      #pragma unroll
      for (int jt=0; jt<2; ++jt)
        acc1[rt][jt] = (floatx4){0.f,0.f,0.f,0.f};
    #pragma unroll
    for (int ks=0; ks<4; ++ks){
      #pragma unroll
      for (int jt=0; jt<2; ++jt){
        int j = jp*32 + jt*16 + ln;
        short8 bhi = *(const short8*)&w1hiT[(size_t)j*128 + ks*32 + g*8];
        short8 blo = *(const short8*)&w1loT[(size_t)j*128 + ks*32 + g*8];
        #pragma unroll
        for (int rt=0; rt<2; ++rt){
          acc1[rt][jt] = __builtin_amdgcn_mfma_f32_16x16x32_bf16(ahi[rt][ks], bhi, acc1[rt][jt], 0,0,0);
          acc1[rt][jt] = __builtin_amdgcn_mfma_f32_16x16x32_bf16(alo[rt][ks], bhi, acc1[rt][jt], 0,0,0);
          acc1[rt][jt] = __builtin_amdgcn_mfma_f32_16x16x32_bf16(ahi[rt][ks], blo, acc1[rt][jt], 0,0,0);
        }
      }
    }
    #pragma unroll
    for (int jt=0; jt<2; ++jt){
      float bb = b1[jp*32 + jt*16 + ln];
      #pragma unroll
      for (int rt=0; rt<2; ++rt)
        #pragma unroll
        for (int i=0; i<4; ++i)
          bw[(rt*16 + g*4 + i)*34 + jt*16 + ln] = gelu_f(bb + acc1[rt][jt][i]);
    }
    #pragma unroll
    for (int rt=0; rt<2; ++rt){
      int base = (rt*16 + ln)*34 + g*8;
      float2 p0 = *(float2*)&bw[base+0];
      float2 p1 = *(float2*)&bw[base+2];
      float2 p2 = *(float2*)&bw[base+4];
      float2 p3 = *(float2*)&bw[base+6];
      float hv[8] = {p0.x,p0.y,p1.x,p1.y,p2.x,p2.y,p3.x,p3.y};
      short8 a2h, a2l;
      #pragma unroll
      for (int e=0; e<8; ++e){
        ushort_t hi = bf16_rne(hv[e]);
        float hif = __uint_as_float(((uint_t)hi)<<16);
        ushort_t lo = bf16_rne(hv[e] - hif);
        a2h[e] = (short)hi;
        a2l[e] = (short)lo;
      }
      #pragma unroll
      for (int ct=0; ct<4; ++ct){
        short8 b2h = *(const short8*)&w2hiT[(size_t)(ct*16+ln)*128 + jp*32 + g*8];
        short8 b2l = *(const short8*)&w2loT[(size_t)(ct*16+ln)*128 + jp*32 + g*8];
        acc2[rt][ct] = __builtin_amdgcn_mfma_f32_16x16x32_bf16(a2h, b2h, acc2[rt][ct], 0,0,0);
        acc2[rt][ct] = __builtin_amdgcn_mfma_f32_16x16x32_bf16(a2l, b2h, acc2[rt][ct], 0,0,0);
        acc2[rt][ct] = __builtin_amdgcn_mfma_f32_16x16x32_bf16(a2h, b2l, acc2[rt][ct], 0,0,0);
      }
    }
  }
  #pragma unroll
  for (int ct=0; ct<4; ++ct){
    float bb = b2[ct*16 + ln];
    #pragma unroll
    for (int rt=0; rt<2; ++rt)
      #pragma unroll
      for (int i=0; i<4; ++i){
        int row = wid*32 + rt*16 + g*4 + i;
        size_t fiber = (size_t)vbid*128 + row;
        kbxp[fiber*64 + ct*16 + ln] = pack_hl(gelu_f(bb + acc2[rt][ct][i]));
      }
  }
}

__global__ __launch_bounds__(256) void k_dmkbx(
    const uint_t* __restrict__ x1p, const int* __restrict__ nbrD,
    const ushort_t* __restrict__ dwThi, const ushort_t* __restrict__ dwTlo,
    const float* __restrict__ db, float* __restrict__ xA,
    const float* __restrict__ ps, const int* __restrict__ nbrS,
    const float* __restrict__ grid, const float* __restrict__ rff,
    const ushort_t* __restrict__ w1hiT, const ushort_t* __restrict__ w1loT,
    const ushort_t* __restrict__ w2hiT, const ushort_t* __restrict__ w2loT,
    const float* __restrict__ b1, const float* __restrict__ b2,
    uint_t* __restrict__ kbxp){
  __shared__ __align__(16) uint_t um[12384];   // 49.5 KB union
  int bid = blockIdx.x;
  if (bid < B_*M_)
    dm_body(um, bid, x1p, nbrD, dwThi, dwTlo, db, xA);
  else
    kbx_body((float*)um, bid - B_*M_, ps, nbrS, grid, rff, w1hiT, w1loT, w2hiT, w2loT, b1, b2, kbxp);
}

// ============ interaction layer (MFMA kx-apply, T14 register prefetch) ============
__global__ __launch_bounds__(256) void k_inter(
    const float* __restrict__ xin, const int* __restrict__ nbr,
    const uint_t* __restrict__ kbxp, const float* __restrict__ kR,
    const ushort_t* __restrict__ kxhT, const ushort_t* __restrict__ kxlT,
    const float* __restrict__ kxb,
    const float* __restrict__ mw, const float* __restrict__ mb,
    float* __restrict__ xout, float* __restrict__ part){
  int bm = blockIdx.x; int b = bm / M_;
  int tid = threadIdx.x;
  int wid = tid>>6, lane = tid&63, ln = lane&15, g4 = lane>>4;
  int c = tid & 127, gh = tid >> 7;
  __shared__ uint_t kbsL[48][68];
  __shared__ float Ts[48][130];
  __shared__ float aggS[NG_][C_];
  __shared__ float yS[NG_][C_];
  __shared__ float psumS[2][C_];

  const uint4* ksrc = (const uint4*)(kbxp + (size_t)bm*192*64);

  // prologue: kbx chunk 0 -> regs; nbr chunk 0 -> scalars (latency overlaps B-frag setup)
  uint4 ka = ksrc[tid], kbv = ksrc[tid+256], kc = ksrc[tid+512];
  int nb0 = nbr[(size_t)bm*K_+0], nb1 = nbr[(size_t)bm*K_+1],
      nb2 = nbr[(size_t)bm*K_+2], nb3 = nbr[(size_t)bm*K_+3];

  short8 bh[2][2], bl[2][2];
  float kxbv[2];
  #pragma unroll
  for (int nt=0; nt<2; ++nt){
    int cc_ = (wid*2+nt)*16 + ln;
    kxbv[nt] = kxb[cc_];
    #pragma unroll
    for (int ks=0; ks<2; ++ks){
      bh[nt][ks] = *(const short8*)&kxhT[(size_t)cc_*64 + ks*32 + g4*8];
      bl[nt][ks] = *(const short8*)&kxlT[(size_t)cc_*64 + ks*32 + g4*8];
    }
  }
  float accg[6] = {0,0,0,0,0,0};

  for (int cc=0; cc<4; ++cc){
    // write prefetched kbx regs -> LDS
    {
      int i0=tid, i1=tid+256, i2=tid+512;
      *(uint4*)&kbsL[i0>>4][(i0&15)*4] = ka;
      *(uint4*)&kbsL[i1>>4][(i1&15)*4] = kbv;
      *(uint4*)&kbsL[i2>>4][(i2&15)*4] = kc;
    }
    __syncthreads();   // A: kbsL ready
    // issue prefetches: kbx chunk cc+1, nbr chunk cc+1, xin values for THIS chunk
    float xreg[24];
    {
      const float* xr0 = xin + ((size_t)(b*M_) + nb0)*(NG_*C_);
      const float* xr1 = xin + ((size_t)(b*M_) + nb1)*(NG_*C_);
      const float* xr2 = xin + ((size_t)(b*M_) + nb2)*(NG_*C_);
      const float* xr3 = xin + ((size_t)(b*M_) + nb3)*(NG_*C_);
      #pragma unroll
      for (int gi=0; gi<6; ++gi){
        int off = (gh*6+gi)*C_ + c;
        xreg[0*6+gi] = xr0[off];
        xreg[1*6+gi] = xr1[off];
        xreg[2*6+gi] = xr2[off];
        xreg[3*6+gi] = xr3[off];
      }
    }
    if (cc < 3){
      ka  = ksrc[(cc+1)*768 + tid];
      kbv = ksrc[(cc+1)*768 + tid + 256];
      kc  = ksrc[(cc+1)*768 + tid + 512];
      nb0 = nbr[(size_t)bm*K_ + (cc+1)*4 + 0];
      nb1 = nbr[(size_t)bm*K_ + (cc+1)*4 + 1];
      nb2 = nbr[(size_t)bm*K_ + (cc+1)*4 + 2];
      nb3 = nbr[(size_t)bm*K_ + (cc+1)*4 + 3];
    }
    // MFMA phase (covers prefetch latency)
    floatx4 acc[3][2];
    #pragma unroll
    for (int mt=0; mt<3; ++mt)
      #pragma unroll
      for (int nt=0; nt<2; ++nt)
        acc[mt][nt] = (floatx4){0.f,0.f,0.f,0.f};
    #pragma unroll
    for (int mt=0; mt<3; ++mt){
      short8 ah[2], al[2];
      #pragma unroll
      for (int ks=0; ks<2; ++ks){
        const uint_t* src = &kbsL[mt*16+ln][ks*32+g4*8];
        uint4 q0 = *(const uint4*)src;
        uint4 q1 = *(const uint4*)(src+4);
        UNPACK8(q0, q1, ah[ks], al[ks]);
      }
      #pragma unroll
      for (int nt=0; nt<2; ++nt)
        #pragma unroll
        for (int ks=0; ks<2; ++ks){
          acc[mt][nt] = __builtin_amdgcn_mfma_f32_16x16x32_bf16(ah[ks], bh[nt][ks], acc[mt][nt], 0,0,0);
          acc[mt][nt] = __builtin_amdgcn_mfma_f32_16x16x32_bf16(al[ks], bh[nt][ks], acc[mt][nt], 0,0,0);
          acc[mt][nt] = __builtin_amdgcn_mfma_f32_16x16x32_bf16(ah[ks], bl[nt][ks], acc[mt][nt], 0,0,0);
        }
    }
    #pragma unroll
    for (int mt=0; mt<3; ++mt)
      #pragma unroll
      for (int nt=0; nt<2; ++nt)
        #pragma unroll
        for (int i=0; i<4; ++i)
          Ts[mt*16 + g4*4 + i][(wid*2+nt)*16 + ln] = acc[mt][nt][i] + kxbv[nt];
    __syncthreads();   // B: Ts ready (drain cheap: loads covered by MFMA)
    // agg: pure reg + LDS
    #pragma unroll
    for (int kl=0; kl<4; ++kl)
      #pragma unroll
      for (int gi=0; gi<6; ++gi)
        accg[gi] = fmaf(Ts[kl*12 + gh*6 + gi][c], xreg[kl*6+gi], accg[gi]);
  }
  __syncthreads();
  #pragma unroll
  for (int gi=0; gi<6; ++gi)
    aggS[gh*6+gi][c] = accg[gi] * (1.0f/16.0f);
  __syncthreads();
  #pragma unroll
  for (int gi=0; gi<6; ++gi){
    int g = gh*6+gi;
    float yv = 0.f;
    #pragma unroll
    for (int n=0;n<NG_;++n) yv = fmaf(aggS[n][c], kR[((size_t)g*NG_+n)*C_ + c], yv);
    yS[g][c] = yv * (1.0f/12.0f);
  }
  __syncthreads();
  float m6[6] = {0,0,0,0,0,0};
  for (int i4=0;i4<32;++i4){
    float w0 = mw[(i4*4+0)*C_+c], w1 = mw[(i4*4+1)*C_+c],
          w2 = mw[(i4*4+2)*C_+c], w3 = mw[(i4*4+3)*C_+c];
    #pragma unroll
    for (int gi=0;gi<6;++gi){
      int g = gh*6+gi;
      float4 yv = *(const float4*)&yS[g][i4*4];
      m6[gi] = fmaf(yv.x,w0,fmaf(yv.y,w1,fmaf(yv.z,w2,fmaf(yv.w,w3,m6[gi]))));
    }
  }
  float mbc = mb[c];
  float psum = 0.f;
  #pragma unroll
  for (int gi=0;gi<6;++gi){
    int g = gh*6+gi;
    size_t off = (size_t)bm*(NG_*C_) + g*C_ + c;
    float val = xin[off] + gelu_f(m6[gi] + mbc);
    xout[off] = val;
    psum += val;
  }
  if (part){
    psumS[gh][c] = psum;
    __syncthreads();
    if (gh == 0)
      part[(size_t)bm*C_ + c] = psumS[0][c] + psumS[1][c];
  }
}

// ============ head: 512-row reduce + MLP ============
__global__ __launch_bounds__(256) void k_head(
    const float* __restrict__ part,
    const float* __restrict__ p1w, const float* __restrict__ p1b,
    const float* __restrict__ p2w, const float* __restrict__ p2b,
    const float* __restrict__ p3w, const float* __restrict__ p3b,
    float* __restrict__ out){
  int b = blockIdx.x, tid = threadIdx.x;
  int c = tid & 127, half = tid >> 7;
  __shared__ float red[256];
  __shared__ float gs[128];
  {
    const float* pb = part + (size_t)b*M_*C_;
    float a0=0.f,a1=0.f,a2=0.f,a3=0.f;
    for (int r = half*4; r < M_; r += 8){
      a0 += pb[(size_t)(r+0)*C_ + c];
      a1 += pb[(size_t)(r+1)*C_ + c];
      a2 += pb[(size_t)(r+2)*C_ + c];
      a3 += pb[(size_t)(r+3)*C_ + c];
    }
    red[tid] = (a0+a1)+(a2+a3);
  }
  __syncthreads();
  if (half==0) gs[c] = (red[c] + red[128+c]) * (1.0f/(M_*NG_));
  __syncthreads();
  __shared__ float h1[256];
  {
    float a = p1b[tid];
    for (int i=0;i<128;++i) a = fmaf(gs[i], p1w[i*256+tid], a);
    h1[tid] = gelu_f(a);
  }
  __syncthreads();
  __shared__ float h2[64];
  if (tid<64){
    float a = p2b[tid];
    for (int i=0;i<256;++i) a = fmaf(h1[i], p2w[i*64+tid], a);
    h2[tid] = gelu_f(a);
  }
  __syncthreads();
  if (tid==0){
    float a = p3b[0];
    for (int i=0;i<64;++i) a = fmaf(h2[i], p3w[i], a);
    out[b] = a;
  }
}

extern "C" void kernel_launch(void* const* d_in, const int* in_sizes, int n_in,
                              void* d_out, int out_size, void* d_ws, size_t ws_size,
                              hipStream_t stream){
  const float* pos    = (const float*)d_in[0];
  const float* normal = (const float*)d_in[1];
  const float* grid   = (const float*)d_in[2];
  const float* e1w = (const float*)d_in[3];  const float* e1b = (const float*)d_in[4];
  const float* e2w = (const float*)d_in[5];  const float* e2b = (const float*)d_in[6];
  const float* dww = (const float*)d_in[7];  const float* dwb = (const float*)d_in[8];
  const float* bx_rff = (const float*)d_in[9];
  const float* bx1w = (const float*)d_in[10]; const float* bx1b = (const float*)d_in[11];
  const float* bx2w = (const float*)d_in[12]; const float* bx2b = (const float*)d_in[13];
  const float* bR_rff = (const float*)d_in[14];
  const float* bR1w = (const float*)d_in[15]; const float* bR1b = (const float*)d_in[16];
  const float* bR2w = (const float*)d_in[17]; const float* bR2b = (const float*)d_in[18];
  const float* i1kxw = (const float*)d_in[19]; const float* i1kxb = (const float*)d_in[20];
  const float* i1kRw = (const float*)d_in[21]; const float* i1kRb = (const float*)d_in[22];
  const float* i1mw  = (const float*)d_in[23]; const float* i1mb  = (const float*)d_in[24];
  const float* i2kxw = (const float*)d_in[25]; const float* i2kxb = (const float*)d_in[26];
  const float* i2kRw = (const float*)d_in[27]; const float* i2kRb = (const float*)d_in[28];
  const float* i2mw  = (const float*)d_in[29]; const float* i2mb  = (const float*)d_in[30];
  const float* p1w = (const float*)d_in[31]; const float* p1b = (const float*)d_in[32];
  const float* p2w = (const float*)d_in[33]; const float* p2b = (const float*)d_in[34];
  const float* p3w = (const float*)d_in[35]; const float* p3b = (const float*)d_in[36];
  float* out = (float*)d_out;

  float* ws = (float*)d_ws;
  size_t o = 0;
  uint_t* x1p = (uint_t*)(ws + o); o += (size_t)B_*N_*NG_*H_;     // packed bf16 hi/lo
  float* psb = ws + o; o += (size_t)B_*M_*3;
  float* xA  = ws + o; o += (size_t)B_*M_*NG_*C_;
  float* xB  = ws + o; o += (size_t)B_*M_*NG_*C_;
  uint_t* kbxp = (uint_t*)(ws + o); o += (size_t)B_*M_*K_*NG_*BD_; // packed
  float* kRb1 = ws + o; o += (size_t)NG_*NG_*C_;
  float* kRb2 = ws + o; o += (size_t)NG_*NG_*C_;
  float* part = ws + o; o += (size_t)B_*M_*C_;                     // 262144
  int* nbrD  = (int*)(ws + o); o += (size_t)B_*M_*K_;
  int* nbrS  = (int*)(ws + o); o += (size_t)B_*M_*K_;
  ushort_t* w1hiT = (ushort_t*)(ws + o); o += 8192;
  ushort_t* w1loT = (ushort_t*)(ws + o); o += 8192;
  ushort_t* w2hiT = (ushort_t*)(ws + o); o += 4096;
  ushort_t* w2loT = (ushort_t*)(ws + o); o += 4096;
  ushort_t* x1hiT = (ushort_t*)(ws + o); o += 4096;
  ushort_t* x1loT = (ushort_t*)(ws + o); o += 4096;
  ushort_t* x2hiT = (ushort_t*)(ws + o); o += 4096;
  ushort_t* x2loT = (ushort_t*)(ws + o); o += 4096;
  ushort_t* dwThi = (ushort_t*)(ws + o); o += 4096;
  ushort_t* dwTlo = (ushort_t*)(ws + o); o += 4096;

  k_mega1<<<FPSB + LIFTB + WSB + KBRB, 256, 0, stream>>>(
      pos, normal, grid, e1w, e1b, e2w, e2b, x1p, psb,
      bx1w, bx2w, i1kxw, i2kxw, dww,
      w1hiT, w1loT, w2hiT, w2loT, x1hiT, x1loT, x2hiT, x2loT, dwThi, dwTlo,
      bR_rff, bR1w, bR1b, bR2w, bR2b,
      i1kRw, i1kRb, i2kRw, i2kRb, kRb1, kRb2);
  k_knn_all<<<2*B_*M_, 64, 0, stream>>>(psb, pos, nbrD, nbrS);
  k_dmkbx<<<B_*M_ + (B_*M_*K_*NG_)/128, 256, 0, stream>>>(
      x1p, nbrD, dwThi, dwTlo, dwb, xA,
      psb, nbrS, grid, bx_rff, w1hiT, w1loT, w2hiT, w2loT, bx1b, bx2b, kbxp);
  k_inter<<<B_*M_, 256, 0, stream>>>(xA, nbrS, kbxp, kRb1, x1hiT, x1loT, i1kxb, i1mw, i1mb, xB, nullptr);
  k_inter<<<B_*M_, 256, 0, stream>>>(xB, nbrS, kbxp, kRb2, x2hiT, x2loT, i2kxb, i2mw, i2mb, xA, part);
  k_head<<<B_, 256, 0, stream>>>(part, p1w, p1b, p2w, p2b, p3w, p3b, out);
}

// Round 11
// 736.060 us; speedup vs baseline: 1.9108x; 1.0197x over previous
//
#include <hip/hip_runtime.h>
#include <hip/hip_bf16.h>
#include <cfloat>

#define B_ 4
#define N_ 2048
#define NG_ 12
#define K_ 16
#define H_ 64
#define C_ 128
#define BD_ 64
#define M_ 512

typedef __attribute__((ext_vector_type(8))) short short8;
typedef __attribute__((ext_vector_type(4))) float floatx4;
typedef unsigned short ushort_t;
typedef unsigned int uint_t;

__device__ __forceinline__ float gelu_f(float x){
  float s = 0.7978845608028654f*(x + 0.044715f*x*x*x);
  float e = __expf(2.0f*s);
  float t = 1.0f - 2.0f/(e + 1.0f);
  return 0.5f*x*(1.0f + t);
}

__device__ __forceinline__ ushort_t bf16_rne(float x){
  uint_t u = __float_as_uint(x);
  uint_t r = (u + 0x7fffu + ((u >> 16) & 1u)) >> 16;
  return (ushort_t)r;
}

// pack fp32 -> (hi bf16) | (lo bf16 << 16)
__device__ __forceinline__ uint_t pack_hl(float x){
  ushort_t hi = bf16_rne(x);
  float hif = __uint_as_float(((uint_t)hi)<<16);
  ushort_t lo = bf16_rne(x - hif);
  return (uint_t)hi | ((uint_t)lo << 16);
}

__device__ __forceinline__ uint_t perm_lo16(uint_t a, uint_t b){ return __builtin_amdgcn_perm(a, b, 0x05040100u); }
__device__ __forceinline__ uint_t perm_hi16(uint_t a, uint_t b){ return __builtin_amdgcn_perm(a, b, 0x07060302u); }

#define UNPACK8(Q0, Q1, AH, AL) { \
  uint_t* _ap = (uint_t*)&(AH); uint_t* _lp = (uint_t*)&(AL); \
  _ap[0] = perm_lo16((Q0).y, (Q0).x); _ap[1] = perm_lo16((Q0).w, (Q0).z); \
  _ap[2] = perm_lo16((Q1).y, (Q1).x); _ap[3] = perm_lo16((Q1).w, (Q1).z); \
  _lp[0] = perm_hi16((Q0).y, (Q0).x); _lp[1] = perm_hi16((Q0).w, (Q0).z); \
  _lp[2] = perm_hi16((Q1).y, (Q1).x); _lp[3] = perm_hi16((Q1).w, (Q1).z); }

#define DPP_AMAX(CTRL) { \
  int _vb = __float_as_int(v); \
  int _ov = __builtin_amdgcn_update_dpp(_vb, _vb, (CTRL), 0xF, 0xF, false); \
  int _oi = __builtin_amdgcn_update_dpp(vi, vi, (CTRL), 0xF, 0xF, false); \
  float _of = __int_as_float(_ov); \
  bool _tk = (_of > v) || (_of == v && _oi < vi); \
  v = _tk ? _of : v; vi = _tk ? _oi : vi; }

#define DPP_AMIN(CTRL) { \
  int _vb = __float_as_int(v); \
  int _ov = __builtin_amdgcn_update_dpp(_vb, _vb, (CTRL), 0xF, 0xF, false); \
  int _oi = __builtin_amdgcn_update_dpp(vi, vi, (CTRL), 0xF, 0xF, false); \
  float _of = __int_as_float(_ov); \
  bool _tk = (_of < v) || (_of == v && _oi < vi); \
  v = _tk ? _of : v; vi = _tk ? _oi : vi; }

// ============ MEGA-KERNEL 1: fps + lift + wsplit + kbR/kR + pos4 ============
#define FPSB 4
#define LIFTB (B_*N_*NG_/4)      // 6144
#define WSB 64
#define KBRB (NG_*NG_)           // 144
#define PM4B 32

__global__ __launch_bounds__(256) void k_mega1(
    const float* __restrict__ pos, const float* __restrict__ normal,
    const float* __restrict__ grid,
    const float* __restrict__ e1w, const float* __restrict__ e1b,
    const float* __restrict__ e2w, const float* __restrict__ e2b,
    uint_t* __restrict__ x1p, float* __restrict__ ps,
    float4* __restrict__ pos4, float4* __restrict__ ps4,
    const float* __restrict__ bx1w, const float* __restrict__ bx2w,
    const float* __restrict__ kxw1, const float* __restrict__ kxw2,
    const float* __restrict__ dww,
    ushort_t* __restrict__ w1hiT, ushort_t* __restrict__ w1loT,
    ushort_t* __restrict__ w2hiT, ushort_t* __restrict__ w2loT,
    ushort_t* __restrict__ x1hiT, ushort_t* __restrict__ x1loT,
    ushort_t* __restrict__ x2hiT, ushort_t* __restrict__ x2loT,
    ushort_t* __restrict__ dwThi, ushort_t* __restrict__ dwTlo,
    const float* __restrict__ bR_rff,
    const float* __restrict__ bR1w, const float* __restrict__ bR1b,
    const float* __restrict__ bR2w, const float* __restrict__ bR2b,
    const float* __restrict__ kR1w, const float* __restrict__ kR1b,
    const float* __restrict__ kR2w, const float* __restrict__ kR2b,
    float* __restrict__ kRb1, float* __restrict__ kRb2){
  __shared__ float4 posS4[N_];        // fps
  __shared__ float2 wred[2][4];       // fps
  __shared__ int sidxS[M_];           // fps sample indices
  __shared__ float ts4[4][64];        // lift
  __shared__ float fsb[128], hsb[128];// kbR
  int bid = blockIdx.x;
  int tid = threadIdx.x;

  if (bid < FPSB){
    // ---- FPS: no global ops inside the loop
    int b = bid;
    for (int i=tid;i<N_;i+=256){
      const float* p = pos + (size_t)b*N_*3 + (size_t)i*3;
      posS4[i] = make_float4(p[0], p[1], p[2], 0.f);
    }
    __syncthreads();
    float px[8],py[8],pz[8],d[8];
    #pragma unroll
    for (int j=0;j<8;++j){
      float4 pt = posS4[tid + 256*j];
      px[j]=pt.x; py[j]=pt.y; pz[j]=pt.z;
      d[j]=1e10f;
    }
    int wave = tid>>6, lane = tid&63;
    int last = 0;
    for (int s=0;s<M_;++s){
      if (tid==0) sidxS[s] = last;
      if (s==M_-1) break;
      float4 lp = posS4[last];
      float lx=lp.x, ly=lp.y, lz=lp.z;
      #pragma unroll
      for (int j=0;j<8;++j){
        float dx=__fsub_rn(px[j],lx), dy=__fsub_rn(py[j],ly), dz=__fsub_rn(pz[j],lz);
        float dist=__fadd_rn(__fadd_rn(__fmul_rn(dx,dx),__fmul_rn(dy,dy)),__fmul_rn(dz,dz));
        d[j]=fminf(d[j],dist);
      }
      float va = d[1]>d[0]?d[1]:d[0]; int ja = d[1]>d[0]?1:0;
      float vb = d[3]>d[2]?d[3]:d[2]; int jb = d[3]>d[2]?3:2;
      float vc = d[5]>d[4]?d[5]:d[4]; int jc = d[5]>d[4]?5:4;
      float vd = d[7]>d[6]?d[7]:d[6]; int jd = d[7]>d[6]?7:6;
      float ve = vb>va?vb:va; int je = vb>va?jb:ja;
      float vf = vd>vc?vd:vc; int jf = vd>vc?jd:jc;
      float v  = vf>ve?vf:ve; int jj = vf>ve?jf:je;
      int vi = tid + (jj<<8);
      DPP_AMAX(0x121); DPP_AMAX(0x122); DPP_AMAX(0x124); DPP_AMAX(0x128);
      DPP_AMAX(0x142); DPP_AMAX(0x143);
      int sv = __builtin_amdgcn_readlane(__float_as_int(v), 63);
      int si = __builtin_amdgcn_readlane(vi, 63);
      if (lane==0) wred[s&1][wave] = make_float2(__int_as_float(sv), __int_as_float(si));
      __syncthreads();
      float2 r0 = wred[s&1][0], r1 = wred[s&1][1], r2 = wred[s&1][2], r3 = wred[s&1][3];
      float bv = r0.x; int bi = __float_as_int(r0.y);
      int i1 = __float_as_int(r1.y); if (r1.x>bv || (r1.x==bv && i1<bi)){ bv=r1.x; bi=i1; }
      int i2 = __float_as_int(r2.y); if (r2.x>bv || (r2.x==bv && i2<bi)){ bv=r2.x; bi=i2; }
      int i3 = __float_as_int(r3.y); if (r3.x>bv || (r3.x==bv && i3<bi)){ bv=r3.x; bi=i3; }
      last = bi;
    }
    __syncthreads();
    for (int i=tid; i<M_; i+=256){
      float4 p = posS4[sidxS[i]];
      float* o = ps + ((size_t)b*M_+i)*3;
      o[0]=p.x; o[1]=p.y; o[2]=p.z;
      ps4[(size_t)b*M_+i] = make_float4(p.x, p.y, p.z, 0.f);
    }
  } else if (bid < FPSB + LIFTB){
    int vbid = bid - FPSB;
    int q = tid>>6, lane = tid&63;
    int fid = vbid*4 + q;
    int g = fid % NG_;
    int n = (fid / NG_) % N_;
    int b = fid / (NG_*N_);
    const float* nm = normal + (size_t)(b*N_+n)*3;
    const float* pp = pos + (size_t)(b*N_+n)*3;
    const float* gg = grid + g*3;
    float f0 = nm[0]*gg[0] + nm[1]*gg[1] + nm[2]*gg[2];
    float t = e1b[lane] + f0*e1w[lane] + pp[0]*e1w[64+lane] + pp[1]*e1w[128+lane] + pp[2]*e1w[192+lane];
    ts4[q][lane] = gelu_f(t);
    __syncthreads();
    float acc = e2b[lane];
    #pragma unroll
    for (int i=0;i<64;++i) acc = fmaf(ts4[q][i], e2w[i*64+lane], acc);
    x1p[(size_t)fid*64 + lane] = pack_hl(acc);
  } else if (bid < FPSB + LIFTB + WSB){
    int tg = (bid - FPSB - LIFTB)*256 + tid;
    if (tg < 16384){
      int j = tg >> 7, k = tg & 127;
      float x = bx1w[k*128 + j];
      ushort_t hi = bf16_rne(x);
      float hif = __uint_as_float(((uint_t)hi)<<16);
      ushort_t lo = bf16_rne(x - hif);
      w1hiT[tg] = hi; w1loT[tg] = lo;
    }
    if (tg < 8192){
      int c = tg >> 7, j = tg & 127;
      float x = bx2w[j*64 + c];
      ushort_t hi = bf16_rne(x);
      float hif = __uint_as_float(((uint_t)hi)<<16);
      ushort_t lo = bf16_rne(x - hif);
      w2hiT[tg] = hi; w2loT[tg] = lo;
    }
    if (tg < 8192){
      int c = tg >> 6, d = tg & 63;
      float xa = kxw1[d*128 + c];
      ushort_t hi = bf16_rne(xa);
      float hif = __uint_as_float(((uint_t)hi)<<16);
      ushort_t lo = bf16_rne(xa - hif);
      x1hiT[tg] = hi; x1loT[tg] = lo;
      float xb = kxw2[d*128 + c];
      ushort_t hi2 = bf16_rne(xb);
      float hif2 = __uint_as_float(((uint_t)hi2)<<16);
      ushort_t lo2 = bf16_rne(xb - hif2);
      x2hiT[tg] = hi2; x2loT[tg] = lo2;
      float xd = dww[d*128 + c];
      ushort_t hi3 = bf16_rne(xd);
      float hif3 = __uint_as_float(((uint_t)hi3)<<16);
      ushort_t lo3 = bf16_rne(xd - hif3);
      dwThi[tg] = hi3; dwTlo[tg] = lo3;
    }
  } else if (bid < FPSB + LIFTB + WSB + KBRB){
    // kbR basis MLP + both kR layers (pair-local)
    int vbid = bid - FPSB - LIFTB - WSB;
    int gm = vbid / NG_, gn = vbid % NG_;
    int j = tid;
    if (j < 128){
      float z = grid[gm*3]*grid[gn*3] + grid[gm*3+1]*grid[gn*3+1] + grid[gm*3+2]*grid[gn*3+2];
      float ang = 6.283185307179586f * (z * bR_rff[j & 63]);
      fsb[j] = (j<64) ? sinf(ang) : cosf(ang);
    }
    __syncthreads();
    if (j < 128){
      float acc = bR1b[j];
      for (int i=0;i<128;++i) acc = fmaf(fsb[i], bR1w[i*128+j], acc);
      hsb[j] = gelu_f(acc);
    }
    __syncthreads();
    if (j < 64){
      float a2 = bR2b[j];
      for (int i=0;i<128;++i) a2 = fmaf(hsb[i], bR2w[i*64+j], a2);
      fsb[j] = gelu_f(a2);
    }
    __syncthreads();
    if (j < 128){
      float a1 = kR1b[j], a2v = kR2b[j];
      for (int d=0; d<64; ++d){
        float kv = fsb[d];
        a1  = fmaf(kv, kR1w[d*128+j], a1);
        a2v = fmaf(kv, kR2w[d*128+j], a2v);
      }
      kRb1[(size_t)vbid*128 + j] = a1;
      kRb2[(size_t)vbid*128 + j] = a2v;
    }
  } else {
    // pos -> padded float4 pos4
    int i = (bid - FPSB - LIFTB - WSB - KBRB)*256 + tid;   // 0..8191
    const float* p = pos + (size_t)i*3;
    pos4[i] = make_float4(p[0], p[1], p[2], 0.f);
  }
}

// ============ KNN: 4 queries/block (wave-per-query), float4 pools ============
template<int NP>
__device__ __forceinline__ void knn_body4(int qm, const float4* __restrict__ qp4,
                                          const float4* __restrict__ pool4, int* __restrict__ out){
  constexpr int R = NP/64;
  int lane = threadIdx.x & 63;
  int b = qm / M_;
  float4 q = qp4[qm];
  float qx=q.x, qy=q.y, qz=q.z;
  float d2[R];
  #pragma unroll
  for (int j=0;j<R;++j){
    float4 p = pool4[(size_t)b*NP + lane + 64*j];
    float dx=__fsub_rn(qx,p.x), dy=__fsub_rn(qy,p.y), dz=__fsub_rn(qz,p.z);
    d2[j]=__fadd_rn(__fadd_rn(__fmul_rn(dx,dx),__fmul_rn(dy,dy)),__fmul_rn(dz,dz));
  }
  for (int r=0;r<K_;++r){
    float v=FLT_MAX; int vi=0x7fffffff;
    #pragma unroll
    for (int j=0;j<R;++j){
      if (d2[j]<v){ v=d2[j]; vi=lane+64*j; }
    }
    DPP_AMIN(0x121); DPP_AMIN(0x122); DPP_AMIN(0x124); DPP_AMIN(0x128);
    DPP_AMIN(0x142); DPP_AMIN(0x143);
    int si = __builtin_amdgcn_readlane(vi, 63);
    if (lane==0) out[(size_t)qm*K_ + r] = si;
    #pragma unroll
    for (int j=0;j<R;++j){ if (si == lane + 64*j) d2[j] = FLT_MAX; }
  }
}

__global__ __launch_bounds__(256) void k_knn_all(const float4* __restrict__ ps4,
    const float4* __restrict__ pos4, int* __restrict__ nbrD, int* __restrict__ nbrS){
  int w = threadIdx.x >> 6;
  int bid = blockIdx.x;
  if (bid < B_*M_/4) knn_body4<N_>(bid*4 + w, ps4, pos4, nbrD);
  else               knn_body4<M_>((bid - B_*M_/4)*4 + w, ps4, ps4, nbrS);
}

// ============ downmax (MFMA, packed x1) + kbx in one dispatch ============
__device__ __forceinline__ void dm_body(uint_t* um, int bm,
    const uint_t* __restrict__ x1p, const int* __restrict__ nbrD,
    const ushort_t* __restrict__ dwThi, const ushort_t* __restrict__ dwTlo,
    const float* __restrict__ db, float* __restrict__ xA){
  int b = bm / M_;
  int tid = threadIdx.x;
  uint_t* xs = um;                       // [16][768] packed, xor-swizzled granules
  int* nb = (int*)(um + 12288);
  if (tid < K_) nb[tid] = nbrD[(size_t)bm*K_ + tid];
  __syncthreads();
  for (int idx=tid; idx<3072; idx+=256){
    int k = idx / 192, qq = idx % 192;
    uint4 vv = ((const uint4*)&x1p[((size_t)(b*N_) + nb[k])*(NG_*H_)])[qq];
    int gran = (qq >> 1) ^ (k & 7);
    *(uint4*)&xs[k*768 + gran*8 + (qq&1)*4] = vv;
  }
  __syncthreads();
  int wid = tid>>6, lane = tid&63, ln = lane&15, g4 = lane>>4;
  short8 bh[2][2], bl[2][2];
  float dbv[2];
  #pragma unroll
  for (int nt=0; nt<2; ++nt){
    int col = wid*32 + nt*16 + ln;
    dbv[nt] = db[col];
    #pragma unroll
    for (int ks=0; ks<2; ++ks){
      bh[nt][ks] = *(const short8*)&dwThi[(size_t)col*64 + ks*32 + g4*8];
      bl[nt][ks] = *(const short8*)&dwTlo[(size_t)col*64 + ks*32 + g4*8];
    }
  }
  int xorl = ln & 7;
  #pragma unroll
  for (int g=0; g<NG_; ++g){
    short8 ah[2], al[2];
    #pragma unroll
    for (int ks=0; ks<2; ++ks){
      int col0 = g*64 + ks*32 + g4*8;
      int gran = (col0 >> 3) ^ xorl;
      const uint_t* src = &xs[ln*768 + gran*8];
      uint4 q0 = *(const uint4*)src;
      uint4 q1 = *(const uint4*)(src+4);
      UNPACK8(q0, q1, ah[ks], al[ks]);
    }
    floatx4 acc[2];
    acc[0] = (floatx4){0.f,0.f,0.f,0.f};
    acc[1] = (floatx4){0.f,0.f,0.f,0.f};
    #pragma unroll
    for (int nt=0; nt<2; ++nt)
      #pragma unroll
      for (int ks=0; ks<2; ++ks){
        acc[nt] = __builtin_amdgcn_mfma_f32_16x16x32_bf16(ah[ks], bh[nt][ks], acc[nt], 0,0,0);
        acc[nt] = __builtin_amdgcn_mfma_f32_16x16x32_bf16(al[ks], bh[nt][ks], acc[nt], 0,0,0);
        acc[nt] = __builtin_amdgcn_mfma_f32_16x16x32_bf16(ah[ks], bl[nt][ks], acc[nt], 0,0,0);
      }
    #pragma unroll
    for (int nt=0; nt<2; ++nt){
      float mx = fmaxf(fmaxf(acc[nt][0],acc[nt][1]), fmaxf(acc[nt][2],acc[nt][3]));
      mx = fmaxf(mx, __shfl_xor(mx, 16));
      mx = fmaxf(mx, __shfl_xor(mx, 32));
      if (g4 == 0)
        xA[(size_t)bm*(NG_*C_) + g*C_ + wid*32 + nt*16 + ln] = fmaxf(mx + dbv[nt], 0.0f);
    }
  }
}

__device__ __forceinline__ void kbx_body(float* um, int vbid,
    const float* __restrict__ ps, const int* __restrict__ nbr,
    const float* __restrict__ grid, const float* __restrict__ rff,
    const ushort_t* __restrict__ w1hiT, const ushort_t* __restrict__ w1loT,
    const ushort_t* __restrict__ w2hiT, const ushort_t* __restrict__ w2loT,
    const float* __restrict__ b1, const float* __restrict__ b2,
    uint_t* __restrict__ kbxp){
  float* z0s = um;
  float* z1s = um + 128;
  float* rws = um + 256;
  int tid = threadIdx.x;
  if (tid < 128){
    rws[tid] = rff[tid];
    int fid = vbid*128 + tid;
    int g = fid % NG_;
    int k = (fid/NG_) % K_;
    int bm = fid / (NG_*K_);
    int b = bm / M_;
    int nb = nbr[(size_t)bm*K_ + k];
    const float* pm = ps + (size_t)bm*3;
    const float* pn = ps + ((size_t)(b*M_) + nb)*3;
    float rx = pn[0]-pm[0], ry = pn[1]-pm[1], rz3 = pn[2]-pm[2];
    const float* gg = grid + g*3;
    float rz = rx*gg[0] + ry*gg[1] + rz3*gg[2];
    float vx = rx - rz*gg[0], vy = ry - rz*gg[1], vz = rz3 - rz*gg[2];
    float rxy = sqrtf(vx*vx + vy*vy + vz*vz + 1e-12f);
    z0s[tid]=rxy; z1s[tid]=rz;
  }
  __syncthreads();
  int wid = tid>>6, lane = tid&63;
  int ln = lane & 15, g = lane >> 4;
  float* bw = um + 384 + wid*1088;

  short8 ahi[2][4], alo[2][4];
  #pragma unroll
  for (int rt=0; rt<2; ++rt){
    float z0 = z0s[wid*32 + rt*16 + ln];
    float z1 = z1s[wid*32 + rt*16 + ln];
    #pragma unroll
    for (int ks=0; ks<4; ++ks){
      #pragma unroll
      for (int e=0; e<8; ++e){
        int kd = ks*32 + g*8 + e;
        int kk = kd & 63;
        float t = z0*rws[kk] + z1*rws[64+kk];
        t = t - floorf(t);
        float v = (ks < 2) ? __builtin_amdgcn_sinf(t) : __builtin_amdgcn_cosf(t);
        ushort_t hi = bf16_rne(v);
        float hif = __uint_as_float(((uint_t)hi)<<16);
        ushort_t lo = bf16_rne(v - hif);
        ahi[rt][ks][e] = (short)hi;
        alo[rt][ks][e] = (short)lo;
      }
    }
  }
  floatx4 acc2[2][4];
  #pragma unroll
  for (int rt=0; rt<2; ++rt)
    #pragma unroll
    for (int ct=0; ct<4; ++ct)
      acc2[rt][ct] = (floatx4){0.f,0.f,0.f,0.f};

  #pragma unroll
  for (int jp=0; jp<4; ++jp){
    floatx4 acc1[2][2];
    #pragma unroll
    for (int rt=0; rt<2; ++rt)
      #pragma unroll
      for (int jt=0; jt<2; ++jt)
        acc1[rt][jt] = (floatx4){0.f,0.f,0.f,0.f};
    #pragma unroll
    for (int ks=0; ks<4; ++ks){
      #pragma unroll
      for (int jt=0; jt<2; ++jt){
        int j = jp*32 + jt*16 + ln;
        short8 bhi = *(const short8*)&w1hiT[(size_t)j*128 + ks*32 + g*8];
        short8 blo = *(const short8*)&w1loT[(size_t)j*128 + ks*32 + g*8];
        #pragma unroll
        for (int rt=0; rt<2; ++rt){
          acc1[rt][jt] = __builtin_amdgcn_mfma_f32_16x16x32_bf16(ahi[rt][ks], bhi, acc1[rt][jt], 0,0,0);
          acc1[rt][jt] = __builtin_amdgcn_mfma_f32_16x16x32_bf16(alo[rt][ks], bhi, acc1[rt][jt], 0,0,0);
          acc1[rt][jt] = __builtin_amdgcn_mfma_f32_16x16x32_bf16(ahi[rt][ks], blo, acc1[rt][jt], 0,0,0);
        }
      }
    }
    #pragma unroll
    for (int jt=0; jt<2; ++jt){
      float bb = b1[jp*32 + jt*16 + ln];
      #pragma unroll
      for (int rt=0; rt<2; ++rt)
        #pragma unroll
        for (int i=0; i<4; ++i)
          bw[(rt*16 + g*4 + i)*34 + jt*16 + ln] = gelu_f(bb + acc1[rt][jt][i]);
    }
    #pragma unroll
    for (int rt=0; rt<2; ++rt){
      int base = (rt*16 + ln)*34 + g*8;
      float2 p0 = *(float2*)&bw[base+0];
      float2 p1 = *(float2*)&bw[base+2];
      float2 p2 = *(float2*)&bw[base+4];
      float2 p3 = *(float2*)&bw[base+6];
      float hv[8] = {p0.x,p0.y,p1.x,p1.y,p2.x,p2.y,p3.x,p3.y};
      short8 a2h, a2l;
      #pragma unroll
      for (int e=0; e<8; ++e){
        ushort_t hi = bf16_rne(hv[e]);
        float hif = __uint_as_float(((uint_t)hi)<<16);
        ushort_t lo = bf16_rne(hv[e] - hif);
        a2h[e] = (short)hi;
        a2l[e] = (short)lo;
      }
      #pragma unroll
      for (int ct=0; ct<4; ++ct){
        short8 b2h = *(const short8*)&w2hiT[(size_t)(ct*16+ln)*128 + jp*32 + g*8];
        short8 b2l = *(const short8*)&w2loT[(size_t)(ct*16+ln)*128 + jp*32 + g*8];
        acc2[rt][ct] = __builtin_amdgcn_mfma_f32_16x16x32_bf16(a2h, b2h, acc2[rt][ct], 0,0,0);
        acc2[rt][ct] = __builtin_amdgcn_mfma_f32_16x16x32_bf16(a2l, b2h, acc2[rt][ct], 0,0,0);
        acc2[rt][ct] = __builtin_amdgcn_mfma_f32_16x16x32_bf16(a2h, b2l, acc2[rt][ct], 0,0,0);
      }
    }
  }
  #pragma unroll
  for (int ct=0; ct<4; ++ct){
    float bb = b2[ct*16 + ln];
    #pragma unroll
    for (int rt=0; rt<2; ++rt)
      #pragma unroll
      for (int i=0; i<4; ++i){
        int row = wid*32 + rt*16 + g*4 + i;
        size_t fiber = (size_t)vbid*128 + row;
        kbxp[fiber*64 + ct*16 + ln] = pack_hl(gelu_f(bb + acc2[rt][ct][i]));
      }
  }
}

__global__ __launch_bounds__(256) void k_dmkbx(
    const uint_t* __restrict__ x1p, const int* __restrict__ nbrD,
    const ushort_t* __restrict__ dwThi, const ushort_t* __restrict__ dwTlo,
    const float* __restrict__ db, float* __restrict__ xA,
    const float* __restrict__ ps, const int* __restrict__ nbrS,
    const float* __restrict__ grid, const float* __restrict__ rff,
    const ushort_t* __restrict__ w1hiT, const ushort_t* __restrict__ w1loT,
    const ushort_t* __restrict__ w2hiT, const ushort_t* __restrict__ w2loT,
    const float* __restrict__ b1, const float* __restrict__ b2,
    uint_t* __restrict__ kbxp){
  __shared__ __align__(16) uint_t um[12384];   // 49.5 KB union
  int bid = blockIdx.x;
  if (bid < B_*M_)
    dm_body(um, bid, x1p, nbrD, dwThi, dwTlo, db, xA);
  else
    kbx_body((float*)um, bid - B_*M_, ps, nbrS, grid, rff, w1hiT, w1loT, w2hiT, w2loT, b1, b2, kbxp);
}

// ============ interaction layer (MFMA kx-apply, T14 prefetch, aliased LDS) ============
__global__ __launch_bounds__(256) void k_inter(
    const float* __restrict__ xin, const int* __restrict__ nbr,
    const uint_t* __restrict__ kbxp, const float* __restrict__ kR,
    const ushort_t* __restrict__ kxhT, const ushort_t* __restrict__ kxlT,
    const float* __restrict__ kxb,
    const float* __restrict__ mw, const float* __restrict__ mb,
    float* __restrict__ xout, float* __restrict__ part){
  int bm = blockIdx.x; int b = bm / M_;
  int tid = threadIdx.x;
  int wid = tid>>6, lane = tid&63, ln = lane&15, g4 = lane>>4;
  int c = tid & 127, gh = tid >> 7;
  __shared__ uint_t kbsL[48][68];                 // 13.06 KB
  __shared__ __align__(16) float TsU[48*129];     // 24.19 KB; aliased: Ts -> aggS/yS/psumS
  float* aggS_ = TsU;            // [12][128]
  float* yS_   = TsU + 1536;     // [12][128]
  float* psumS_= TsU + 3072;     // [2][128]

  const uint4* ksrc = (const uint4*)(kbxp + (size_t)bm*192*64);

  uint4 ka = ksrc[tid], kbv = ksrc[tid+256], kc = ksrc[tid+512];
  int nb0 = nbr[(size_t)bm*K_+0], nb1 = nbr[(size_t)bm*K_+1],
      nb2 = nbr[(size_t)bm*K_+2], nb3 = nbr[(size_t)bm*K_+3];

  short8 bh[2][2], bl[2][2];
  float kxbv[2];
  #pragma unroll
  for (int nt=0; nt<2; ++nt){
    int cc_ = (wid*2+nt)*16 + ln;
    kxbv[nt] = kxb[cc_];
    #pragma unroll
    for (int ks=0; ks<2; ++ks){
      bh[nt][ks] = *(const short8*)&kxhT[(size_t)cc_*64 + ks*32 + g4*8];
      bl[nt][ks] = *(const short8*)&kxlT[(size_t)cc_*64 + ks*32 + g4*8];
    }
  }
  float accg[6] = {0,0,0,0,0,0};

  for (int cc=0; cc<4; ++cc){
    {
      int i0=tid, i1=tid+256, i2=tid+512;
      *(uint4*)&kbsL[i0>>4][(i0&15)*4] = ka;
      *(uint4*)&kbsL[i1>>4][(i1&15)*4] = kbv;
      *(uint4*)&kbsL[i2>>4][(i2&15)*4] = kc;
    }
    __syncthreads();   // A: kbsL ready
    float xreg[24];
    {
      const float* xr0 = xin + ((size_t)(b*M_) + nb0)*(NG_*C_);
      const float* xr1 = xin + ((size_t)(b*M_) + nb1)*(NG_*C_);
      const float* xr2 = xin + ((size_t)(b*M_) + nb2)*(NG_*C_);
      const float* xr3 = xin + ((size_t)(b*M_) + nb3)*(NG_*C_);
      #pragma unroll
      for (int gi=0; gi<6; ++gi){
        int off = (gh*6+gi)*C_ + c;
        xreg[0*6+gi] = xr0[off];
        xreg[1*6+gi] = xr1[off];
        xreg[2*6+gi] = xr2[off];
        xreg[3*6+gi] = xr3[off];
      }
    }
    if (cc < 3){
      ka  = ksrc[(cc+1)*768 + tid];
      kbv = ksrc[(cc+1)*768 + tid + 256];
      kc  = ksrc[(cc+1)*768 + tid + 512];
      nb0 = nbr[(size_t)bm*K_ + (cc+1)*4 + 0];
      nb1 = nbr[(size_t)bm*K_ + (cc+1)*4 + 1];
      nb2 = nbr[(size_t)bm*K_ + (cc+1)*4 + 2];
      nb3 = nbr[(size_t)bm*K_ + (cc+1)*4 + 3];
    }
    floatx4 acc[3][2];
    #pragma unroll
    for (int mt=0; mt<3; ++mt)
      #pragma unroll
      for (int nt=0; nt<2; ++nt)
        acc[mt][nt] = (floatx4){0.f,0.f,0.f,0.f};
    #pragma unroll
    for (int mt=0; mt<3; ++mt){
      short8 ah[2], al[2];
      #pragma unroll
      for (int ks=0; ks<2; ++ks){
        const uint_t* src = &kbsL[mt*16+ln][ks*32+g4*8];
        uint4 q0 = *(const uint4*)src;
        uint4 q1 = *(const uint4*)(src+4);
        UNPACK8(q0, q1, ah[ks], al[ks]);
      }
      #pragma unroll
      for (int nt=0; nt<2; ++nt)
        #pragma unroll
        for (int ks=0; ks<2; ++ks){
          acc[mt][nt] = __builtin_amdgcn_mfma_f32_16x16x32_bf16(ah[ks], bh[nt][ks], acc[mt][nt], 0,0,0);
          acc[mt][nt] = __builtin_amdgcn_mfma_f32_16x16x32_bf16(al[ks], bh[nt][ks], acc[mt][nt], 0,0,0);
          acc[mt][nt] = __builtin_amdgcn_mfma_f32_16x16x32_bf16(ah[ks], bl[nt][ks], acc[mt][nt], 0,0,0);
        }
    }
    #pragma unroll
    for (int mt=0; mt<3; ++mt)
      #pragma unroll
      for (int nt=0; nt<2; ++nt)
        #pragma unroll
        for (int i=0; i<4; ++i)
          TsU[(mt*16 + g4*4 + i)*129 + (wid*2+nt)*16 + ln] = acc[mt][nt][i] + kxbv[nt];
    __syncthreads();   // B: Ts ready
    #pragma unroll
    for (int kl=0; kl<4; ++kl)
      #pragma unroll
      for (int gi=0; gi<6; ++gi)
        accg[gi] = fmaf(TsU[(kl*12 + gh*6 + gi)*129 + c], xreg[kl*6+gi], accg[gi]);
    __syncthreads();   // C: Ts reads done before next chunk overwrites kbsL/Ts
  }
  // Ts region dead -> reuse for aggS/yS/psumS
  #pragma unroll
  for (int gi=0; gi<6; ++gi)
    aggS_[(gh*6+gi)*C_ + c] = accg[gi] * (1.0f/16.0f);
  __syncthreads();
  #pragma unroll
  for (int gi=0; gi<6; ++gi){
    int g = gh*6+gi;
    float yv = 0.f;
    #pragma unroll
    for (int n=0;n<NG_;++n) yv = fmaf(aggS_[n*C_ + c], kR[((size_t)g*NG_+n)*C_ + c], yv);
    yS_[g*C_ + c] = yv * (1.0f/12.0f);
  }
  __syncthreads();
  float m6[6] = {0,0,0,0,0,0};
  for (int i4=0;i4<32;++i4){
    float w0 = mw[(i4*4+0)*C_+c], w1 = mw[(i4*4+1)*C_+c],
          w2 = mw[(i4*4+2)*C_+c], w3 = mw[(i4*4+3)*C_+c];
    #pragma unroll
    for (int gi=0;gi<6;++gi){
      int g = gh*6+gi;
      float4 yv = *(const float4*)&yS_[g*C_ + i4*4];
      m6[gi] = fmaf(yv.x,w0,fmaf(yv.y,w1,fmaf(yv.z,w2,fmaf(yv.w,w3,m6[gi]))));
    }
  }
  float mbc = mb[c];
  float psum = 0.f;
  #pragma unroll
  for (int gi=0;gi<6;++gi){
    int g = gh*6+gi;
    size_t off = (size_t)bm*(NG_*C_) + g*C_ + c;
    float val = xin[off] + gelu_f(m6[gi] + mbc);
    xout[off] = val;
    psum += val;
  }
  if (part){
    psumS_[gh*C_ + c] = psum;
    __syncthreads();
    if (gh == 0)
      part[(size_t)bm*C_ + c] = psumS_[c] + psumS_[C_ + c];
  }
}

// ============ head: 512-row reduce + MLP ============
__global__ __launch_bounds__(256) void k_head(
    const float* __restrict__ part,
    const float* __restrict__ p1w, const float* __restrict__ p1b,
    const float* __restrict__ p2w, const float* __restrict__ p2b,
    const float* __restrict__ p3w, const float* __restrict__ p3b,
    float* __restrict__ out){
  int b = blockIdx.x, tid = threadIdx.x;
  int c = tid & 127, half = tid >> 7;
  __shared__ float red[256];
  __shared__ float gs[128];
  {
    const float* pb = part + (size_t)b*M_*C_;
    float a0=0.f,a1=0.f,a2=0.f,a3=0.f;
    for (int r = half*4; r < M_; r += 8){
      a0 += pb[(size_t)(r+0)*C_ + c];
      a1 += pb[(size_t)(r+1)*C_ + c];
      a2 += pb[(size_t)(r+2)*C_ + c];
      a3 += pb[(size_t)(r+3)*C_ + c];
    }
    red[tid] = (a0+a1)+(a2+a3);
  }
  __syncthreads();
  if (half==0) gs[c] = (red[c] + red[128+c]) * (1.0f/(M_*NG_));
  __syncthreads();
  __shared__ float h1[256];
  {
    float a = p1b[tid];
    for (int i=0;i<128;++i) a = fmaf(gs[i], p1w[i*256+tid], a);
    h1[tid] = gelu_f(a);
  }
  __syncthreads();
  __shared__ float h2[64];
  if (tid<64){
    float a = p2b[tid];
    for (int i=0;i<256;++i) a = fmaf(h1[i], p2w[i*64+tid], a);
    h2[tid] = gelu_f(a);
  }
  __syncthreads();
  if (tid==0){
    float a = p3b[0];
    for (int i=0;i<64;++i) a = fmaf(h2[i], p3w[i], a);
    out[b] = a;
  }
}

extern "C" void kernel_launch(void* const* d_in, const int* in_sizes, int n_in,
                              void* d_out, int out_size, void* d_ws, size_t ws_size,
                              hipStream_t stream){
  const float* pos    = (const float*)d_in[0];
  const float* normal = (const float*)d_in[1];
  const float* grid   = (const float*)d_in[2];
  const float* e1w = (const float*)d_in[3];  const float* e1b = (const float*)d_in[4];
  const float* e2w = (const float*)d_in[5];  const float* e2b = (const float*)d_in[6];
  const float* dww = (const float*)d_in[7];  const float* dwb = (const float*)d_in[8];
  const float* bx_rff = (const float*)d_in[9];
  const float* bx1w = (const float*)d_in[10]; const float* bx1b = (const float*)d_in[11];
  const float* bx2w = (const float*)d_in[12]; const float* bx2b = (const float*)d_in[13];
  const float* bR_rff = (const float*)d_in[14];
  const float* bR1w = (const float*)d_in[15]; const float* bR1b = (const float*)d_in[16];
  const float* bR2w = (const float*)d_in[17]; const float* bR2b = (const float*)d_in[18];
  const float* i1kxw = (const float*)d_in[19]; const float* i1kxb = (const float*)d_in[20];
  const float* i1kRw = (const float*)d_in[21]; const float* i1kRb = (const float*)d_in[22];
  const float* i1mw  = (const float*)d_in[23]; const float* i1mb  = (const float*)d_in[24];
  const float* i2kxw = (const float*)d_in[25]; const float* i2kxb = (const float*)d_in[26];
  const float* i2kRw = (const float*)d_in[27]; const float* i2kRb = (const float*)d_in[28];
  const float* i2mw  = (const float*)d_in[29]; const float* i2mb  = (const float*)d_in[30];
  const float* p1w = (const float*)d_in[31]; const float* p1b = (const float*)d_in[32];
  const float* p2w = (const float*)d_in[33]; const float* p2b = (const float*)d_in[34];
  const float* p3w = (const float*)d_in[35]; const float* p3b = (const float*)d_in[36];
  float* out = (float*)d_out;

  float* ws = (float*)d_ws;
  size_t o = 0;
  uint_t* x1p = (uint_t*)(ws + o); o += (size_t)B_*N_*NG_*H_;
  float* psb = ws + o; o += (size_t)B_*M_*3;
  float* xA  = ws + o; o += (size_t)B_*M_*NG_*C_;
  float* xB  = ws + o; o += (size_t)B_*M_*NG_*C_;
  uint_t* kbxp = (uint_t*)(ws + o); o += (size_t)B_*M_*K_*NG_*BD_;
  float* kRb1 = ws + o; o += (size_t)NG_*NG_*C_;
  float* kRb2 = ws + o; o += (size_t)NG_*NG_*C_;
  float* part = ws + o; o += (size_t)B_*M_*C_;
  float4* pos4 = (float4*)(ws + o); o += (size_t)B_*N_*4;
  float4* ps4  = (float4*)(ws + o); o += (size_t)B_*M_*4;
  int* nbrD  = (int*)(ws + o); o += (size_t)B_*M_*K_;
  int* nbrS  = (int*)(ws + o); o += (size_t)B_*M_*K_;
  ushort_t* w1hiT = (ushort_t*)(ws + o); o += 8192;
  ushort_t* w1loT = (ushort_t*)(ws + o); o += 8192;
  ushort_t* w2hiT = (ushort_t*)(ws + o); o += 4096;
  ushort_t* w2loT = (ushort_t*)(ws + o); o += 4096;
  ushort_t* x1hiT = (ushort_t*)(ws + o); o += 4096;
  ushort_t* x1loT = (ushort_t*)(ws + o); o += 4096;
  ushort_t* x2hiT = (ushort_t*)(ws + o); o += 4096;
  ushort_t* x2loT = (ushort_t*)(ws + o); o += 4096;
  ushort_t* dwThi = (ushort_t*)(ws + o); o += 4096;
  ushort_t* dwTlo = (ushort_t*)(ws + o); o += 4096;

  k_mega1<<<FPSB + LIFTB + WSB + KBRB + PM4B, 256, 0, stream>>>(
      pos, normal, grid, e1w, e1b, e2w, e2b, x1p, psb, pos4, ps4,
      bx1w, bx2w, i1kxw, i2kxw, dww,
      w1hiT, w1loT, w2hiT, w2loT, x1hiT, x1loT, x2hiT, x2loT, dwThi, dwTlo,
      bR_rff, bR1w, bR1b, bR2w, bR2b,
      i1kRw, i1kRb, i2kRw, i2kRb, kRb1, kRb2);
  k_knn_all<<<B_*M_/2, 256, 0, stream>>>(ps4, pos4, nbrD, nbrS);
  k_dmkbx<<<B_*M_ + (B_*M_*K_*NG_)/128, 256, 0, stream>>>(
      x1p, nbrD, dwThi, dwTlo, dwb, xA,
      psb, nbrS, grid, bx_rff, w1hiT, w1loT, w2hiT, w2loT, bx1b, bx2b, kbxp);
  k_inter<<<B_*M_, 256, 0, stream>>>(xA, nbrS, kbxp, kRb1, x1hiT, x1loT, i1kxb, i1mw, i1mb, xB, nullptr);
  k_inter<<<B_*M_, 256, 0, stream>>>(xB, nbrS, kbxp, kRb2, x2hiT, x2loT, i2kxb, i2mw, i2mb, xA, part);
  k_head<<<B_, 256, 0, stream>>>(part, p1w, p1b, p2w, p2b, p3w, p3b, out);
}

// Round 12
// 732.582 us; speedup vs baseline: 1.9199x; 1.0047x over previous
//
#include <hip/hip_runtime.h>
#include <hip/hip_bf16.h>
#include <cfloat>

#define B_ 4
#define N_ 2048
#define NG_ 12
#define K_ 16
#define H_ 64
#define C_ 128
#define BD_ 64
#define M_ 512

typedef __attribute__((ext_vector_type(8))) short short8;
typedef __attribute__((ext_vector_type(4))) float floatx4;
typedef unsigned short ushort_t;
typedef unsigned int uint_t;

__device__ __forceinline__ float gelu_f(float x){
  float s = 0.7978845608028654f*(x + 0.044715f*x*x*x);
  float e = __expf(2.0f*s);
  float t = 1.0f - 2.0f/(e + 1.0f);
  return 0.5f*x*(1.0f + t);
}

__device__ __forceinline__ ushort_t bf16_rne(float x){
  uint_t u = __float_as_uint(x);
  uint_t r = (u + 0x7fffu + ((u >> 16) & 1u)) >> 16;
  return (ushort_t)r;
}

// pack fp32 -> (hi bf16) | (lo bf16 << 16)  (bit-twiddle form, used on cold paths)
__device__ __forceinline__ uint_t pack_hl(float x){
  ushort_t hi = bf16_rne(x);
  float hif = __uint_as_float(((uint_t)hi)<<16);
  ushort_t lo = bf16_rne(x - hif);
  return (uint_t)hi | ((uint_t)lo << 16);
}

// HW packed convert: dst[15:0]=bf16(a), dst[31:16]=bf16(b), RNE (== bf16_rne)
__device__ __forceinline__ uint_t cvtpk_bf16(float a, float b){
  uint_t r;
  asm("v_cvt_pk_bf16_f32 %0, %1, %2" : "=v"(r) : "v"(a), "v"(b));
  return r;
}

// split 2 consecutive elements into hi-pair dword and lo-pair dword
__device__ __forceinline__ void split2(float v0, float v1, uint_t& hp, uint_t& lp){
  hp = cvtpk_bf16(v0, v1);
  float h0 = __uint_as_float(hp << 16);
  float h1 = __uint_as_float(hp & 0xffff0000u);
  lp = cvtpk_bf16(v0 - h0, v1 - h1);
}

// single-value packed hi|lo<<16 via cvt (numerically == pack_hl)
__device__ __forceinline__ uint_t pack_hl2(float v){
  uint_t hp = cvtpk_bf16(v, v);
  float hf = __uint_as_float(hp << 16);
  uint_t lp = cvtpk_bf16(v - hf, v - hf);
  return (hp & 0xffffu) | (lp << 16);
}

__device__ __forceinline__ uint_t perm_lo16(uint_t a, uint_t b){ return __builtin_amdgcn_perm(a, b, 0x05040100u); }
__device__ __forceinline__ uint_t perm_hi16(uint_t a, uint_t b){ return __builtin_amdgcn_perm(a, b, 0x07060302u); }

#define UNPACK8(Q0, Q1, AH, AL) { \
  uint_t* _ap = (uint_t*)&(AH); uint_t* _lp = (uint_t*)&(AL); \
  _ap[0] = perm_lo16((Q0).y, (Q0).x); _ap[1] = perm_lo16((Q0).w, (Q0).z); \
  _ap[2] = perm_lo16((Q1).y, (Q1).x); _ap[3] = perm_lo16((Q1).w, (Q1).z); \
  _lp[0] = perm_hi16((Q0).y, (Q0).x); _lp[1] = perm_hi16((Q0).w, (Q0).z); \
  _lp[2] = perm_hi16((Q1).y, (Q1).x); _lp[3] = perm_hi16((Q1).w, (Q1).z); }

#define DPP_AMAX(CTRL) { \
  int _vb = __float_as_int(v); \
  int _ov = __builtin_amdgcn_update_dpp(_vb, _vb, (CTRL), 0xF, 0xF, false); \
  int _oi = __builtin_amdgcn_update_dpp(vi, vi, (CTRL), 0xF, 0xF, false); \
  float _of = __int_as_float(_ov); \
  bool _tk = (_of > v) || (_of == v && _oi < vi); \
  v = _tk ? _of : v; vi = _tk ? _oi : vi; }

#define DPP_AMIN(CTRL) { \
  int _vb = __float_as_int(v); \
  int _ov = __builtin_amdgcn_update_dpp(_vb, _vb, (CTRL), 0xF, 0xF, false); \
  int _oi = __builtin_amdgcn_update_dpp(vi, vi, (CTRL), 0xF, 0xF, false); \
  float _of = __int_as_float(_ov); \
  bool _tk = (_of < v) || (_of == v && _oi < vi); \
  v = _tk ? _of : v; vi = _tk ? _oi : vi; }

// ============ MEGA-KERNEL 1: fps + lift + wsplit + kbR/kR + pos4 ============
#define FPSB 4
#define LIFTB (B_*N_*NG_/4)      // 6144
#define WSB 64
#define KBRB (NG_*NG_)           // 144
#define PM4B 32

__global__ __launch_bounds__(256) void k_mega1(
    const float* __restrict__ pos, const float* __restrict__ normal,
    const float* __restrict__ grid,
    const float* __restrict__ e1w, const float* __restrict__ e1b,
    const float* __restrict__ e2w, const float* __restrict__ e2b,
    uint_t* __restrict__ x1p, float* __restrict__ ps,
    float4* __restrict__ pos4, float4* __restrict__ ps4,
    const float* __restrict__ bx1w, const float* __restrict__ bx2w,
    const float* __restrict__ kxw1, const float* __restrict__ kxw2,
    const float* __restrict__ dww,
    ushort_t* __restrict__ w1hiT, ushort_t* __restrict__ w1loT,
    ushort_t* __restrict__ w2hiT, ushort_t* __restrict__ w2loT,
    ushort_t* __restrict__ x1hiT, ushort_t* __restrict__ x1loT,
    ushort_t* __restrict__ x2hiT, ushort_t* __restrict__ x2loT,
    ushort_t* __restrict__ dwThi, ushort_t* __restrict__ dwTlo,
    const float* __restrict__ bR_rff,
    const float* __restrict__ bR1w, const float* __restrict__ bR1b,
    const float* __restrict__ bR2w, const float* __restrict__ bR2b,
    const float* __restrict__ kR1w, const float* __restrict__ kR1b,
    const float* __restrict__ kR2w, const float* __restrict__ kR2b,
    float* __restrict__ kRb1, float* __restrict__ kRb2){
  __shared__ float4 posS4[N_];        // fps
  __shared__ float2 wred[2][4];       // fps
  __shared__ int sidxS[M_];           // fps sample indices
  __shared__ float ts4[4][64];        // lift
  __shared__ float fsb[128], hsb[128];// kbR
  int bid = blockIdx.x;
  int tid = threadIdx.x;

  if (bid < FPSB){
    // ---- FPS: no global ops inside the loop
    int b = bid;
    for (int i=tid;i<N_;i+=256){
      const float* p = pos + (size_t)b*N_*3 + (size_t)i*3;
      posS4[i] = make_float4(p[0], p[1], p[2], 0.f);
    }
    __syncthreads();
    float px[8],py[8],pz[8],d[8];
    #pragma unroll
    for (int j=0;j<8;++j){
      float4 pt = posS4[tid + 256*j];
      px[j]=pt.x; py[j]=pt.y; pz[j]=pt.z;
      d[j]=1e10f;
    }
    int wave = tid>>6, lane = tid&63;
    int last = 0;
    for (int s=0;s<M_;++s){
      if (tid==0) sidxS[s] = last;
      if (s==M_-1) break;
      float4 lp = posS4[last];
      float lx=lp.x, ly=lp.y, lz=lp.z;
      #pragma unroll
      for (int j=0;j<8;++j){
        float dx=__fsub_rn(px[j],lx), dy=__fsub_rn(py[j],ly), dz=__fsub_rn(pz[j],lz);
        float dist=__fadd_rn(__fadd_rn(__fmul_rn(dx,dx),__fmul_rn(dy,dy)),__fmul_rn(dz,dz));
        d[j]=fminf(d[j],dist);
      }
      float va = d[1]>d[0]?d[1]:d[0]; int ja = d[1]>d[0]?1:0;
      float vb = d[3]>d[2]?d[3]:d[2]; int jb = d[3]>d[2]?3:2;
      float vc = d[5]>d[4]?d[5]:d[4]; int jc = d[5]>d[4]?5:4;
      float vd = d[7]>d[6]?d[7]:d[6]; int jd = d[7]>d[6]?7:6;
      float ve = vb>va?vb:va; int je = vb>va?jb:ja;
      float vf = vd>vc?vd:vc; int jf = vd>vc?jd:jc;
      float v  = vf>ve?vf:ve; int jj = vf>ve?jf:je;
      int vi = tid + (jj<<8);
      DPP_AMAX(0x121); DPP_AMAX(0x122); DPP_AMAX(0x124); DPP_AMAX(0x128);
      DPP_AMAX(0x142); DPP_AMAX(0x143);
      int sv = __builtin_amdgcn_readlane(__float_as_int(v), 63);
      int si = __builtin_amdgcn_readlane(vi, 63);
      if (lane==0) wred[s&1][wave] = make_float2(__int_as_float(sv), __int_as_float(si));
      __syncthreads();
      float2 r0 = wred[s&1][0], r1 = wred[s&1][1], r2 = wred[s&1][2], r3 = wred[s&1][3];
      float bv = r0.x; int bi = __float_as_int(r0.y);
      int i1 = __float_as_int(r1.y); if (r1.x>bv || (r1.x==bv && i1<bi)){ bv=r1.x; bi=i1; }
      int i2 = __float_as_int(r2.y); if (r2.x>bv || (r2.x==bv && i2<bi)){ bv=r2.x; bi=i2; }
      int i3 = __float_as_int(r3.y); if (r3.x>bv || (r3.x==bv && i3<bi)){ bv=r3.x; bi=i3; }
      last = bi;
    }
    __syncthreads();
    for (int i=tid; i<M_; i+=256){
      float4 p = posS4[sidxS[i]];
      float* o = ps + ((size_t)b*M_+i)*3;
      o[0]=p.x; o[1]=p.y; o[2]=p.z;
      ps4[(size_t)b*M_+i] = make_float4(p.x, p.y, p.z, 0.f);
    }
  } else if (bid < FPSB + LIFTB){
    int vbid = bid - FPSB;
    int q = tid>>6, lane = tid&63;
    int fid = vbid*4 + q;
    int g = fid % NG_;
    int n = (fid / NG_) % N_;
    int b = fid / (NG_*N_);
    const float* nm = normal + (size_t)(b*N_+n)*3;
    const float* pp = pos + (size_t)(b*N_+n)*3;
    const float* gg = grid + g*3;
    float f0 = nm[0]*gg[0] + nm[1]*gg[1] + nm[2]*gg[2];
    float t = e1b[lane] + f0*e1w[lane] + pp[0]*e1w[64+lane] + pp[1]*e1w[128+lane] + pp[2]*e1w[192+lane];
    ts4[q][lane] = gelu_f(t);
    __syncthreads();
    float acc = e2b[lane];
    #pragma unroll
    for (int i=0;i<64;++i) acc = fmaf(ts4[q][i], e2w[i*64+lane], acc);
    x1p[(size_t)fid*64 + lane] = pack_hl(acc);
  } else if (bid < FPSB + LIFTB + WSB){
    int tg = (bid - FPSB - LIFTB)*256 + tid;
    if (tg < 16384){
      int j = tg >> 7, k = tg & 127;
      float x = bx1w[k*128 + j];
      ushort_t hi = bf16_rne(x);
      float hif = __uint_as_float(((uint_t)hi)<<16);
      ushort_t lo = bf16_rne(x - hif);
      w1hiT[tg] = hi; w1loT[tg] = lo;
    }
    if (tg < 8192){
      int c = tg >> 7, j = tg & 127;
      float x = bx2w[j*64 + c];
      ushort_t hi = bf16_rne(x);
      float hif = __uint_as_float(((uint_t)hi)<<16);
      ushort_t lo = bf16_rne(x - hif);
      w2hiT[tg] = hi; w2loT[tg] = lo;
    }
    if (tg < 8192){
      int c = tg >> 6, d = tg & 63;
      float xa = kxw1[d*128 + c];
      ushort_t hi = bf16_rne(xa);
      float hif = __uint_as_float(((uint_t)hi)<<16);
      ushort_t lo = bf16_rne(xa - hif);
      x1hiT[tg] = hi; x1loT[tg] = lo;
      float xb = kxw2[d*128 + c];
      ushort_t hi2 = bf16_rne(xb);
      float hif2 = __uint_as_float(((uint_t)hi2)<<16);
      ushort_t lo2 = bf16_rne(xb - hif2);
      x2hiT[tg] = hi2; x2loT[tg] = lo2;
      float xd = dww[d*128 + c];
      ushort_t hi3 = bf16_rne(xd);
      float hif3 = __uint_as_float(((uint_t)hi3)<<16);
      ushort_t lo3 = bf16_rne(xd - hif3);
      dwThi[tg] = hi3; dwTlo[tg] = lo3;
    }
  } else if (bid < FPSB + LIFTB + WSB + KBRB){
    // kbR basis MLP + both kR layers (pair-local)
    int vbid = bid - FPSB - LIFTB - WSB;
    int gm = vbid / NG_, gn = vbid % NG_;
    int j = tid;
    if (j < 128){
      float z = grid[gm*3]*grid[gn*3] + grid[gm*3+1]*grid[gn*3+1] + grid[gm*3+2]*grid[gn*3+2];
      float ang = 6.283185307179586f * (z * bR_rff[j & 63]);
      fsb[j] = (j<64) ? sinf(ang) : cosf(ang);
    }
    __syncthreads();
    if (j < 128){
      float acc = bR1b[j];
      for (int i=0;i<128;++i) acc = fmaf(fsb[i], bR1w[i*128+j], acc);
      hsb[j] = gelu_f(acc);
    }
    __syncthreads();
    if (j < 64){
      float a2 = bR2b[j];
      for (int i=0;i<128;++i) a2 = fmaf(hsb[i], bR2w[i*64+j], a2);
      fsb[j] = gelu_f(a2);
    }
    __syncthreads();
    if (j < 128){
      float a1 = kR1b[j], a2v = kR2b[j];
      for (int d=0; d<64; ++d){
        float kv = fsb[d];
        a1  = fmaf(kv, kR1w[d*128+j], a1);
        a2v = fmaf(kv, kR2w[d*128+j], a2v);
      }
      kRb1[(size_t)vbid*128 + j] = a1;
      kRb2[(size_t)vbid*128 + j] = a2v;
    }
  } else {
    // pos -> padded float4 pos4
    int i = (bid - FPSB - LIFTB - WSB - KBRB)*256 + tid;   // 0..8191
    const float* p = pos + (size_t)i*3;
    pos4[i] = make_float4(p[0], p[1], p[2], 0.f);
  }
}

// ============ KNN: 4 queries/block (wave-per-query), float4 pools ============
template<int NP>
__device__ __forceinline__ void knn_body4(int qm, const float4* __restrict__ qp4,
                                          const float4* __restrict__ pool4, int* __restrict__ out){
  constexpr int R = NP/64;
  int lane = threadIdx.x & 63;
  int b = qm / M_;
  float4 q = qp4[qm];
  float qx=q.x, qy=q.y, qz=q.z;
  float d2[R];
  #pragma unroll
  for (int j=0;j<R;++j){
    float4 p = pool4[(size_t)b*NP + lane + 64*j];
    float dx=__fsub_rn(qx,p.x), dy=__fsub_rn(qy,p.y), dz=__fsub_rn(qz,p.z);
    d2[j]=__fadd_rn(__fadd_rn(__fmul_rn(dx,dx),__fmul_rn(dy,dy)),__fmul_rn(dz,dz));
  }
  for (int r=0;r<K_;++r){
    float v=FLT_MAX; int vi=0x7fffffff;
    #pragma unroll
    for (int j=0;j<R;++j){
      if (d2[j]<v){ v=d2[j]; vi=lane+64*j; }
    }
    DPP_AMIN(0x121); DPP_AMIN(0x122); DPP_AMIN(0x124); DPP_AMIN(0x128);
    DPP_AMIN(0x142); DPP_AMIN(0x143);
    int si = __builtin_amdgcn_readlane(vi, 63);
    if (lane==0) out[(size_t)qm*K_ + r] = si;
    #pragma unroll
    for (int j=0;j<R;++j){ if (si == lane + 64*j) d2[j] = FLT_MAX; }
  }
}

__global__ __launch_bounds__(256) void k_knn_all(const float4* __restrict__ ps4,
    const float4* __restrict__ pos4, int* __restrict__ nbrD, int* __restrict__ nbrS){
  int w = threadIdx.x >> 6;
  int bid = blockIdx.x;
  if (bid < B_*M_/4) knn_body4<N_>(bid*4 + w, ps4, pos4, nbrD);
  else               knn_body4<M_>((bid - B_*M_/4)*4 + w, ps4, ps4, nbrS);
}

// ============ downmax (MFMA, packed x1) + kbx in one dispatch ============
__device__ __forceinline__ void dm_body(uint_t* um, int bm,
    const uint_t* __restrict__ x1p, const int* __restrict__ nbrD,
    const ushort_t* __restrict__ dwThi, const ushort_t* __restrict__ dwTlo,
    const float* __restrict__ db, float* __restrict__ xA){
  int b = bm / M_;
  int tid = threadIdx.x;
  uint_t* xs = um;                       // [16][768] packed, xor-swizzled granules
  int* nb = (int*)(um + 12288);
  if (tid < K_) nb[tid] = nbrD[(size_t)bm*K_ + tid];
  __syncthreads();
  for (int idx=tid; idx<3072; idx+=256){
    int k = idx / 192, qq = idx % 192;
    uint4 vv = ((const uint4*)&x1p[((size_t)(b*N_) + nb[k])*(NG_*H_)])[qq];
    int gran = (qq >> 1) ^ (k & 7);
    *(uint4*)&xs[k*768 + gran*8 + (qq&1)*4] = vv;
  }
  __syncthreads();
  int wid = tid>>6, lane = tid&63, ln = lane&15, g4 = lane>>4;
  short8 bh[2][2], bl[2][2];
  float dbv[2];
  #pragma unroll
  for (int nt=0; nt<2; ++nt){
    int col = wid*32 + nt*16 + ln;
    dbv[nt] = db[col];
    #pragma unroll
    for (int ks=0; ks<2; ++ks){
      bh[nt][ks] = *(const short8*)&dwThi[(size_t)col*64 + ks*32 + g4*8];
      bl[nt][ks] = *(const short8*)&dwTlo[(size_t)col*64 + ks*32 + g4*8];
    }
  }
  int xorl = ln & 7;
  #pragma unroll
  for (int g=0; g<NG_; ++g){
    short8 ah[2], al[2];
    #pragma unroll
    for (int ks=0; ks<2; ++ks){
      int col0 = g*64 + ks*32 + g4*8;
      int gran = (col0 >> 3) ^ xorl;
      const uint_t* src = &xs[ln*768 + gran*8];
      uint4 q0 = *(const uint4*)src;
      uint4 q1 = *(const uint4*)(src+4);
      UNPACK8(q0, q1, ah[ks], al[ks]);
    }
    floatx4 acc[2];
    acc[0] = (floatx4){0.f,0.f,0.f,0.f};
    acc[1] = (floatx4){0.f,0.f,0.f,0.f};
    #pragma unroll
    for (int nt=0; nt<2; ++nt)
      #pragma unroll
      for (int ks=0; ks<2; ++ks){
        acc[nt] = __builtin_amdgcn_mfma_f32_16x16x32_bf16(ah[ks], bh[nt][ks], acc[nt], 0,0,0);
        acc[nt] = __builtin_amdgcn_mfma_f32_16x16x32_bf16(al[ks], bh[nt][ks], acc[nt], 0,0,0);
        acc[nt] = __builtin_amdgcn_mfma_f32_16x16x32_bf16(ah[ks], bl[nt][ks], acc[nt], 0,0,0);
      }
    #pragma unroll
    for (int nt=0; nt<2; ++nt){
      float mx = fmaxf(fmaxf(acc[nt][0],acc[nt][1]), fmaxf(acc[nt][2],acc[nt][3]));
      mx = fmaxf(mx, __shfl_xor(mx, 16));
      mx = fmaxf(mx, __shfl_xor(mx, 32));
      if (g4 == 0)
        xA[(size_t)bm*(NG_*C_) + g*C_ + wid*32 + nt*16 + ln] = fmaxf(mx + dbv[nt], 0.0f);
    }
  }
}

__device__ __forceinline__ void kbx_body(float* um, int vbid,
    const float* __restrict__ ps, const int* __restrict__ nbr,
    const float* __restrict__ grid, const float* __restrict__ rff,
    const ushort_t* __restrict__ w1hiT, const ushort_t* __restrict__ w1loT,
    const ushort_t* __restrict__ w2hiT, const ushort_t* __restrict__ w2loT,
    const float* __restrict__ b1, const float* __restrict__ b2,
    uint_t* __restrict__ kbxp){
  float* z0s = um;
  float* z1s = um + 128;
  float* rws = um + 256;
  int tid = threadIdx.x;
  if (tid < 128){
    rws[tid] = rff[tid];
    int fid = vbid*128 + tid;
    int g = fid % NG_;
    int k = (fid/NG_) % K_;
    int bm = fid / (NG_*K_);
    int b = bm / M_;
    int nb = nbr[(size_t)bm*K_ + k];
    const float* pm = ps + (size_t)bm*3;
    const float* pn = ps + ((size_t)(b*M_) + nb)*3;
    float rx = pn[0]-pm[0], ry = pn[1]-pm[1], rz3 = pn[2]-pm[2];
    const float* gg = grid + g*3;
    float rz = rx*gg[0] + ry*gg[1] + rz3*gg[2];
    float vx = rx - rz*gg[0], vy = ry - rz*gg[1], vz = rz3 - rz*gg[2];
    float rxy = sqrtf(vx*vx + vy*vy + vz*vz + 1e-12f);
    z0s[tid]=rxy; z1s[tid]=rz;
  }
  __syncthreads();
  int wid = tid>>6, lane = tid&63;
  int ln = lane & 15, g = lane >> 4;
  float* bw = um + 384 + wid*1088;

  short8 ahi[2][4], alo[2][4];
  #pragma unroll
  for (int rt=0; rt<2; ++rt){
    float z0 = z0s[wid*32 + rt*16 + ln];
    float z1 = z1s[wid*32 + rt*16 + ln];
    #pragma unroll
    for (int ks=0; ks<4; ++ks){
      float vv[8];
      #pragma unroll
      for (int e=0; e<8; ++e){
        int kd = ks*32 + g*8 + e;
        int kk = kd & 63;
        float t = z0*rws[kk] + z1*rws[64+kk];
        t = t - floorf(t);
        vv[e] = (ks < 2) ? __builtin_amdgcn_sinf(t) : __builtin_amdgcn_cosf(t);
      }
      uint_t* hp = (uint_t*)&ahi[rt][ks];
      uint_t* lp = (uint_t*)&alo[rt][ks];
      #pragma unroll
      for (int p=0; p<4; ++p) split2(vv[2*p], vv[2*p+1], hp[p], lp[p]);
    }
  }
  floatx4 acc2[2][4];
  #pragma unroll
  for (int rt=0; rt<2; ++rt)
    #pragma unroll
    for (int ct=0; ct<4; ++ct)
      acc2[rt][ct] = (floatx4){0.f,0.f,0.f,0.f};

  #pragma unroll
  for (int jp=0; jp<4; ++jp){
    floatx4 acc1[2][2];
    #pragma unroll
    for (int rt=0; rt<2; ++rt)
      #pragma unroll
      for (int jt=0; jt<2; ++jt)
        acc1[rt][jt] = (floatx4){0.f,0.f,0.f,0.f};
    #pragma unroll
    for (int ks=0; ks<4; ++ks){
      #pragma unroll
      for (int jt=0; jt<2; ++jt){
        int j = jp*32 + jt*16 + ln;
        short8 bhi = *(const short8*)&w1hiT[(size_t)j*128 + ks*32 + g*8];
        short8 blo = *(const short8*)&w1loT[(size_t)j*128 + ks*32 + g*8];
        #pragma unroll
        for (int rt=0; rt<2; ++rt){
          acc1[rt][jt] = __builtin_amdgcn_mfma_f32_16x16x32_bf16(ahi[rt][ks], bhi, acc1[rt][jt], 0,0,0);
          acc1[rt][jt] = __builtin_amdgcn_mfma_f32_16x16x32_bf16(alo[rt][ks], bhi, acc1[rt][jt], 0,0,0);
          acc1[rt][jt] = __builtin_amdgcn_mfma_f32_16x16x32_bf16(ahi[rt][ks], blo, acc1[rt][jt], 0,0,0);
        }
      }
    }
    #pragma unroll
    for (int jt=0; jt<2; ++jt){
      float bb = b1[jp*32 + jt*16 + ln];
      #pragma unroll
      for (int rt=0; rt<2; ++rt)
        #pragma unroll
        for (int i=0; i<4; ++i)
          bw[(rt*16 + g*4 + i)*34 + jt*16 + ln] = gelu_f(bb + acc1[rt][jt][i]);
    }
    #pragma unroll
    for (int rt=0; rt<2; ++rt){
      int base = (rt*16 + ln)*34 + g*8;
      float2 p0 = *(float2*)&bw[base+0];
      float2 p1 = *(float2*)&bw[base+2];
      float2 p2 = *(float2*)&bw[base+4];
      float2 p3 = *(float2*)&bw[base+6];
      short8 a2h, a2l;
      uint_t* hp = (uint_t*)&a2h;
      uint_t* lp = (uint_t*)&a2l;
      split2(p0.x, p0.y, hp[0], lp[0]);
      split2(p1.x, p1.y, hp[1], lp[1]);
      split2(p2.x, p2.y, hp[2], lp[2]);
      split2(p3.x, p3.y, hp[3], lp[3]);
      #pragma unroll
      for (int ct=0; ct<4; ++ct){
        short8 b2h = *(const short8*)&w2hiT[(size_t)(ct*16+ln)*128 + jp*32 + g*8];
        short8 b2l = *(const short8*)&w2loT[(size_t)(ct*16+ln)*128 + jp*32 + g*8];
        acc2[rt][ct] = __builtin_amdgcn_mfma_f32_16x16x32_bf16(a2h, b2h, acc2[rt][ct], 0,0,0);
        acc2[rt][ct] = __builtin_amdgcn_mfma_f32_16x16x32_bf16(a2l, b2h, acc2[rt][ct], 0,0,0);
        acc2[rt][ct] = __builtin_amdgcn_mfma_f32_16x16x32_bf16(a2h, b2l, acc2[rt][ct], 0,0,0);
      }
    }
  }
  #pragma unroll
  for (int ct=0; ct<4; ++ct){
    float bb = b2[ct*16 + ln];
    #pragma unroll
    for (int rt=0; rt<2; ++rt)
      #pragma unroll
      for (int i=0; i<4; ++i){
        int row = wid*32 + rt*16 + g*4 + i;
        size_t fiber = (size_t)vbid*128 + row;
        kbxp[fiber*64 + ct*16 + ln] = pack_hl2(gelu_f(bb + acc2[rt][ct][i]));
      }
  }
}

__global__ __launch_bounds__(256) void k_dmkbx(
    const uint_t* __restrict__ x1p, const int* __restrict__ nbrD,
    const ushort_t* __restrict__ dwThi, const ushort_t* __restrict__ dwTlo,
    const float* __restrict__ db, float* __restrict__ xA,
    const float* __restrict__ ps, const int* __restrict__ nbrS,
    const float* __restrict__ grid, const float* __restrict__ rff,
    const ushort_t* __restrict__ w1hiT, const ushort_t* __restrict__ w1loT,
    const ushort_t* __restrict__ w2hiT, const ushort_t* __restrict__ w2loT,
    const float* __restrict__ b1, const float* __restrict__ b2,
    uint_t* __restrict__ kbxp){
  __shared__ __align__(16) uint_t um[12384];   // 49.5 KB union
  int bid = blockIdx.x;
  if (bid < B_*M_)
    dm_body(um, bid, x1p, nbrD, dwThi, dwTlo, db, xA);
  else
    kbx_body((float*)um, bid - B_*M_, ps, nbrS, grid, rff, w1hiT, w1loT, w2hiT, w2loT, b1, b2, kbxp);
}

// ============ interaction layer (MFMA kx-apply, T14 prefetch, aliased LDS) ============
__global__ __launch_bounds__(256) void k_inter(
    const float* __restrict__ xin, const int* __restrict__ nbr,
    const uint_t* __restrict__ kbxp, const float* __restrict__ kR,
    const ushort_t* __restrict__ kxhT, const ushort_t* __restrict__ kxlT,
    const float* __restrict__ kxb,
    const float* __restrict__ mw, const float* __restrict__ mb,
    float* __restrict__ xout, float* __restrict__ part){
  int bm = blockIdx.x; int b = bm / M_;
  int tid = threadIdx.x;
  int wid = tid>>6, lane = tid&63, ln = lane&15, g4 = lane>>4;
  int c = tid & 127, gh = tid >> 7;
  __shared__ uint_t kbsL[48][68];                 // 13.06 KB
  __shared__ __align__(16) float TsU[48*129];     // 24.19 KB; aliased: Ts -> aggS/yS/psumS
  float* aggS_ = TsU;            // [12][128]
  float* yS_   = TsU + 1536;     // [12][128]
  float* psumS_= TsU + 3072;     // [2][128]

  const uint4* ksrc = (const uint4*)(kbxp + (size_t)bm*192*64);

  uint4 ka = ksrc[tid], kbv = ksrc[tid+256], kc = ksrc[tid+512];
  int nb0 = nbr[(size_t)bm*K_+0], nb1 = nbr[(size_t)bm*K_+1],
      nb2 = nbr[(size_t)bm*K_+2], nb3 = nbr[(size_t)bm*K_+3];

  short8 bh[2][2], bl[2][2];
  float kxbv[2];
  #pragma unroll
  for (int nt=0; nt<2; ++nt){
    int cc_ = (wid*2+nt)*16 + ln;
    kxbv[nt] = kxb[cc_];
    #pragma unroll
    for (int ks=0; ks<2; ++ks){
      bh[nt][ks] = *(const short8*)&kxhT[(size_t)cc_*64 + ks*32 + g4*8];
      bl[nt][ks] = *(const short8*)&kxlT[(size_t)cc_*64 + ks*32 + g4*8];
    }
  }
  float accg[6] = {0,0,0,0,0,0};

  for (int cc=0; cc<4; ++cc){
    {
      int i0=tid, i1=tid+256, i2=tid+512;
      *(uint4*)&kbsL[i0>>4][(i0&15)*4] = ka;
      *(uint4*)&kbsL[i1>>4][(i1&15)*4] = kbv;
      *(uint4*)&kbsL[i2>>4][(i2&15)*4] = kc;
    }
    __syncthreads();   // A: kbsL ready
    float xreg[24];
    {
      const float* xr0 = xin + ((size_t)(b*M_) + nb0)*(NG_*C_);
      const float* xr1 = xin + ((size_t)(b*M_) + nb1)*(NG_*C_);
      const float* xr2 = xin + ((size_t)(b*M_) + nb2)*(NG_*C_);
      const float* xr3 = xin + ((size_t)(b*M_) + nb3)*(NG_*C_);
      #pragma unroll
      for (int gi=0; gi<6; ++gi){
        int off = (gh*6+gi)*C_ + c;
        xreg[0*6+gi] = xr0[off];
        xreg[1*6+gi] = xr1[off];
        xreg[2*6+gi] = xr2[off];
        xreg[3*6+gi] = xr3[off];
      }
    }
    if (cc < 3){
      ka  = ksrc[(cc+1)*768 + tid];
      kbv = ksrc[(cc+1)*768 + tid + 256];
      kc  = ksrc[(cc+1)*768 + tid + 512];
      nb0 = nbr[(size_t)bm*K_ + (cc+1)*4 + 0];
      nb1 = nbr[(size_t)bm*K_ + (cc+1)*4 + 1];
      nb2 = nbr[(size_t)bm*K_ + (cc+1)*4 + 2];
      nb3 = nbr[(size_t)bm*K_ + (cc+1)*4 + 3];
    }
    floatx4 acc[3][2];
    #pragma unroll
    for (int mt=0; mt<3; ++mt)
      #pragma unroll
      for (int nt=0; nt<2; ++nt)
        acc[mt][nt] = (floatx4){0.f,0.f,0.f,0.f};
    #pragma unroll
    for (int mt=0; mt<3; ++mt){
      short8 ah[2], al[2];
      #pragma unroll
      for (int ks=0; ks<2; ++ks){
        const uint_t* src = &kbsL[mt*16+ln][ks*32+g4*8];
        uint4 q0 = *(const uint4*)src;
        uint4 q1 = *(const uint4*)(src+4);
        UNPACK8(q0, q1, ah[ks], al[ks]);
      }
      #pragma unroll
      for (int nt=0; nt<2; ++nt)
        #pragma unroll
        for (int ks=0; ks<2; ++ks){
          acc[mt][nt] = __builtin_amdgcn_mfma_f32_16x16x32_bf16(ah[ks], bh[nt][ks], acc[mt][nt], 0,0,0);
          acc[mt][nt] = __builtin_amdgcn_mfma_f32_16x16x32_bf16(al[ks], bh[nt][ks], acc[mt][nt], 0,0,0);
          acc[mt][nt] = __builtin_amdgcn_mfma_f32_16x16x32_bf16(ah[ks], bl[nt][ks], acc[mt][nt], 0,0,0);
        }
    }
    #pragma unroll
    for (int mt=0; mt<3; ++mt)
      #pragma unroll
      for (int nt=0; nt<2; ++nt)
        #pragma unroll
        for (int i=0; i<4; ++i)
          TsU[(mt*16 + g4*4 + i)*129 + (wid*2+nt)*16 + ln] = acc[mt][nt][i] + kxbv[nt];
    __syncthreads();   // B: Ts ready
    #pragma unroll
    for (int kl=0; kl<4; ++kl)
      #pragma unroll
      for (int gi=0; gi<6; ++gi)
        accg[gi] = fmaf(TsU[(kl*12 + gh*6 + gi)*129 + c], xreg[kl*6+gi], accg[gi]);
    __syncthreads();   // C: Ts reads done before next chunk overwrites kbsL/Ts
  }
  // Ts region dead -> reuse for aggS/yS/psumS
  #pragma unroll
  for (int gi=0; gi<6; ++gi)
    aggS_[(gh*6+gi)*C_ + c] = accg[gi] * (1.0f/16.0f);
  __syncthreads();
  #pragma unroll
  for (int gi=0; gi<6; ++gi){
    int g = gh*6+gi;
    float yv = 0.f;
    #pragma unroll
    for (int n=0;n<NG_;++n) yv = fmaf(aggS_[n*C_ + c], kR[((size_t)g*NG_+n)*C_ + c], yv);
    yS_[g*C_ + c] = yv * (1.0f/12.0f);
  }
  __syncthreads();
  float m6[6] = {0,0,0,0,0,0};
  for (int i4=0;i4<32;++i4){
    float w0 = mw[(i4*4+0)*C_+c], w1 = mw[(i4*4+1)*C_+c],
          w2 = mw[(i4*4+2)*C_+c], w3 = mw[(i4*4+3)*C_+c];
    #pragma unroll
    for (int gi=0;gi<6;++gi){
      int g = gh*6+gi;
      float4 yv = *(const float4*)&yS_[g*C_ + i4*4];
      m6[gi] = fmaf(yv.x,w0,fmaf(yv.y,w1,fmaf(yv.z,w2,fmaf(yv.w,w3,m6[gi]))));
    }
  }
  float mbc = mb[c];
  float psum = 0.f;
  #pragma unroll
  for (int gi=0;gi<6;++gi){
    int g = gh*6+gi;
    size_t off = (size_t)bm*(NG_*C_) + g*C_ + c;
    float val = xin[off] + gelu_f(m6[gi] + mbc);
    xout[off] = val;
    psum += val;
  }
  if (part){
    psumS_[gh*C_ + c] = psum;
    __syncthreads();
    if (gh == 0)
      part[(size_t)bm*C_ + c] = psumS_[c] + psumS_[C_ + c];
  }
}

// ============ head: 512-row reduce + MLP ============
__global__ __launch_bounds__(256) void k_head(
    const float* __restrict__ part,
    const float* __restrict__ p1w, const float* __restrict__ p1b,
    const float* __restrict__ p2w, const float* __restrict__ p2b,
    const float* __restrict__ p3w, const float* __restrict__ p3b,
    float* __restrict__ out){
  int b = blockIdx.x, tid = threadIdx.x;
  int c = tid & 127, half = tid >> 7;
  __shared__ float red[256];
  __shared__ float gs[128];
  {
    const float* pb = part + (size_t)b*M_*C_;
    float a0=0.f,a1=0.f,a2=0.f,a3=0.f;
    for (int r = half*4; r < M_; r += 8){
      a0 += pb[(size_t)(r+0)*C_ + c];
      a1 += pb[(size_t)(r+1)*C_ + c];
      a2 += pb[(size_t)(r+2)*C_ + c];
      a3 += pb[(size_t)(r+3)*C_ + c];
    }
    red[tid] = (a0+a1)+(a2+a3);
  }
  __syncthreads();
  if (half==0) gs[c] = (red[c] + red[128+c]) * (1.0f/(M_*NG_));
  __syncthreads();
  __shared__ float h1[256];
  {
    float a = p1b[tid];
    for (int i=0;i<128;++i) a = fmaf(gs[i], p1w[i*256+tid], a);
    h1[tid] = gelu_f(a);
  }
  __syncthreads();
  __shared__ float h2[64];
  if (tid<64){
    float a = p2b[tid];
    for (int i=0;i<256;++i) a = fmaf(h1[i], p2w[i*64+tid], a);
    h2[tid] = gelu_f(a);
  }
  __syncthreads();
  if (tid==0){
    float a = p3b[0];
    for (int i=0;i<64;++i) a = fmaf(h2[i], p3w[i], a);
    out[b] = a;
  }
}

extern "C" void kernel_launch(void* const* d_in, const int* in_sizes, int n_in,
                              void* d_out, int out_size, void* d_ws, size_t ws_size,
                              hipStream_t stream){
  const float* pos    = (const float*)d_in[0];
  const float* normal = (const float*)d_in[1];
  const float* grid   = (const float*)d_in[2];
  const float* e1w = (const float*)d_in[3];  const float* e1b = (const float*)d_in[4];
  const float* e2w = (const float*)d_in[5];  const float* e2b = (const float*)d_in[6];
  const float* dww = (const float*)d_in[7];  const float* dwb = (const float*)d_in[8];
  const float* bx_rff = (const float*)d_in[9];
  const float* bx1w = (const float*)d_in[10]; const float* bx1b = (const float*)d_in[11];
  const float* bx2w = (const float*)d_in[12]; const float* bx2b = (const float*)d_in[13];
  const float* bR_rff = (const float*)d_in[14];
  const float* bR1w = (const float*)d_in[15]; const float* bR1b = (const float*)d_in[16];
  const float* bR2w = (const float*)d_in[17]; const float* bR2b = (const float*)d_in[18];
  const float* i1kxw = (const float*)d_in[19]; const float* i1kxb = (const float*)d_in[20];
  const float* i1kRw = (const float*)d_in[21]; const float* i1kRb = (const float*)d_in[22];
  const float* i1mw  = (const float*)d_in[23]; const float* i1mb  = (const float*)d_in[24];
  const float* i2kxw = (const float*)d_in[25]; const float* i2kxb = (const float*)d_in[26];
  const float* i2kRw = (const float*)d_in[27]; const float* i2kRb = (const float*)d_in[28];
  const float* i2mw  = (const float*)d_in[29]; const float* i2mb  = (const float*)d_in[30];
  const float* p1w = (const float*)d_in[31]; const float* p1b = (const float*)d_in[32];
  const float* p2w = (const float*)d_in[33]; const float* p2b = (const float*)d_in[34];
  const float* p3w = (const float*)d_in[35]; const float* p3b = (const float*)d_in[36];
  float* out = (float*)d_out;

  float* ws = (float*)d_ws;
  size_t o = 0;
  uint_t* x1p = (uint_t*)(ws + o); o += (size_t)B_*N_*NG_*H_;
  float* psb = ws + o; o += (size_t)B_*M_*3;
  float* xA  = ws + o; o += (size_t)B_*M_*NG_*C_;
  float* xB  = ws + o; o += (size_t)B_*M_*NG_*C_;
  uint_t* kbxp = (uint_t*)(ws + o); o += (size_t)B_*M_*K_*NG_*BD_;
  float* kRb1 = ws + o; o += (size_t)NG_*NG_*C_;
  float* kRb2 = ws + o; o += (size_t)NG_*NG_*C_;
  float* part = ws + o; o += (size_t)B_*M_*C_;
  float4* pos4 = (float4*)(ws + o); o += (size_t)B_*N_*4;
  float4* ps4  = (float4*)(ws + o); o += (size_t)B_*M_*4;
  int* nbrD  = (int*)(ws + o); o += (size_t)B_*M_*K_;
  int* nbrS  = (int*)(ws + o); o += (size_t)B_*M_*K_;
  ushort_t* w1hiT = (ushort_t*)(ws + o); o += 8192;
  ushort_t* w1loT = (ushort_t*)(ws + o); o += 8192;
  ushort_t* w2hiT = (ushort_t*)(ws + o); o += 4096;
  ushort_t* w2loT = (ushort_t*)(ws + o); o += 4096;
  ushort_t* x1hiT = (ushort_t*)(ws + o); o += 4096;
  ushort_t* x1loT = (ushort_t*)(ws + o); o += 4096;
  ushort_t* x2hiT = (ushort_t*)(ws + o); o += 4096;
  ushort_t* x2loT = (ushort_t*)(ws + o); o += 4096;
  ushort_t* dwThi = (ushort_t*)(ws + o); o += 4096;
  ushort_t* dwTlo = (ushort_t*)(ws + o); o += 4096;

  k_mega1<<<FPSB + LIFTB + WSB + KBRB + PM4B, 256, 0, stream>>>(
      pos, normal, grid, e1w, e1b, e2w, e2b, x1p, psb, pos4, ps4,
      bx1w, bx2w, i1kxw, i2kxw, dww,
      w1hiT, w1loT, w2hiT, w2loT, x1hiT, x1loT, x2hiT, x2loT, dwThi, dwTlo,
      bR_rff, bR1w, bR1b, bR2w, bR2b,
      i1kRw, i1kRb, i2kRw, i2kRb, kRb1, kRb2);
  k_knn_all<<<B_*M_/2, 256, 0, stream>>>(ps4, pos4, nbrD, nbrS);
  k_dmkbx<<<B_*M_ + (B_*M_*K_*NG_)/128, 256, 0, stream>>>(
      x1p, nbrD, dwThi, dwTlo, dwb, xA,
      psb, nbrS, grid, bx_rff, w1hiT, w1loT, w2hiT, w2loT, bx1b, bx2b, kbxp);
  k_inter<<<B_*M_, 256, 0, stream>>>(xA, nbrS, kbxp, kRb1, x1hiT, x1loT, i1kxb, i1mw, i1mb, xB, nullptr);
  k_inter<<<B_*M_, 256, 0, stream>>>(xB, nbrS, kbxp, kRb2, x2hiT, x2loT, i2kxb, i2mw, i2mb, xA, part);
  k_head<<<B_, 256, 0, stream>>>(part, p1w, p1b, p2w, p2b, p3w, p3b, out);
}

// Round 13
// 722.667 us; speedup vs baseline: 1.9462x; 1.0137x over previous
//
#include <hip/hip_runtime.h>
#include <hip/hip_bf16.h>
#include <cfloat>

#define B_ 4
#define N_ 2048
#define NG_ 12
#define K_ 16
#define H_ 64
#define C_ 128
#define BD_ 64
#define M_ 512

typedef __attribute__((ext_vector_type(8))) short short8;
typedef __attribute__((ext_vector_type(4))) float floatx4;
typedef unsigned short ushort_t;
typedef unsigned int uint_t;

__device__ __forceinline__ float gelu_f(float x){
  float s = 0.7978845608028654f*(x + 0.044715f*x*x*x);
  float e = __expf(2.0f*s);
  float t = 1.0f - 2.0f/(e + 1.0f);
  return 0.5f*x*(1.0f + t);
}

__device__ __forceinline__ ushort_t bf16_rne(float x){
  uint_t u = __float_as_uint(x);
  uint_t r = (u + 0x7fffu + ((u >> 16) & 1u)) >> 16;
  return (ushort_t)r;
}

__device__ __forceinline__ uint_t pack_hl(float x){
  ushort_t hi = bf16_rne(x);
  float hif = __uint_as_float(((uint_t)hi)<<16);
  ushort_t lo = bf16_rne(x - hif);
  return (uint_t)hi | ((uint_t)lo << 16);
}

__device__ __forceinline__ uint_t cvtpk_bf16(float a, float b){
  uint_t r;
  asm("v_cvt_pk_bf16_f32 %0, %1, %2" : "=v"(r) : "v"(a), "v"(b));
  return r;
}

__device__ __forceinline__ void split2(float v0, float v1, uint_t& hp, uint_t& lp){
  hp = cvtpk_bf16(v0, v1);
  float h0 = __uint_as_float(hp << 16);
  float h1 = __uint_as_float(hp & 0xffff0000u);
  lp = cvtpk_bf16(v0 - h0, v1 - h1);
}

__device__ __forceinline__ uint_t pack_hl2(float v){
  uint_t hp = cvtpk_bf16(v, v);
  float hf = __uint_as_float(hp << 16);
  uint_t lp = cvtpk_bf16(v - hf, v - hf);
  return (hp & 0xffffu) | (lp << 16);
}

__device__ __forceinline__ uint_t perm_lo16(uint_t a, uint_t b){ return __builtin_amdgcn_perm(a, b, 0x05040100u); }
__device__ __forceinline__ uint_t perm_hi16(uint_t a, uint_t b){ return __builtin_amdgcn_perm(a, b, 0x07060302u); }

#define UNPACK8(Q0, Q1, AH, AL) { \
  uint_t* _ap = (uint_t*)&(AH); uint_t* _lp = (uint_t*)&(AL); \
  _ap[0] = perm_lo16((Q0).y, (Q0).x); _ap[1] = perm_lo16((Q0).w, (Q0).z); \
  _ap[2] = perm_lo16((Q1).y, (Q1).x); _ap[3] = perm_lo16((Q1).w, (Q1).z); \
  _lp[0] = perm_hi16((Q0).y, (Q0).x); _lp[1] = perm_hi16((Q0).w, (Q0).z); \
  _lp[2] = perm_hi16((Q1).y, (Q1).x); _lp[3] = perm_hi16((Q1).w, (Q1).z); }

#define DPP_AMAX(CTRL) { \
  int _vb = __float_as_int(v); \
  int _ov = __builtin_amdgcn_update_dpp(_vb, _vb, (CTRL), 0xF, 0xF, false); \
  int _oi = __builtin_amdgcn_update_dpp(vi, vi, (CTRL), 0xF, 0xF, false); \
  float _of = __int_as_float(_ov); \
  bool _tk = (_of > v) || (_of == v && _oi < vi); \
  v = _tk ? _of : v; vi = _tk ? _oi : vi; }

#define DPP_AMIN(CTRL) { \
  int _vb = __float_as_int(v); \
  int _ov = __builtin_amdgcn_update_dpp(_vb, _vb, (CTRL), 0xF, 0xF, false); \
  int _oi = __builtin_amdgcn_update_dpp(vi, vi, (CTRL), 0xF, 0xF, false); \
  float _of = __int_as_float(_ov); \
  bool _tk = (_of < v) || (_of == v && _oi < vi); \
  v = _tk ? _of : v; vi = _tk ? _oi : vi; }

// ============ MEGA-KERNEL 1: fps + lift + wsplit + kbR/kR + pos4 + allknnD ============
#define FPSB 4
#define LIFTB (B_*N_*NG_/4)      // 6144
#define WSB 64
#define KBRB (NG_*NG_)           // 144
#define PM4B 32
#define AKB (B_*N_/4)            // 2048: all-pairs knn-D, 4 queries/block

__global__ __launch_bounds__(256) void k_mega1(
    const float* __restrict__ pos, const float* __restrict__ normal,
    const float* __restrict__ grid,
    const float* __restrict__ e1w, const float* __restrict__ e1b,
    const float* __restrict__ e2w, const float* __restrict__ e2b,
    uint_t* __restrict__ x1p, float* __restrict__ ps,
    float4* __restrict__ pos4, float4* __restrict__ ps4,
    int* __restrict__ sidxG, int* __restrict__ allD,
    const float* __restrict__ bx1w, const float* __restrict__ bx2w,
    const float* __restrict__ kxw1, const float* __restrict__ kxw2,
    const float* __restrict__ dww,
    ushort_t* __restrict__ w1hiT, ushort_t* __restrict__ w1loT,
    ushort_t* __restrict__ w2hiT, ushort_t* __restrict__ w2loT,
    ushort_t* __restrict__ x1hiT, ushort_t* __restrict__ x1loT,
    ushort_t* __restrict__ x2hiT, ushort_t* __restrict__ x2loT,
    ushort_t* __restrict__ dwThi, ushort_t* __restrict__ dwTlo,
    const float* __restrict__ bR_rff,
    const float* __restrict__ bR1w, const float* __restrict__ bR1b,
    const float* __restrict__ bR2w, const float* __restrict__ bR2b,
    const float* __restrict__ kR1w, const float* __restrict__ kR1b,
    const float* __restrict__ kR2w, const float* __restrict__ kR2b,
    float* __restrict__ kRb1, float* __restrict__ kRb2){
  __shared__ float4 posS4[N_];        // fps
  __shared__ float2 wred[2][4];       // fps
  __shared__ int sidxS[M_];           // fps sample indices
  __shared__ float ts4[4][64];        // lift
  __shared__ float fsb[128], hsb[128];// kbR
  int bid = blockIdx.x;
  int tid = threadIdx.x;

  if (bid < FPSB){
    // ---- FPS: no global ops inside the loop
    int b = bid;
    for (int i=tid;i<N_;i+=256){
      const float* p = pos + (size_t)b*N_*3 + (size_t)i*3;
      posS4[i] = make_float4(p[0], p[1], p[2], 0.f);
    }
    __syncthreads();
    float px[8],py[8],pz[8],d[8];
    #pragma unroll
    for (int j=0;j<8;++j){
      float4 pt = posS4[tid + 256*j];
      px[j]=pt.x; py[j]=pt.y; pz[j]=pt.z;
      d[j]=1e10f;
    }
    int wave = tid>>6, lane = tid&63;
    int last = 0;
    for (int s=0;s<M_;++s){
      if (tid==0) sidxS[s] = last;
      if (s==M_-1) break;
      float4 lp = posS4[last];
      float lx=lp.x, ly=lp.y, lz=lp.z;
      #pragma unroll
      for (int j=0;j<8;++j){
        float dx=__fsub_rn(px[j],lx), dy=__fsub_rn(py[j],ly), dz=__fsub_rn(pz[j],lz);
        float dist=__fadd_rn(__fadd_rn(__fmul_rn(dx,dx),__fmul_rn(dy,dy)),__fmul_rn(dz,dz));
        d[j]=fminf(d[j],dist);
      }
      float va = d[1]>d[0]?d[1]:d[0]; int ja = d[1]>d[0]?1:0;
      float vb = d[3]>d[2]?d[3]:d[2]; int jb = d[3]>d[2]?3:2;
      float vc = d[5]>d[4]?d[5]:d[4]; int jc = d[5]>d[4]?5:4;
      float vd = d[7]>d[6]?d[7]:d[6]; int jd = d[7]>d[6]?7:6;
      float ve = vb>va?vb:va; int je = vb>va?jb:ja;
      float vf = vd>vc?vd:vc; int jf = vd>vc?jd:jc;
      float v  = vf>ve?vf:ve; int jj = vf>ve?jf:je;
      int vi = tid + (jj<<8);
      DPP_AMAX(0x121); DPP_AMAX(0x122); DPP_AMAX(0x124); DPP_AMAX(0x128);
      DPP_AMAX(0x142); DPP_AMAX(0x143);
      int sv = __builtin_amdgcn_readlane(__float_as_int(v), 63);
      int si = __builtin_amdgcn_readlane(vi, 63);
      if (lane==0) wred[s&1][wave] = make_float2(__int_as_float(sv), __int_as_float(si));
      __syncthreads();
      float2 r0 = wred[s&1][0], r1 = wred[s&1][1], r2 = wred[s&1][2], r3 = wred[s&1][3];
      float bv = r0.x; int bi = __float_as_int(r0.y);
      int i1 = __float_as_int(r1.y); if (r1.x>bv || (r1.x==bv && i1<bi)){ bv=r1.x; bi=i1; }
      int i2 = __float_as_int(r2.y); if (r2.x>bv || (r2.x==bv && i2<bi)){ bv=r2.x; bi=i2; }
      int i3 = __float_as_int(r3.y); if (r3.x>bv || (r3.x==bv && i3<bi)){ bv=r3.x; bi=i3; }
      last = bi;
    }
    __syncthreads();
    for (int i=tid; i<M_; i+=256){
      int si = sidxS[i];
      float4 p = posS4[si];
      float* o = ps + ((size_t)b*M_+i)*3;
      o[0]=p.x; o[1]=p.y; o[2]=p.z;
      ps4[(size_t)b*M_+i] = make_float4(p.x, p.y, p.z, 0.f);
      sidxG[(size_t)b*M_+i] = si;
    }
  } else if (bid < FPSB + LIFTB){
    int vbid = bid - FPSB;
    int q = tid>>6, lane = tid&63;
    int fid = vbid*4 + q;
    int g = fid % NG_;
    int n = (fid / NG_) % N_;
    int b = fid / (NG_*N_);
    const float* nm = normal + (size_t)(b*N_+n)*3;
    const float* pp = pos + (size_t)(b*N_+n)*3;
    const float* gg = grid + g*3;
    float f0 = nm[0]*gg[0] + nm[1]*gg[1] + nm[2]*gg[2];
    float t = e1b[lane] + f0*e1w[lane] + pp[0]*e1w[64+lane] + pp[1]*e1w[128+lane] + pp[2]*e1w[192+lane];
    ts4[q][lane] = gelu_f(t);
    __syncthreads();
    float acc = e2b[lane];
    #pragma unroll
    for (int i=0;i<64;++i) acc = fmaf(ts4[q][i], e2w[i*64+lane], acc);
    x1p[(size_t)fid*64 + lane] = pack_hl(acc);
  } else if (bid < FPSB + LIFTB + WSB){
    int tg = (bid - FPSB - LIFTB)*256 + tid;
    if (tg < 16384){
      int j = tg >> 7, k = tg & 127;
      float x = bx1w[k*128 + j];
      ushort_t hi = bf16_rne(x);
      float hif = __uint_as_float(((uint_t)hi)<<16);
      ushort_t lo = bf16_rne(x - hif);
      w1hiT[tg] = hi; w1loT[tg] = lo;
    }
    if (tg < 8192){
      int c = tg >> 7, j = tg & 127;
      float x = bx2w[j*64 + c];
      ushort_t hi = bf16_rne(x);
      float hif = __uint_as_float(((uint_t)hi)<<16);
      ushort_t lo = bf16_rne(x - hif);
      w2hiT[tg] = hi; w2loT[tg] = lo;
    }
    if (tg < 8192){
      int c = tg >> 6, d = tg & 63;
      float xa = kxw1[d*128 + c];
      ushort_t hi = bf16_rne(xa);
      float hif = __uint_as_float(((uint_t)hi)<<16);
      ushort_t lo = bf16_rne(xa - hif);
      x1hiT[tg] = hi; x1loT[tg] = lo;
      float xb = kxw2[d*128 + c];
      ushort_t hi2 = bf16_rne(xb);
      float hif2 = __uint_as_float(((uint_t)hi2)<<16);
      ushort_t lo2 = bf16_rne(xb - hif2);
      x2hiT[tg] = hi2; x2loT[tg] = lo2;
      float xd = dww[d*128 + c];
      ushort_t hi3 = bf16_rne(xd);
      float hif3 = __uint_as_float(((uint_t)hi3)<<16);
      ushort_t lo3 = bf16_rne(xd - hif3);
      dwThi[tg] = hi3; dwTlo[tg] = lo3;
    }
  } else if (bid < FPSB + LIFTB + WSB + KBRB){
    // kbR basis MLP + both kR layers (pair-local)
    int vbid = bid - FPSB - LIFTB - WSB;
    int gm = vbid / NG_, gn = vbid % NG_;
    int j = tid;
    if (j < 128){
      float z = grid[gm*3]*grid[gn*3] + grid[gm*3+1]*grid[gn*3+1] + grid[gm*3+2]*grid[gn*3+2];
      float ang = 6.283185307179586f * (z * bR_rff[j & 63]);
      fsb[j] = (j<64) ? sinf(ang) : cosf(ang);
    }
    __syncthreads();
    if (j < 128){
      float acc = bR1b[j];
      for (int i=0;i<128;++i) acc = fmaf(fsb[i], bR1w[i*128+j], acc);
      hsb[j] = gelu_f(acc);
    }
    __syncthreads();
    if (j < 64){
      float a2 = bR2b[j];
      for (int i=0;i<128;++i) a2 = fmaf(hsb[i], bR2w[i*64+j], a2);
      fsb[j] = gelu_f(a2);
    }
    __syncthreads();
    if (j < 128){
      float a1 = kR1b[j], a2v = kR2b[j];
      for (int d=0; d<64; ++d){
        float kv = fsb[d];
        a1  = fmaf(kv, kR1w[d*128+j], a1);
        a2v = fmaf(kv, kR2w[d*128+j], a2v);
      }
      kRb1[(size_t)vbid*128 + j] = a1;
      kRb2[(size_t)vbid*128 + j] = a2v;
    }
  } else if (bid < FPSB + LIFTB + WSB + KBRB + PM4B){
    // pos -> padded float4 pos4
    int i = (bid - FPSB - LIFTB - WSB - KBRB)*256 + tid;   // 0..8191
    const float* p = pos + (size_t)i*3;
    pos4[i] = make_float4(p[0], p[1], p[2], 0.f);
  } else {
    // ---- all-pairs knn-D: query i = pos[i] over pool pos[b] (hidden under FPS) ----
    int w = tid>>6, lane = tid&63;
    int qi = (bid - FPSB - LIFTB - WSB - KBRB - PM4B)*4 + w;   // 0..8191 = b*N+n
    int b = qi / N_;
    const float* q = pos + (size_t)qi*3;
    float qx=q[0], qy=q[1], qz=q[2];
    float d2[32];
    #pragma unroll
    for (int j=0;j<32;++j){
      const float* p = pos + ((size_t)(b*N_) + lane + 64*j)*3;
      float dx=__fsub_rn(qx,p[0]), dy=__fsub_rn(qy,p[1]), dz=__fsub_rn(qz,p[2]);
      d2[j]=__fadd_rn(__fadd_rn(__fmul_rn(dx,dx),__fmul_rn(dy,dy)),__fmul_rn(dz,dz));
    }
    for (int r=0;r<K_;++r){
      float v=FLT_MAX; int vi=0x7fffffff;
      #pragma unroll
      for (int j=0;j<32;++j){
        if (d2[j]<v){ v=d2[j]; vi=lane+64*j; }
      }
      DPP_AMIN(0x121); DPP_AMIN(0x122); DPP_AMIN(0x124); DPP_AMIN(0x128);
      DPP_AMIN(0x142); DPP_AMIN(0x143);
      int si = __builtin_amdgcn_readlane(vi, 63);
      if (lane==0) allD[(size_t)qi*K_ + r] = si;
      #pragma unroll
      for (int j=0;j<32;++j){ if (si == lane + 64*j) d2[j] = FLT_MAX; }
    }
  }
}

// ============ KNN-S only (pool = ps) ============
template<int NP>
__device__ __forceinline__ void knn_body4(int qm, const float4* __restrict__ qp4,
                                          const float4* __restrict__ pool4, int* __restrict__ out){
  constexpr int R = NP/64;
  int lane = threadIdx.x & 63;
  int b = qm / M_;
  float4 q = qp4[qm];
  float qx=q.x, qy=q.y, qz=q.z;
  float d2[R];
  #pragma unroll
  for (int j=0;j<R;++j){
    float4 p = pool4[(size_t)b*NP + lane + 64*j];
    float dx=__fsub_rn(qx,p.x), dy=__fsub_rn(qy,p.y), dz=__fsub_rn(qz,p.z);
    d2[j]=__fadd_rn(__fadd_rn(__fmul_rn(dx,dx),__fmul_rn(dy,dy)),__fmul_rn(dz,dz));
  }
  for (int r=0;r<K_;++r){
    float v=FLT_MAX; int vi=0x7fffffff;
    #pragma unroll
    for (int j=0;j<R;++j){
      if (d2[j]<v){ v=d2[j]; vi=lane+64*j; }
    }
    DPP_AMIN(0x121); DPP_AMIN(0x122); DPP_AMIN(0x124); DPP_AMIN(0x128);
    DPP_AMIN(0x142); DPP_AMIN(0x143);
    int si = __builtin_amdgcn_readlane(vi, 63);
    if (lane==0) out[(size_t)qm*K_ + r] = si;
    #pragma unroll
    for (int j=0;j<R;++j){ if (si == lane + 64*j) d2[j] = FLT_MAX; }
  }
}

__global__ __launch_bounds__(256) void k_knn_all(const float4* __restrict__ ps4,
    int* __restrict__ nbrS){
  int w = threadIdx.x >> 6;
  knn_body4<M_>(blockIdx.x*4 + w, ps4, ps4, nbrS);
}

// ============ downmax (MFMA, packed x1) + kbx in one dispatch ============
__device__ __forceinline__ void dm_body(uint_t* um, int bm,
    const uint_t* __restrict__ x1p,
    const int* __restrict__ sidxG, const int* __restrict__ allD,
    const ushort_t* __restrict__ dwThi, const ushort_t* __restrict__ dwTlo,
    const float* __restrict__ db, float* __restrict__ xA){
  int b = bm / M_;
  int tid = threadIdx.x;
  uint_t* xs = um;                       // [16][768] packed, xor-swizzled granules
  int* nb = (int*)(um + 12288);
  if (tid < K_) nb[tid] = allD[((size_t)(b*N_) + sidxG[bm])*K_ + tid];
  __syncthreads();
  for (int idx=tid; idx<3072; idx+=256){
    int k = idx / 192, qq = idx % 192;
    uint4 vv = ((const uint4*)&x1p[((size_t)(b*N_) + nb[k])*(NG_*H_)])[qq];
    int gran = (qq >> 1) ^ (k & 7);
    *(uint4*)&xs[k*768 + gran*8 + (qq&1)*4] = vv;
  }
  __syncthreads();
  int wid = tid>>6, lane = tid&63, ln = lane&15, g4 = lane>>4;
  short8 bh[2][2], bl[2][2];
  float dbv[2];
  #pragma unroll
  for (int nt=0; nt<2; ++nt){
    int col = wid*32 + nt*16 + ln;
    dbv[nt] = db[col];
    #pragma unroll
    for (int ks=0; ks<2; ++ks){
      bh[nt][ks] = *(const short8*)&dwThi[(size_t)col*64 + ks*32 + g4*8];
      bl[nt][ks] = *(const short8*)&dwTlo[(size_t)col*64 + ks*32 + g4*8];
    }
  }
  int xorl = ln & 7;
  #pragma unroll
  for (int g=0; g<NG_; ++g){
    short8 ah[2], al[2];
    #pragma unroll
    for (int ks=0; ks<2; ++ks){
      int col0 = g*64 + ks*32 + g4*8;
      int gran = (col0 >> 3) ^ xorl;
      const uint_t* src = &xs[ln*768 + gran*8];
      uint4 q0 = *(const uint4*)src;
      uint4 q1 = *(const uint4*)(src+4);
      UNPACK8(q0, q1, ah[ks], al[ks]);
    }
    floatx4 acc[2];
    acc[0] = (floatx4){0.f,0.f,0.f,0.f};
    acc[1] = (floatx4){0.f,0.f,0.f,0.f};
    #pragma unroll
    for (int nt=0; nt<2; ++nt)
      #pragma unroll
      for (int ks=0; ks<2; ++ks){
        acc[nt] = __builtin_amdgcn_mfma_f32_16x16x32_bf16(ah[ks], bh[nt][ks], acc[nt], 0,0,0);
        acc[nt] = __builtin_amdgcn_mfma_f32_16x16x32_bf16(al[ks], bh[nt][ks], acc[nt], 0,0,0);
        acc[nt] = __builtin_amdgcn_mfma_f32_16x16x32_bf16(ah[ks], bl[nt][ks], acc[nt], 0,0,0);
      }
    #pragma unroll
    for (int nt=0; nt<2; ++nt){
      float mx = fmaxf(fmaxf(acc[nt][0],acc[nt][1]), fmaxf(acc[nt][2],acc[nt][3]));
      mx = fmaxf(mx, __shfl_xor(mx, 16));
      mx = fmaxf(mx, __shfl_xor(mx, 32));
      if (g4 == 0)
        xA[(size_t)bm*(NG_*C_) + g*C_ + wid*32 + nt*16 + ln] = fmaxf(mx + dbv[nt], 0.0f);
    }
  }
}

__device__ __forceinline__ void kbx_body(float* um, int vbid,
    const float* __restrict__ ps, const int* __restrict__ nbr,
    const float* __restrict__ grid, const float* __restrict__ rff,
    const ushort_t* __restrict__ w1hiT, const ushort_t* __restrict__ w1loT,
    const ushort_t* __restrict__ w2hiT, const ushort_t* __restrict__ w2loT,
    const float* __restrict__ b1, const float* __restrict__ b2,
    uint_t* __restrict__ kbxp){
  float* z0s = um;
  float* z1s = um + 128;
  float* rws = um + 256;
  int tid = threadIdx.x;
  if (tid < 128){
    rws[tid] = rff[tid];
    int fid = vbid*128 + tid;
    int g = fid % NG_;
    int k = (fid/NG_) % K_;
    int bm = fid / (NG_*K_);
    int b = bm / M_;
    int nb = nbr[(size_t)bm*K_ + k];
    const float* pm = ps + (size_t)bm*3;
    const float* pn = ps + ((size_t)(b*M_) + nb)*3;
    float rx = pn[0]-pm[0], ry = pn[1]-pm[1], rz3 = pn[2]-pm[2];
    const float* gg = grid + g*3;
    float rz = rx*gg[0] + ry*gg[1] + rz3*gg[2];
    float vx = rx - rz*gg[0], vy = ry - rz*gg[1], vz = rz3 - rz*gg[2];
    float rxy = sqrtf(vx*vx + vy*vy + vz*vz + 1e-12f);
    z0s[tid]=rxy; z1s[tid]=rz;
  }
  __syncthreads();
  int wid = tid>>6, lane = tid&63;
  int ln = lane & 15, g = lane >> 4;
  float* bw = um + 384 + wid*1088;

  short8 ahi[2][4], alo[2][4];
  #pragma unroll
  for (int rt=0; rt<2; ++rt){
    float z0 = z0s[wid*32 + rt*16 + ln];
    float z1 = z1s[wid*32 + rt*16 + ln];
    #pragma unroll
    for (int ks=0; ks<4; ++ks){
      float vv[8];
      #pragma unroll
      for (int e=0; e<8; ++e){
        int kd = ks*32 + g*8 + e;
        int kk = kd & 63;
        float t = z0*rws[kk] + z1*rws[64+kk];
        t = t - floorf(t);
        vv[e] = (ks < 2) ? __builtin_amdgcn_sinf(t) : __builtin_amdgcn_cosf(t);
      }
      uint_t* hp = (uint_t*)&ahi[rt][ks];
      uint_t* lp = (uint_t*)&alo[rt][ks];
      #pragma unroll
      for (int p=0; p<4; ++p) split2(vv[2*p], vv[2*p+1], hp[p], lp[p]);
    }
  }
  floatx4 acc2[2][4];
  #pragma unroll
  for (int rt=0; rt<2; ++rt)
    #pragma unroll
    for (int ct=0; ct<4; ++ct)
      acc2[rt][ct] = (floatx4){0.f,0.f,0.f,0.f};

  #pragma unroll
  for (int jp=0; jp<4; ++jp){
    floatx4 acc1[2][2];
    #pragma unroll
    for (int rt=0; rt<2; ++rt)
      #pragma unroll
      for (int jt=0; jt<2; ++jt)
        acc1[rt][jt] = (floatx4){0.f,0.f,0.f,0.f};
    #pragma unroll
    for (int ks=0; ks<4; ++ks){
      #pragma unroll
      for (int jt=0; jt<2; ++jt){
        int j = jp*32 + jt*16 + ln;
        short8 bhi = *(const short8*)&w1hiT[(size_t)j*128 + ks*32 + g*8];
        short8 blo = *(const short8*)&w1loT[(size_t)j*128 + ks*32 + g*8];
        #pragma unroll
        for (int rt=0; rt<2; ++rt){
          acc1[rt][jt] = __builtin_amdgcn_mfma_f32_16x16x32_bf16(ahi[rt][ks], bhi, acc1[rt][jt], 0,0,0);
          acc1[rt][jt] = __builtin_amdgcn_mfma_f32_16x16x32_bf16(alo[rt][ks], bhi, acc1[rt][jt], 0,0,0);
          acc1[rt][jt] = __builtin_amdgcn_mfma_f32_16x16x32_bf16(ahi[rt][ks], blo, acc1[rt][jt], 0,0,0);
        }
      }
    }
    #pragma unroll
    for (int jt=0; jt<2; ++jt){
      float bb = b1[jp*32 + jt*16 + ln];
      #pragma unroll
      for (int rt=0; rt<2; ++rt)
        #pragma unroll
        for (int i=0; i<4; ++i)
          bw[(rt*16 + g*4 + i)*34 + jt*16 + ln] = gelu_f(bb + acc1[rt][jt][i]);
    }
    #pragma unroll
    for (int rt=0; rt<2; ++rt){
      int base = (rt*16 + ln)*34 + g*8;
      float2 p0 = *(float2*)&bw[base+0];
      float2 p1 = *(float2*)&bw[base+2];
      float2 p2 = *(float2*)&bw[base+4];
      float2 p3 = *(float2*)&bw[base+6];
      short8 a2h, a2l;
      uint_t* hp = (uint_t*)&a2h;
      uint_t* lp = (uint_t*)&a2l;
      split2(p0.x, p0.y, hp[0], lp[0]);
      split2(p1.x, p1.y, hp[1], lp[1]);
      split2(p2.x, p2.y, hp[2], lp[2]);
      split2(p3.x, p3.y, hp[3], lp[3]);
      #pragma unroll
      for (int ct=0; ct<4; ++ct){
        short8 b2h = *(const short8*)&w2hiT[(size_t)(ct*16+ln)*128 + jp*32 + g*8];
        short8 b2l = *(const short8*)&w2loT[(size_t)(ct*16+ln)*128 + jp*32 + g*8];
        acc2[rt][ct] = __builtin_amdgcn_mfma_f32_16x16x32_bf16(a2h, b2h, acc2[rt][ct], 0,0,0);
        acc2[rt][ct] = __builtin_amdgcn_mfma_f32_16x16x32_bf16(a2l, b2h, acc2[rt][ct], 0,0,0);
        acc2[rt][ct] = __builtin_amdgcn_mfma_f32_16x16x32_bf16(a2h, b2l, acc2[rt][ct], 0,0,0);
      }
    }
  }
  #pragma unroll
  for (int ct=0; ct<4; ++ct){
    float bb = b2[ct*16 + ln];
    #pragma unroll
    for (int rt=0; rt<2; ++rt)
      #pragma unroll
      for (int i=0; i<4; ++i){
        int row = wid*32 + rt*16 + g*4 + i;
        size_t fiber = (size_t)vbid*128 + row;
        kbxp[fiber*64 + ct*16 + ln] = pack_hl2(gelu_f(bb + acc2[rt][ct][i]));
      }
  }
}

__global__ __launch_bounds__(256) void k_dmkbx(
    const uint_t* __restrict__ x1p,
    const int* __restrict__ sidxG, const int* __restrict__ allD,
    const ushort_t* __restrict__ dwThi, const ushort_t* __restrict__ dwTlo,
    const float* __restrict__ db, float* __restrict__ xA,
    const float* __restrict__ ps, const int* __restrict__ nbrS,
    const float* __restrict__ grid, const float* __restrict__ rff,
    const ushort_t* __restrict__ w1hiT, const ushort_t* __restrict__ w1loT,
    const ushort_t* __restrict__ w2hiT, const ushort_t* __restrict__ w2loT,
    const float* __restrict__ b1, const float* __restrict__ b2,
    uint_t* __restrict__ kbxp){
  __shared__ __align__(16) uint_t um[12384];   // 49.5 KB union
  int bid = blockIdx.x;
  if (bid < B_*M_)
    dm_body(um, bid, x1p, sidxG, allD, dwThi, dwTlo, db, xA);
  else
    kbx_body((float*)um, bid - B_*M_, ps, nbrS, grid, rff, w1hiT, w1loT, w2hiT, w2loT, b1, b2, kbxp);
}

// ============ interaction layer (MFMA kx-apply, T14 prefetch, aliased LDS) ============
__global__ __launch_bounds__(256) void k_inter(
    const float* __restrict__ xin, const int* __restrict__ nbr,
    const uint_t* __restrict__ kbxp, const float* __restrict__ kR,
    const ushort_t* __restrict__ kxhT, const ushort_t* __restrict__ kxlT,
    const float* __restrict__ kxb,
    const float* __restrict__ mw, const float* __restrict__ mb,
    float* __restrict__ xout, float* __restrict__ part){
  int bm = blockIdx.x; int b = bm / M_;
  int tid = threadIdx.x;
  int wid = tid>>6, lane = tid&63, ln = lane&15, g4 = lane>>4;
  int c = tid & 127, gh = tid >> 7;
  __shared__ uint_t kbsL[48][68];                 // 13.06 KB
  __shared__ __align__(16) float TsU[48*129];     // 24.19 KB; aliased: Ts -> aggS/yS/psumS
  float* aggS_ = TsU;            // [12][128]
  float* yS_   = TsU + 1536;     // [12][128]
  float* psumS_= TsU + 3072;     // [2][128]

  const uint4* ksrc = (const uint4*)(kbxp + (size_t)bm*192*64);

  uint4 ka = ksrc[tid], kbv = ksrc[tid+256], kc = ksrc[tid+512];
  int nb0 = nbr[(size_t)bm*K_+0], nb1 = nbr[(size_t)bm*K_+1],
      nb2 = nbr[(size_t)bm*K_+2], nb3 = nbr[(size_t)bm*K_+3];

  short8 bh[2][2], bl[2][2];
  float kxbv[2];
  #pragma unroll
  for (int nt=0; nt<2; ++nt){
    int cc_ = (wid*2+nt)*16 + ln;
    kxbv[nt] = kxb[cc_];
    #pragma unroll
    for (int ks=0; ks<2; ++ks){
      bh[nt][ks] = *(const short8*)&kxhT[(size_t)cc_*64 + ks*32 + g4*8];
      bl[nt][ks] = *(const short8*)&kxlT[(size_t)cc_*64 + ks*32 + g4*8];
    }
  }
  float accg[6] = {0,0,0,0,0,0};

  for (int cc=0; cc<4; ++cc){
    {
      int i0=tid, i1=tid+256, i2=tid+512;
      *(uint4*)&kbsL[i0>>4][(i0&15)*4] = ka;
      *(uint4*)&kbsL[i1>>4][(i1&15)*4] = kbv;
      *(uint4*)&kbsL[i2>>4][(i2&15)*4] = kc;
    }
    __syncthreads();   // A: kbsL ready
    float xreg[24];
    {
      const float* xr0 = xin + ((size_t)(b*M_) + nb0)*(NG_*C_);
      const float* xr1 = xin + ((size_t)(b*M_) + nb1)*(NG_*C_);
      const float* xr2 = xin + ((size_t)(b*M_) + nb2)*(NG_*C_);
      const float* xr3 = xin + ((size_t)(b*M_) + nb3)*(NG_*C_);
      #pragma unroll
      for (int gi=0; gi<6; ++gi){
        int off = (gh*6+gi)*C_ + c;
        xreg[0*6+gi] = xr0[off];
        xreg[1*6+gi] = xr1[off];
        xreg[2*6+gi] = xr2[off];
        xreg[3*6+gi] = xr3[off];
      }
    }
    if (cc < 3){
      ka  = ksrc[(cc+1)*768 + tid];
      kbv = ksrc[(cc+1)*768 + tid + 256];
      kc  = ksrc[(cc+1)*768 + tid + 512];
      nb0 = nbr[(size_t)bm*K_ + (cc+1)*4 + 0];
      nb1 = nbr[(size_t)bm*K_ + (cc+1)*4 + 1];
      nb2 = nbr[(size_t)bm*K_ + (cc+1)*4 + 2];
      nb3 = nbr[(size_t)bm*K_ + (cc+1)*4 + 3];
    }
    floatx4 acc[3][2];
    #pragma unroll
    for (int mt=0; mt<3; ++mt)
      #pragma unroll
      for (int nt=0; nt<2; ++nt)
        acc[mt][nt] = (floatx4){0.f,0.f,0.f,0.f};
    #pragma unroll
    for (int mt=0; mt<3; ++mt){
      short8 ah[2], al[2];
      #pragma unroll
      for (int ks=0; ks<2; ++ks){
        const uint_t* src = &kbsL[mt*16+ln][ks*32+g4*8];
        uint4 q0 = *(const uint4*)src;
        uint4 q1 = *(const uint4*)(src+4);
        UNPACK8(q0, q1, ah[ks], al[ks]);
      }
      #pragma unroll
      for (int nt=0; nt<2; ++nt)
        #pragma unroll
        for (int ks=0; ks<2; ++ks){
          acc[mt][nt] = __builtin_amdgcn_mfma_f32_16x16x32_bf16(ah[ks], bh[nt][ks], acc[mt][nt], 0,0,0);
          acc[mt][nt] = __builtin_amdgcn_mfma_f32_16x16x32_bf16(al[ks], bh[nt][ks], acc[mt][nt], 0,0,0);
          acc[mt][nt] = __builtin_amdgcn_mfma_f32_16x16x32_bf16(ah[ks], bl[nt][ks], acc[mt][nt], 0,0,0);
        }
    }
    #pragma unroll
    for (int mt=0; mt<3; ++mt)
      #pragma unroll
      for (int nt=0; nt<2; ++nt)
        #pragma unroll
        for (int i=0; i<4; ++i)
          TsU[(mt*16 + g4*4 + i)*129 + (wid*2+nt)*16 + ln] = acc[mt][nt][i] + kxbv[nt];
    __syncthreads();   // B: Ts ready
    #pragma unroll
    for (int kl=0; kl<4; ++kl)
      #pragma unroll
      for (int gi=0; gi<6; ++gi)
        accg[gi] = fmaf(TsU[(kl*12 + gh*6 + gi)*129 + c], xreg[kl*6+gi], accg[gi]);
    __syncthreads();   // C: Ts reads done before next chunk overwrites kbsL/Ts
  }
  // Ts region dead -> reuse for aggS/yS/psumS
  #pragma unroll
  for (int gi=0; gi<6; ++gi)
    aggS_[(gh*6+gi)*C_ + c] = accg[gi] * (1.0f/16.0f);
  __syncthreads();
  #pragma unroll
  for (int gi=0; gi<6; ++gi){
    int g = gh*6+gi;
    float yv = 0.f;
    #pragma unroll
    for (int n=0;n<NG_;++n) yv = fmaf(aggS_[n*C_ + c], kR[((size_t)g*NG_+n)*C_ + c], yv);
    yS_[g*C_ + c] = yv * (1.0f/12.0f);
  }
  __syncthreads();
  float m6[6] = {0,0,0,0,0,0};
  for (int i4=0;i4<32;++i4){
    float w0 = mw[(i4*4+0)*C_+c], w1 = mw[(i4*4+1)*C_+c],
          w2 = mw[(i4*4+2)*C_+c], w3 = mw[(i4*4+3)*C_+c];
    #pragma unroll
    for (int gi=0;gi<6;++gi){
      int g = gh*6+gi;
      float4 yv = *(const float4*)&yS_[g*C_ + i4*4];
      m6[gi] = fmaf(yv.x,w0,fmaf(yv.y,w1,fmaf(yv.z,w2,fmaf(yv.w,w3,m6[gi]))));
    }
  }
  float mbc = mb[c];
  float psum = 0.f;
  #pragma unroll
  for (int gi=0;gi<6;++gi){
    int g = gh*6+gi;
    size_t off = (size_t)bm*(NG_*C_) + g*C_ + c;
    float val = xin[off] + gelu_f(m6[gi] + mbc);
    xout[off] = val;
    psum += val;
  }
  if (part){
    psumS_[gh*C_ + c] = psum;
    __syncthreads();
    if (gh == 0)
      part[(size_t)bm*C_ + c] = psumS_[c] + psumS_[C_ + c];
  }
}

// ============ head: 512-row reduce + MLP ============
__global__ __launch_bounds__(256) void k_head(
    const float* __restrict__ part,
    const float* __restrict__ p1w, const float* __restrict__ p1b,
    const float* __restrict__ p2w, const float* __restrict__ p2b,
    const float* __restrict__ p3w, const float* __restrict__ p3b,
    float* __restrict__ out){
  int b = blockIdx.x, tid = threadIdx.x;
  int c = tid & 127, half = tid >> 7;
  __shared__ float red[256];
  __shared__ float gs[128];
  {
    const float* pb = part + (size_t)b*M_*C_;
    float a0=0.f,a1=0.f,a2=0.f,a3=0.f;
    for (int r = half*4; r < M_; r += 8){
      a0 += pb[(size_t)(r+0)*C_ + c];
      a1 += pb[(size_t)(r+1)*C_ + c];
      a2 += pb[(size_t)(r+2)*C_ + c];
      a3 += pb[(size_t)(r+3)*C_ + c];
    }
    red[tid] = (a0+a1)+(a2+a3);
  }
  __syncthreads();
  if (half==0) gs[c] = (red[c] + red[128+c]) * (1.0f/(M_*NG_));
  __syncthreads();
  __shared__ float h1[256];
  {
    float a = p1b[tid];
    for (int i=0;i<128;++i) a = fmaf(gs[i], p1w[i*256+tid], a);
    h1[tid] = gelu_f(a);
  }
  __syncthreads();
  __shared__ float h2[64];
  if (tid<64){
    float a = p2b[tid];
    for (int i=0;i<256;++i) a = fmaf(h1[i], p2w[i*64+tid], a);
    h2[tid] = gelu_f(a);
  }
  __syncthreads();
  if (tid==0){
    float a = p3b[0];
    for (int i=0;i<64;++i) a = fmaf(h2[i], p3w[i], a);
    out[b] = a;
  }
}

extern "C" void kernel_launch(void* const* d_in, const int* in_sizes, int n_in,
                              void* d_out, int out_size, void* d_ws, size_t ws_size,
                              hipStream_t stream){
  const float* pos    = (const float*)d_in[0];
  const float* normal = (const float*)d_in[1];
  const float* grid   = (const float*)d_in[2];
  const float* e1w = (const float*)d_in[3];  const float* e1b = (const float*)d_in[4];
  const float* e2w = (const float*)d_in[5];  const float* e2b = (const float*)d_in[6];
  const float* dww = (const float*)d_in[7];  const float* dwb = (const float*)d_in[8];
  const float* bx_rff = (const float*)d_in[9];
  const float* bx1w = (const float*)d_in[10]; const float* bx1b = (const float*)d_in[11];
  const float* bx2w = (const float*)d_in[12]; const float* bx2b = (const float*)d_in[13];
  const float* bR_rff = (const float*)d_in[14];
  const float* bR1w = (const float*)d_in[15]; const float* bR1b = (const float*)d_in[16];
  const float* bR2w = (const float*)d_in[17]; const float* bR2b = (const float*)d_in[18];
  const float* i1kxw = (const float*)d_in[19]; const float* i1kxb = (const float*)d_in[20];
  const float* i1kRw = (const float*)d_in[21]; const float* i1kRb = (const float*)d_in[22];
  const float* i1mw  = (const float*)d_in[23]; const float* i1mb  = (const float*)d_in[24];
  const float* i2kxw = (const float*)d_in[25]; const float* i2kxb = (const float*)d_in[26];
  const float* i2kRw = (const float*)d_in[27]; const float* i2kRb = (const float*)d_in[28];
  const float* i2mw  = (const float*)d_in[29]; const float* i2mb  = (const float*)d_in[30];
  const float* p1w = (const float*)d_in[31]; const float* p1b = (const float*)d_in[32];
  const float* p2w = (const float*)d_in[33]; const float* p2b = (const float*)d_in[34];
  const float* p3w = (const float*)d_in[35]; const float* p3b = (const float*)d_in[36];
  float* out = (float*)d_out;

  float* ws = (float*)d_ws;
  size_t o = 0;
  uint_t* x1p = (uint_t*)(ws + o); o += (size_t)B_*N_*NG_*H_;
  float* psb = ws + o; o += (size_t)B_*M_*3;
  float* xA  = ws + o; o += (size_t)B_*M_*NG_*C_;
  float* xB  = ws + o; o += (size_t)B_*M_*NG_*C_;
  uint_t* kbxp = (uint_t*)(ws + o); o += (size_t)B_*M_*K_*NG_*BD_;
  float* kRb1 = ws + o; o += (size_t)NG_*NG_*C_;
  float* kRb2 = ws + o; o += (size_t)NG_*NG_*C_;
  float* part = ws + o; o += (size_t)B_*M_*C_;
  float4* pos4 = (float4*)(ws + o); o += (size_t)B_*N_*4;
  float4* ps4  = (float4*)(ws + o); o += (size_t)B_*M_*4;
  int* sidxG = (int*)(ws + o); o += (size_t)B_*M_;
  int* allD  = (int*)(ws + o); o += (size_t)B_*N_*K_;
  int* nbrS  = (int*)(ws + o); o += (size_t)B_*M_*K_;
  ushort_t* w1hiT = (ushort_t*)(ws + o); o += 8192;
  ushort_t* w1loT = (ushort_t*)(ws + o); o += 8192;
  ushort_t* w2hiT = (ushort_t*)(ws + o); o += 4096;
  ushort_t* w2loT = (ushort_t*)(ws + o); o += 4096;
  ushort_t* x1hiT = (ushort_t*)(ws + o); o += 4096;
  ushort_t* x1loT = (ushort_t*)(ws + o); o += 4096;
  ushort_t* x2hiT = (ushort_t*)(ws + o); o += 4096;
  ushort_t* x2loT = (ushort_t*)(ws + o); o += 4096;
  ushort_t* dwThi = (ushort_t*)(ws + o); o += 4096;
  ushort_t* dwTlo = (ushort_t*)(ws + o); o += 4096;

  k_mega1<<<FPSB + LIFTB + WSB + KBRB + PM4B + AKB, 256, 0, stream>>>(
      pos, normal, grid, e1w, e1b, e2w, e2b, x1p, psb, pos4, ps4, sidxG, allD,
      bx1w, bx2w, i1kxw, i2kxw, dww,
      w1hiT, w1loT, w2hiT, w2loT, x1hiT, x1loT, x2hiT, x2loT, dwThi, dwTlo,
      bR_rff, bR1w, bR1b, bR2w, bR2b,
      i1kRw, i1kRb, i2kRw, i2kRb, kRb1, kRb2);
  k_knn_all<<<B_*M_/4, 256, 0, stream>>>(ps4, nbrS);
  k_dmkbx<<<B_*M_ + (B_*M_*K_*NG_)/128, 256, 0, stream>>>(
      x1p, sidxG, allD, dwThi, dwTlo, dwb, xA,
      psb, nbrS, grid, bx_rff, w1hiT, w1loT, w2hiT, w2loT, bx1b, bx2b, kbxp);
  k_inter<<<B_*M_, 256, 0, stream>>>(xA, nbrS, kbxp, kRb1, x1hiT, x1loT, i1kxb, i1mw, i1mb, xB, nullptr);
  k_inter<<<B_*M_, 256, 0, stream>>>(xB, nbrS, kbxp, kRb2, x2hiT, x2loT, i2kxb, i2mw, i2mb, xA, part);
  k_head<<<B_, 256, 0, stream>>>(part, p1w, p1b, p2w, p2b, p3w, p3b, out);
}